// Round 1
// baseline (4789.052 us; speedup 1.0000x reference)
//
#include <hip/hip_runtime.h>
#include <math.h>

#define C     768
#define HEADS 12
#define HD    64
#define NF    8
#define SL    196
#define BB    2
#define NN    1569   // 1 + NF*SL
#define SS    1568   // NF*SL
#define HID   3072

// ---------------- LayerNorm (row per block, C=768 = 256*3) ----------------
__global__ void ln_kernel(const float* __restrict__ x, const float* __restrict__ g,
                          const float* __restrict__ b, float* __restrict__ out, int rows) {
    int row = blockIdx.x;
    if (row >= rows) return;
    const float* xr = x + (size_t)row * C;
    int tid = threadIdx.x;
    float v[3];
    float sum = 0.f, sumsq = 0.f;
#pragma unroll
    for (int i = 0; i < 3; i++) {
        v[i] = xr[tid + 256 * i];
        sum += v[i]; sumsq += v[i] * v[i];
    }
    __shared__ float s1[4], s2[4];
    for (int off = 32; off; off >>= 1) {
        sum   += __shfl_xor(sum, off);
        sumsq += __shfl_xor(sumsq, off);
    }
    int wave = tid >> 6, lane = tid & 63;
    if (lane == 0) { s1[wave] = sum; s2[wave] = sumsq; }
    __syncthreads();
    sum   = s1[0] + s1[1] + s1[2] + s1[3];
    sumsq = s2[0] + s2[1] + s2[2] + s2[3];
    float mu  = sum / C;
    float var = sumsq / C - mu * mu;
    float rstd = rsqrtf(fmaxf(var, 0.f) + 1e-5f);
    float* outr = out + (size_t)row * C;
#pragma unroll
    for (int i = 0; i < 3; i++) {
        int c = tid + 256 * i;
        outr[c] = (v[i] - mu) * rstd * g[c] + b[c];
    }
}

// ---------------- Generic fp32 GEMM: C = A(MxK) * B(KxN) [+bias][gelu][+resid] ----------------
// BM=BN=64, BK=16, 256 threads, 4x4 per thread. K must be multiple of 16.
template<bool GELU>
__global__ void gemm_kernel(const float* __restrict__ A, const float* __restrict__ Bm,
                            const float* __restrict__ bias, const float* __restrict__ resid,
                            float* __restrict__ Cm,
                            int M, int Nc, int K, int lda, int ldb) {
    __shared__ float As[16][65];
    __shared__ float Bs[16][65];
    int tid = threadIdx.x;
    int tx = tid & 15, ty = tid >> 4;
    int row0 = blockIdx.y * 64, col0 = blockIdx.x * 64;
    float acc[4][4] = {};
    for (int k0 = 0; k0 < K; k0 += 16) {
#pragma unroll
        for (int it = 0; it < 4; it++) {
            int flat = tid + 256 * it;
            int m = flat >> 4, kk = flat & 15;
            int gm = row0 + m;
            As[kk][m] = (gm < M) ? A[(size_t)gm * lda + k0 + kk] : 0.f;
        }
#pragma unroll
        for (int it = 0; it < 4; it++) {
            int flat = tid + 256 * it;
            int kk = flat >> 6, n = flat & 63;
            int gn = col0 + n;
            Bs[kk][n] = (gn < Nc) ? Bm[(size_t)(k0 + kk) * ldb + gn] : 0.f;
        }
        __syncthreads();
#pragma unroll
        for (int kk = 0; kk < 16; kk++) {
            float a[4], bq[4];
#pragma unroll
            for (int i = 0; i < 4; i++) a[i] = As[kk][ty + 16 * i];
#pragma unroll
            for (int j = 0; j < 4; j++) bq[j] = Bs[kk][tx + 16 * j];
#pragma unroll
            for (int i = 0; i < 4; i++)
#pragma unroll
                for (int j = 0; j < 4; j++)
                    acc[i][j] += a[i] * bq[j];
        }
        __syncthreads();
    }
#pragma unroll
    for (int i = 0; i < 4; i++) {
        int m = row0 + ty + 16 * i;
        if (m >= M) continue;
#pragma unroll
        for (int j = 0; j < 4; j++) {
            int n = col0 + tx + 16 * j;
            if (n >= Nc) continue;
            float v = acc[i][j];
            if (bias) v += bias[n];
            if (GELU) v = 0.5f * v * (1.f + erff(v * 0.70710678118f));
            if (resid) v += resid[(size_t)m * Nc + n];
            Cm[(size_t)m * Nc + n] = v;
        }
    }
}

// ---------------- cls-token attention: one block per (b, head) ----------------
__global__ void cls_attn_kernel(const float* __restrict__ qkv, float* __restrict__ y) {
    int bh = blockIdx.x;
    int b = bh / HEADS, hh = bh % HEADS;
    int tid = threadIdx.x;
    __shared__ float s_q[HD];
    __shared__ float s_sc[NN];
    __shared__ float swm[4], sws[4];
    if (tid < HD) s_q[tid] = qkv[((size_t)b * NN + 0) * 3 * C + hh * HD + tid];
    __syncthreads();
    const float4* q4 = (const float4*)s_q;
    float pmax = -1e30f;
    for (int j = tid; j < NN; j += 256) {
        const float4* kp = (const float4*)(qkv + ((size_t)b * NN + j) * 3 * C + C + hh * HD);
        float acc = 0.f;
#pragma unroll
        for (int u = 0; u < 16; u++) {
            float4 kq = kp[u]; float4 qq = q4[u];
            acc += qq.x * kq.x + qq.y * kq.y + qq.z * kq.z + qq.w * kq.w;
        }
        acc *= 0.125f;
        s_sc[j] = acc;
        pmax = fmaxf(pmax, acc);
    }
    for (int off = 32; off; off >>= 1) pmax = fmaxf(pmax, __shfl_xor(pmax, off));
    int wave = tid >> 6, lane = tid & 63;
    if (lane == 0) swm[wave] = pmax;
    __syncthreads();
    pmax = fmaxf(fmaxf(swm[0], swm[1]), fmaxf(swm[2], swm[3]));
    float psum = 0.f;
    for (int j = tid; j < NN; j += 256) {
        float e = __expf(s_sc[j] - pmax);
        s_sc[j] = e;
        psum += e;
    }
    for (int off = 32; off; off >>= 1) psum += __shfl_xor(psum, off);
    if (lane == 0) sws[wave] = psum;
    __syncthreads();
    psum = sws[0] + sws[1] + sws[2] + sws[3];
    float inv = 1.f / psum;
    if (tid < HD) {
        float acc = 0.f;
        for (int j = 0; j < NN; j++)
            acc += s_sc[j] * qkv[((size_t)b * NN + j) * 3 * C + 2 * C + hh * HD + tid];
        y[((size_t)b * NN + 0) * C + hh * HD + tid] = acc * inv;
    }
}

// ---------------- spatial attention: one block per (b, head, query) ----------------
__global__ void space_attn_kernel(const float* __restrict__ qkv, float* __restrict__ x1) {
    int idx = blockIdx.x;
    int bh = idx / SS, qi = idx % SS;
    int b = bh / HEADS, hh = bh % HEADS;
    int tid = threadIdx.x;
    __shared__ float s_q[HD];
    __shared__ float s_sc[SS];
    if (tid < HD) s_q[tid] = qkv[((size_t)b * NN + 1 + qi) * 3 * C + hh * HD + tid];
    __syncthreads();
    const float4* q4 = (const float4*)s_q;
    for (int j = tid; j < SS; j += 256) {
        const float4* kp = (const float4*)(qkv + ((size_t)b * NN + 1 + j) * 3 * C + C + hh * HD);
        float acc = 0.f;
#pragma unroll
        for (int u = 0; u < 16; u++) {
            float4 kq = kp[u]; float4 qq = q4[u];
            acc += qq.x * kq.x + qq.y * kq.y + qq.z * kq.z + qq.w * kq.w;
        }
        s_sc[j] = acc * 0.125f;
    }
    __syncthreads();
    // per-frame softmax: wave w handles frames w and w+4
    int wave = tid >> 6, lane = tid & 63;
#pragma unroll
    for (int fi = 0; fi < 2; fi++) {
        int f = wave + 4 * fi;
        float m = -1e30f;
        for (int n = lane; n < SL; n += 64) m = fmaxf(m, s_sc[f * SL + n]);
        for (int off = 32; off; off >>= 1) m = fmaxf(m, __shfl_xor(m, off));
        float sum = 0.f;
        for (int n = lane; n < SL; n += 64) {
            float e = __expf(s_sc[f * SL + n] - m);
            s_sc[f * SL + n] = e;
            sum += e;
        }
        for (int off = 32; off; off >>= 1) sum += __shfl_xor(sum, off);
        float inv = 1.f / sum;
        for (int n = lane; n < SL; n += 64) s_sc[f * SL + n] *= inv;
    }
    __syncthreads();
    // PV: thread -> (f, dd), two frames per thread
    int dd = tid & 63;
#pragma unroll
    for (int fi = 0; fi < 2; fi++) {
        int f = (tid >> 6) + 4 * fi;
        float acc = 0.f;
        const float* vp = qkv + ((size_t)b * NN + 1 + f * SL) * 3 * C + 2 * C + hh * HD + dd;
        for (int n = 0; n < SL; n++) acc += s_sc[f * SL + n] * vp[(size_t)n * 3 * C];
        x1[(((size_t)(b * SS + qi)) * NF + f) * C + hh * HD + dd] = acc;
    }
}

// ---------------- diagonal gather: x_diag[b,s,:] = x1[b,s,s/SL,:] ----------------
__global__ void diag_kernel(const float* __restrict__ x1, float* __restrict__ xd) {
    int i = blockIdx.x * 256 + threadIdx.x; // float4 element of (B*S, C)
    int total = BB * SS * (C / 4);
    if (i >= total) return;
    int c4 = i % (C / 4);
    int row = i / (C / 4);
    int s = row % SS;
    int f = s / SL;
    const float4* src = (const float4*)(x1 + (((size_t)row) * NF + f) * C);
    ((float4*)(xd + (size_t)row * C))[c4] = src[c4];
}

// ---------------- temporal attention: one wave per (b, head, s) ----------------
__global__ void attn2_kernel(const float* __restrict__ q2, const float* __restrict__ k2,
                             const float* __restrict__ x1, float* __restrict__ y) {
    int item = blockIdx.x * 4 + (threadIdx.x >> 6);
    if (item >= BB * HEADS * SS) return;
    int lane = threadIdx.x & 63;
    int s = item % SS;
    int bh = item / SS;
    int b = bh / HEADS, hh = bh % HEADS;
    size_t rowbs = (size_t)(b * SS + s);
    float qv = q2[rowbs * C + hh * HD + lane] * 0.125f;
    float lg[NF];
#pragma unroll
    for (int f = 0; f < NF; f++) {
        float p = qv * k2[(rowbs * NF + f) * C + hh * HD + lane];
        for (int off = 32; off; off >>= 1) p += __shfl_xor(p, off);
        lg[f] = p;
    }
    float m = lg[0];
#pragma unroll
    for (int f = 1; f < NF; f++) m = fmaxf(m, lg[f]);
    float sum = 0.f;
#pragma unroll
    for (int f = 0; f < NF; f++) { lg[f] = __expf(lg[f] - m); sum += lg[f]; }
    float inv = 1.f / sum;
    float acc = 0.f;
#pragma unroll
    for (int f = 0; f < NF; f++) acc += lg[f] * x1[(rowbs * NF + f) * C + hh * HD + lane];
    y[((size_t)b * NN + 1 + s) * C + hh * HD + lane] = acc * inv;
}

extern "C" void kernel_launch(void* const* d_in, const int* in_sizes, int n_in,
                              void* d_out, int out_size, void* d_ws, size_t ws_size,
                              hipStream_t stream) {
    const float* x    = (const float*)d_in[0];
    const float* g1   = (const float*)d_in[1];
    const float* b1   = (const float*)d_in[2];
    const float* Wqkv = (const float*)d_in[3];
    const float* Wq   = (const float*)d_in[4];
    const float* Wkv  = (const float*)d_in[5];
    const float* Wp   = (const float*)d_in[6];
    const float* bp   = (const float*)d_in[7];
    const float* g2   = (const float*)d_in[8];
    const float* b2   = (const float*)d_in[9];
    const float* W1   = (const float*)d_in[10];
    const float* bf1  = (const float*)d_in[11];
    const float* W2   = (const float*)d_in[12];
    const float* bf2  = (const float*)d_in[13];
    float* out = (float*)d_out;
    float* ws  = (float*)d_ws;

    // workspace layout (floats)
    float* xn  = ws;                    // 2,409,984 (B*N*C) -- reused as hn after qkv GEMM
    float* qkv = xn  + 2409984;         // 7,229,952 (B*N*3C)
    float* x1  = qkv + 7229952;         // 19,267,584 (B*S*F*C)
    float* xd  = x1  + 19267584;        // 2,408,448 (B*S*C)
    float* q2  = xd  + 2408448;         // 2,408,448 (B*S*C)
    float* k2  = q2  + 2408448;         // 19,267,584 (B*S*F*C)
    float* y   = k2  + 19267584;        // 2,409,984 (B*N*C)
    float* a1  = y   + 2409984;         // 9,639,936 (B*N*HID)

    const int M1 = BB * NN;       // 3138
    const int M2 = BB * SS;       // 3136
    const int M3 = BB * SS * NF;  // 25088

    // 1. LN1
    ln_kernel<<<M1, 256, 0, stream>>>(x, g1, b1, xn, M1);
    // 2. qkv = xn @ Wqkv
    gemm_kernel<false><<<dim3(2304 / 64, (M1 + 63) / 64), 256, 0, stream>>>(
        xn, Wqkv, nullptr, nullptr, qkv, M1, 2304, 768, 768, 2304);
    // 3. cls attention -> y row 0 per batch
    cls_attn_kernel<<<BB * HEADS, 256, 0, stream>>>(qkv, y);
    // 4. spatial attention -> x1
    space_attn_kernel<<<BB * HEADS * SS, 256, 0, stream>>>(qkv, x1);
    // 5. diagonal gather
    int tot4 = BB * SS * (C / 4);
    diag_kernel<<<(tot4 + 255) / 256, 256, 0, stream>>>(x1, xd);
    // 6. q2 = x_diag @ Wq
    gemm_kernel<false><<<dim3(768 / 64, (M2 + 63) / 64), 256, 0, stream>>>(
        xd, Wq, nullptr, nullptr, q2, M2, 768, 768, 768, 768);
    // 7. k2 = x1 @ Wkv[:, :C]   (v2 is unused by the reference!)
    gemm_kernel<false><<<dim3(768 / 64, M3 / 64), 256, 0, stream>>>(
        x1, Wkv, nullptr, nullptr, k2, M3, 768, 768, 768, 1536);
    // 8. temporal attention -> y rows 1..S per batch
    attn2_kernel<<<(BB * HEADS * SS + 3) / 4, 256, 0, stream>>>(q2, k2, x1, y);
    // 9. proj: out = y @ Wp + bp + x   (x_mid lives in d_out)
    gemm_kernel<false><<<dim3(768 / 64, (M1 + 63) / 64), 256, 0, stream>>>(
        y, Wp, bp, x, out, M1, 768, 768, 768, 768);
    // 10. LN2 (hn reuses xn)
    ln_kernel<<<M1, 256, 0, stream>>>(out, g2, b2, xn, M1);
    // 11. fc1 + exact GELU
    gemm_kernel<true><<<dim3(3072 / 64, (M1 + 63) / 64), 256, 0, stream>>>(
        xn, W1, bf1, nullptr, a1, M1, 3072, 768, 768, 3072);
    // 12. fc2 + residual (in-place on d_out: each thread reads its own element first)
    gemm_kernel<false><<<dim3(768 / 64, (M1 + 63) / 64), 256, 0, stream>>>(
        a1, W2, bf2, out, out, M1, 768, 3072, 3072, 768);
}

// Round 2
// 2150.927 us; speedup vs baseline: 2.2265x; 2.2265x over previous
//
#include <hip/hip_runtime.h>
#include <math.h>

#define C     768
#define HEADS 12
#define HD    64
#define NF    8
#define SL    196
#define BB    2
#define NN    1569   // 1 + NF*SL
#define SS    1568   // NF*SL
#define HID   3072

typedef __attribute__((ext_vector_type(8))) short short8;
typedef __attribute__((ext_vector_type(4))) float f32x4;

__device__ inline unsigned short f2b(float f) {
    union { float f; unsigned u; } v; v.f = f;
    unsigned r = (v.u + 0x7FFFu + ((v.u >> 16) & 1u)) >> 16;
    return (unsigned short)r;
}

// ---------------- LayerNorm (row per block, C=768 = 256*3) ----------------
__global__ void ln_kernel(const float* __restrict__ x, const float* __restrict__ g,
                          const float* __restrict__ b, float* __restrict__ out, int rows) {
    int row = blockIdx.x;
    if (row >= rows) return;
    const float* xr = x + (size_t)row * C;
    int tid = threadIdx.x;
    float v[3];
    float sum = 0.f, sumsq = 0.f;
#pragma unroll
    for (int i = 0; i < 3; i++) {
        v[i] = xr[tid + 256 * i];
        sum += v[i]; sumsq += v[i] * v[i];
    }
    __shared__ float s1[4], s2[4];
    for (int off = 32; off; off >>= 1) {
        sum   += __shfl_xor(sum, off);
        sumsq += __shfl_xor(sumsq, off);
    }
    int wave = tid >> 6, lane = tid & 63;
    if (lane == 0) { s1[wave] = sum; s2[wave] = sumsq; }
    __syncthreads();
    sum   = s1[0] + s1[1] + s1[2] + s1[3];
    sumsq = s2[0] + s2[1] + s2[2] + s2[3];
    float mu  = sum / C;
    float var = sumsq / C - mu * mu;
    float rstd = rsqrtf(fmaxf(var, 0.f) + 1e-5f);
    float* outr = out + (size_t)row * C;
#pragma unroll
    for (int i = 0; i < 3; i++) {
        int c = tid + 256 * i;
        outr[c] = (v[i] - mu) * rstd * g[c] + b[c];
    }
}

// ---------------- Generic fp32 GEMM: C = A(MxK) * B(KxN) [+bias][gelu][+resid] ----------------
template<bool GELU>
__global__ void gemm_kernel(const float* __restrict__ A, const float* __restrict__ Bm,
                            const float* __restrict__ bias, const float* __restrict__ resid,
                            float* __restrict__ Cm,
                            int M, int Nc, int K, int lda, int ldb) {
    __shared__ float As[16][65];
    __shared__ float Bs[16][65];
    int tid = threadIdx.x;
    int tx = tid & 15, ty = tid >> 4;
    int row0 = blockIdx.y * 64, col0 = blockIdx.x * 64;
    float acc[4][4] = {};
    for (int k0 = 0; k0 < K; k0 += 16) {
#pragma unroll
        for (int it = 0; it < 4; it++) {
            int flat = tid + 256 * it;
            int m = flat >> 4, kk = flat & 15;
            int gm = row0 + m;
            As[kk][m] = (gm < M) ? A[(size_t)gm * lda + k0 + kk] : 0.f;
        }
#pragma unroll
        for (int it = 0; it < 4; it++) {
            int flat = tid + 256 * it;
            int kk = flat >> 6, n = flat & 63;
            int gn = col0 + n;
            Bs[kk][n] = (gn < Nc) ? Bm[(size_t)(k0 + kk) * ldb + gn] : 0.f;
        }
        __syncthreads();
#pragma unroll
        for (int kk = 0; kk < 16; kk++) {
            float a[4], bq[4];
#pragma unroll
            for (int i = 0; i < 4; i++) a[i] = As[kk][ty + 16 * i];
#pragma unroll
            for (int j = 0; j < 4; j++) bq[j] = Bs[kk][tx + 16 * j];
#pragma unroll
            for (int i = 0; i < 4; i++)
#pragma unroll
                for (int j = 0; j < 4; j++)
                    acc[i][j] += a[i] * bq[j];
        }
        __syncthreads();
    }
#pragma unroll
    for (int i = 0; i < 4; i++) {
        int m = row0 + ty + 16 * i;
        if (m >= M) continue;
#pragma unroll
        for (int j = 0; j < 4; j++) {
            int n = col0 + tx + 16 * j;
            if (n >= Nc) continue;
            float v = acc[i][j];
            if (bias) v += bias[n];
            if (GELU) v = 0.5f * v * (1.f + erff(v * 0.70710678118f));
            if (resid) v += resid[(size_t)m * Nc + n];
            Cm[(size_t)m * Nc + n] = v;
        }
    }
}

// ---------------- cls-token attention: one block per (b, head) ----------------
__global__ void cls_attn_kernel(const float* __restrict__ qkv, float* __restrict__ y) {
    int bh = blockIdx.x;
    int b = bh / HEADS, hh = bh % HEADS;
    int tid = threadIdx.x;
    __shared__ float s_q[HD];
    __shared__ float s_sc[NN];
    __shared__ float swm[4], sws[4];
    if (tid < HD) s_q[tid] = qkv[((size_t)b * NN + 0) * 3 * C + hh * HD + tid];
    __syncthreads();
    const float4* q4 = (const float4*)s_q;
    float pmax = -1e30f;
    for (int j = tid; j < NN; j += 256) {
        const float4* kp = (const float4*)(qkv + ((size_t)b * NN + j) * 3 * C + C + hh * HD);
        float acc = 0.f;
#pragma unroll
        for (int u = 0; u < 16; u++) {
            float4 kq = kp[u]; float4 qq = q4[u];
            acc += qq.x * kq.x + qq.y * kq.y + qq.z * kq.z + qq.w * kq.w;
        }
        acc *= 0.125f;
        s_sc[j] = acc;
        pmax = fmaxf(pmax, acc);
    }
    for (int off = 32; off; off >>= 1) pmax = fmaxf(pmax, __shfl_xor(pmax, off));
    int wave = tid >> 6, lane = tid & 63;
    if (lane == 0) swm[wave] = pmax;
    __syncthreads();
    pmax = fmaxf(fmaxf(swm[0], swm[1]), fmaxf(swm[2], swm[3]));
    float psum = 0.f;
    for (int j = tid; j < NN; j += 256) {
        float e = __expf(s_sc[j] - pmax);
        s_sc[j] = e;
        psum += e;
    }
    for (int off = 32; off; off >>= 1) psum += __shfl_xor(psum, off);
    if (lane == 0) sws[wave] = psum;
    __syncthreads();
    psum = sws[0] + sws[1] + sws[2] + sws[3];
    float inv = 1.f / psum;
    if (tid < HD) {
        float acc = 0.f;
        for (int j = 0; j < NN; j++)
            acc += s_sc[j] * qkv[((size_t)b * NN + j) * 3 * C + 2 * C + hh * HD + tid];
        y[((size_t)b * NN + 0) * C + hh * HD + tid] = acc * inv;
    }
}

// ---------------- repack kernels: qkv (f32) -> bf16 Qb / Kb / Vt ----------------
// Qb[bh][q][d]           (24, 1568, 64)
__global__ void repack_q_kernel(const float* __restrict__ qkv, unsigned short* __restrict__ Qb) {
    int t = blockIdx.x * 256 + threadIdx.x;
    if (t >= 24 * SS * 8) return;
    int d8 = t & 7;
    int rest = t >> 3;
    int q = rest % SS;
    int bh = rest / SS;
    int b = bh / HEADS, h = bh % HEADS;
    const float* src = qkv + ((size_t)(b * NN) + 1 + q) * 2304 + h * HD + d8 * 8;
    short8 v;
#pragma unroll
    for (int j = 0; j < 8; j++) v[j] = (short)f2b(src[j]);
    *reinterpret_cast<short8*>(Qb + ((size_t)bh * SS + q) * 64 + d8 * 8) = v;
}

// Kb[bh][f][n(208)][d]   (24, 8, 208, 64), pad rows zeroed
__global__ void repack_k_kernel(const float* __restrict__ qkv, unsigned short* __restrict__ Kb) {
    int t = blockIdx.x * 256 + threadIdx.x;
    if (t >= 24 * NF * 208 * 8) return;
    int d8 = t & 7;
    int rest = t >> 3;
    int n = rest % 208;
    rest /= 208;
    int f = rest % NF;
    int bh = rest / NF;
    int b = bh / HEADS, h = bh % HEADS;
    short8 v = {0, 0, 0, 0, 0, 0, 0, 0};
    if (n < SL) {
        const float* src = qkv + ((size_t)(b * NN) + 1 + f * SL + n) * 2304 + C + h * HD + d8 * 8;
#pragma unroll
        for (int j = 0; j < 8; j++) v[j] = (short)f2b(src[j]);
    }
    *reinterpret_cast<short8*>(Kb + (((size_t)bh * NF + f) * 208 + n) * 64 + d8 * 8) = v;
}

// Vt[bh][f][d][n(224)]   (24, 8, 64, 224), pad cols zeroed (transposed V)
__global__ void repack_v_kernel(const float* __restrict__ qkv, unsigned short* __restrict__ Vt) {
    int t = blockIdx.x * 256 + threadIdx.x;
    if (t >= 24 * NF * 64 * 28) return;
    int n8 = t % 28;
    int rest = t / 28;
    int d = rest % 64;
    rest /= 64;
    int f = rest % NF;
    int bh = rest / NF;
    int b = bh / HEADS, h = bh % HEADS;
    int n0 = n8 * 8;
    const float* src = qkv + ((size_t)(b * NN) + 1 + f * SL) * 2304 + 2 * C + h * HD + d;
    short8 v;
#pragma unroll
    for (int j = 0; j < 8; j++) {
        int n = n0 + j;
        v[j] = (n < SL) ? (short)f2b(src[(size_t)n * 2304]) : (short)0;
    }
    *reinterpret_cast<short8*>(Vt + (((size_t)bh * NF + f) * 64 + d) * 224 + n0) = v;
}

// ---------------- MFMA spatial attention: 1 wave per (bh, f, 16-query strip) ----------------
// S = Q(16x64) @ K_f^T(64x196pad208) -> per-row softmax -> out(16x64) = P @ V_f
__global__ __launch_bounds__(64) void space_attn_mfma(
    const unsigned short* __restrict__ Qb, const unsigned short* __restrict__ Kb,
    const unsigned short* __restrict__ Vt, float* __restrict__ x1) {
    __shared__ unsigned short pbuf[16 * 232];   // P strip, stride 232 (2-way-free banks)
    int lane = threadIdx.x;
    int r16 = lane & 15, kg = lane >> 4;
    int qt = blockIdx.x, f = blockIdx.y, bh = blockIdx.z;
    int q0 = qt * 16;

    // A fragments (Q rows)
    const unsigned short* qrow = Qb + ((size_t)bh * SS + q0 + r16) * 64 + kg * 8;
    short8 aq0 = *reinterpret_cast<const short8*>(qrow);
    short8 aq1 = *reinterpret_cast<const short8*>(qrow + 32);

    // QK^T: 13 n-tiles x (2 k-chunks of 32)
    f32x4 acc[13];
#pragma unroll
    for (int t = 0; t < 13; t++) acc[t] = (f32x4){0.f, 0.f, 0.f, 0.f};
    const unsigned short* kbase = Kb + ((size_t)bh * NF + f) * 208 * 64;
#pragma unroll
    for (int t = 0; t < 13; t++) {
        const unsigned short* krow = kbase + (t * 16 + r16) * 64 + kg * 8;
        short8 bk0 = *reinterpret_cast<const short8*>(krow);
        short8 bk1 = *reinterpret_cast<const short8*>(krow + 32);
        acc[t] = __builtin_amdgcn_mfma_f32_16x16x32_bf16(aq0, bk0, acc[t], 0, 0, 0);
        acc[t] = __builtin_amdgcn_mfma_f32_16x16x32_bf16(aq1, bk1, acc[t], 0, 0, 0);
    }

    // softmax across cols (n). Lane holds rows q=kg*4+r, col n=t*16+r16.
    bool tail_mask = (r16 >= 4);  // for t==12: n = 192+r16 >= 196
    float mrow[4] = {-1e30f, -1e30f, -1e30f, -1e30f};
#pragma unroll
    for (int t = 0; t < 13; t++) {
        if (t == 12 && tail_mask) continue;
#pragma unroll
        for (int r = 0; r < 4; r++) mrow[r] = fmaxf(mrow[r], acc[t][r] * 0.125f);
    }
#pragma unroll
    for (int off = 8; off; off >>= 1)
#pragma unroll
        for (int r = 0; r < 4; r++) mrow[r] = fmaxf(mrow[r], __shfl_xor(mrow[r], off));

    float ssum[4] = {0.f, 0.f, 0.f, 0.f};
#pragma unroll
    for (int t = 0; t < 13; t++) {
#pragma unroll
        for (int r = 0; r < 4; r++) {
            float p = (t == 12 && tail_mask) ? 0.f : __expf(acc[t][r] * 0.125f - mrow[r]);
            acc[t][r] = p;
            ssum[r] += p;
        }
    }
#pragma unroll
    for (int off = 8; off; off >>= 1)
#pragma unroll
        for (int r = 0; r < 4; r++) ssum[r] += __shfl_xor(ssum[r], off);
    float inv[4];
#pragma unroll
    for (int r = 0; r < 4; r++) inv[r] = 1.f / ssum[r];

    // write unnormalized P (bf16) to LDS
#pragma unroll
    for (int t = 0; t < 13; t++)
#pragma unroll
        for (int r = 0; r < 4; r++)
            pbuf[(kg * 4 + r) * 232 + t * 16 + r16] = f2b(acc[t][r]);
    // zero pad cols 208..223
    {
        int zr = lane >> 2, zc = 208 + (lane & 3) * 4;
        *reinterpret_cast<uint2*>(&pbuf[zr * 232 + zc]) = (uint2){0u, 0u};
    }

    // PV: out(16x64) = P(16x224) @ V(224x64), V read as Vt[d][n]
    f32x4 o[4];
#pragma unroll
    for (int dt = 0; dt < 4; dt++) o[dt] = (f32x4){0.f, 0.f, 0.f, 0.f};
    const unsigned short* vbase = Vt + ((size_t)bh * NF + f) * 64 * 224;
#pragma unroll
    for (int kc = 0; kc < 7; kc++) {
        short8 pa = *reinterpret_cast<const short8*>(&pbuf[r16 * 232 + kc * 32 + kg * 8]);
#pragma unroll
        for (int dt = 0; dt < 4; dt++) {
            short8 bv = *reinterpret_cast<const short8*>(vbase + (dt * 16 + r16) * 224 + kc * 32 + kg * 8);
            o[dt] = __builtin_amdgcn_mfma_f32_16x16x32_bf16(pa, bv, o[dt], 0, 0, 0);
        }
    }

    // epilogue: rows q=q0+kg*4+r, col d=dt*16+r16
    int b = bh / HEADS, h = bh % HEADS;
#pragma unroll
    for (int dt = 0; dt < 4; dt++)
#pragma unroll
        for (int r = 0; r < 4; r++) {
            int q = q0 + kg * 4 + r;
            x1[(((size_t)(b * SS + q)) * NF + f) * C + h * HD + dt * 16 + r16] = o[dt][r] * inv[r];
        }
}

// ---------------- diagonal gather: x_diag[b,s,:] = x1[b,s,s/SL,:] ----------------
__global__ void diag_kernel(const float* __restrict__ x1, float* __restrict__ xd) {
    int i = blockIdx.x * 256 + threadIdx.x;
    int total = BB * SS * (C / 4);
    if (i >= total) return;
    int c4 = i % (C / 4);
    int row = i / (C / 4);
    int s = row % SS;
    int f = s / SL;
    const float4* src = (const float4*)(x1 + (((size_t)row) * NF + f) * C);
    ((float4*)(xd + (size_t)row * C))[c4] = src[c4];
}

// ---------------- temporal attention: one wave per (b, head, s) ----------------
__global__ void attn2_kernel(const float* __restrict__ q2, const float* __restrict__ k2,
                             const float* __restrict__ x1, float* __restrict__ y) {
    int item = blockIdx.x * 4 + (threadIdx.x >> 6);
    if (item >= BB * HEADS * SS) return;
    int lane = threadIdx.x & 63;
    int s = item % SS;
    int bh = item / SS;
    int b = bh / HEADS, hh = bh % HEADS;
    size_t rowbs = (size_t)(b * SS + s);
    float qv = q2[rowbs * C + hh * HD + lane] * 0.125f;
    float lg[NF];
#pragma unroll
    for (int f = 0; f < NF; f++) {
        float p = qv * k2[(rowbs * NF + f) * C + hh * HD + lane];
        for (int off = 32; off; off >>= 1) p += __shfl_xor(p, off);
        lg[f] = p;
    }
    float m = lg[0];
#pragma unroll
    for (int f = 1; f < NF; f++) m = fmaxf(m, lg[f]);
    float sum = 0.f;
#pragma unroll
    for (int f = 0; f < NF; f++) { lg[f] = __expf(lg[f] - m); sum += lg[f]; }
    float inv = 1.f / sum;
    float acc = 0.f;
#pragma unroll
    for (int f = 0; f < NF; f++) acc += lg[f] * x1[(rowbs * NF + f) * C + hh * HD + lane];
    y[((size_t)b * NN + 1 + s) * C + hh * HD + lane] = acc * inv;
}

extern "C" void kernel_launch(void* const* d_in, const int* in_sizes, int n_in,
                              void* d_out, int out_size, void* d_ws, size_t ws_size,
                              hipStream_t stream) {
    const float* x    = (const float*)d_in[0];
    const float* g1   = (const float*)d_in[1];
    const float* b1   = (const float*)d_in[2];
    const float* Wqkv = (const float*)d_in[3];
    const float* Wq   = (const float*)d_in[4];
    const float* Wkv  = (const float*)d_in[5];
    const float* Wp   = (const float*)d_in[6];
    const float* bp   = (const float*)d_in[7];
    const float* g2   = (const float*)d_in[8];
    const float* b2   = (const float*)d_in[9];
    const float* W1   = (const float*)d_in[10];
    const float* bf1  = (const float*)d_in[11];
    const float* W2   = (const float*)d_in[12];
    const float* bf2  = (const float*)d_in[13];
    float* out = (float*)d_out;
    float* ws  = (float*)d_ws;

    // workspace layout (floats)
    float* xn  = ws;                    // B*N*C   (reused as hn after proj)
    float* qkv = xn  + 2409984;         // B*N*3C
    float* x1  = qkv + 7229952;         // B*S*F*C
    float* xd  = x1  + 19267584;        // B*S*C
    float* q2  = xd  + 2408448;         // B*S*C
    float* k2  = q2  + 2408448;         // B*S*F*C
    float* y   = k2  + 19267584;        // B*N*C
    float* a1  = y   + 2409984;         // B*N*HID

    // bf16 repack buffers alias xd+q2 (dead until diag_kernel)
    unsigned short* Qb = (unsigned short*)xd;      // 24*1568*64    = 2,408,448
    unsigned short* Kb = Qb + 2408448;             // 24*8*208*64   = 2,555,904
    unsigned short* Vt = Kb + 2555904;             // 24*8*64*224   = 2,752,512

    const int M1 = BB * NN;       // 3138
    const int M2 = BB * SS;       // 3136
    const int M3 = BB * SS * NF;  // 25088

    // 1. LN1
    ln_kernel<<<M1, 256, 0, stream>>>(x, g1, b1, xn, M1);
    // 2. qkv = xn @ Wqkv
    gemm_kernel<false><<<dim3(2304 / 64, (M1 + 63) / 64), 256, 0, stream>>>(
        xn, Wqkv, nullptr, nullptr, qkv, M1, 2304, 768, 768, 2304);
    // 3. repack q/k/v to bf16 layouts
    repack_q_kernel<<<(24 * SS * 8 + 255) / 256, 256, 0, stream>>>(qkv, Qb);
    repack_k_kernel<<<(24 * NF * 208 * 8 + 255) / 256, 256, 0, stream>>>(qkv, Kb);
    repack_v_kernel<<<(24 * NF * 64 * 28 + 255) / 256, 256, 0, stream>>>(qkv, Vt);
    // 4. cls attention -> y row 0 per batch
    cls_attn_kernel<<<BB * HEADS, 256, 0, stream>>>(qkv, y);
    // 5. MFMA spatial attention -> x1
    space_attn_mfma<<<dim3(SS / 16, NF, 24), 64, 0, stream>>>(Qb, Kb, Vt, x1);
    // 6. diagonal gather (overwrites repack region — repack buffers dead now)
    int tot4 = BB * SS * (C / 4);
    diag_kernel<<<(tot4 + 255) / 256, 256, 0, stream>>>(x1, xd);
    // 7. q2 = x_diag @ Wq
    gemm_kernel<false><<<dim3(768 / 64, (M2 + 63) / 64), 256, 0, stream>>>(
        xd, Wq, nullptr, nullptr, q2, M2, 768, 768, 768, 768);
    // 8. k2 = x1 @ Wkv[:, :C]   (v2 unused by the reference)
    gemm_kernel<false><<<dim3(768 / 64, M3 / 64), 256, 0, stream>>>(
        x1, Wkv, nullptr, nullptr, k2, M3, 768, 768, 768, 1536);
    // 9. temporal attention -> y rows 1..S per batch
    attn2_kernel<<<(BB * HEADS * SS + 3) / 4, 256, 0, stream>>>(q2, k2, x1, y);
    // 10. proj: out = y @ Wp + bp + x
    gemm_kernel<false><<<dim3(768 / 64, (M1 + 63) / 64), 256, 0, stream>>>(
        y, Wp, bp, x, out, M1, 768, 768, 768, 768);
    // 11. LN2
    ln_kernel<<<M1, 256, 0, stream>>>(out, g2, b2, xn, M1);
    // 12. fc1 + exact GELU
    gemm_kernel<true><<<dim3(3072 / 64, (M1 + 63) / 64), 256, 0, stream>>>(
        xn, W1, bf1, nullptr, a1, M1, 3072, 768, 768, 3072);
    // 13. fc2 + residual
    gemm_kernel<false><<<dim3(768 / 64, (M1 + 63) / 64), 256, 0, stream>>>(
        a1, W2, bf2, out, out, M1, 768, 3072, 3072, 768);
}

// Round 3
// 592.462 us; speedup vs baseline: 8.0833x; 3.6305x over previous
//
#include <hip/hip_runtime.h>
#include <math.h>

#define C     768
#define HEADS 12
#define HD    64
#define NF    8
#define SL    196
#define BB    2
#define NN    1569   // 1 + NF*SL
#define SS    1568   // NF*SL
#define HID   3072

typedef __attribute__((ext_vector_type(8))) short short8;
typedef __attribute__((ext_vector_type(4))) float f32x4;
typedef unsigned short u16;

__device__ inline u16 f2b(float f) {
    union { float f; unsigned u; } v; v.f = f;
    unsigned r = (v.u + 0x7FFFu + ((v.u >> 16) & 1u)) >> 16;
    return (u16)r;
}
__device__ inline float b2f(u16 u) {
    union { unsigned u; float f; } v; v.u = ((unsigned)u) << 16;
    return v.f;
}

__device__ inline void gload_lds16(const void* g, void* l) {
    __builtin_amdgcn_global_load_lds(
        (const __attribute__((address_space(1))) void*)g,
        (__attribute__((address_space(3))) void*)l, 16, 0, 0);
}

// ---------------- LayerNorm: f32 in -> bf16 out ----------------
__global__ void ln_kernel(const float* __restrict__ x, const float* __restrict__ g,
                          const float* __restrict__ b, u16* __restrict__ out, int rows) {
    int row = blockIdx.x;
    if (row >= rows) return;
    const float* xr = x + (size_t)row * C;
    int tid = threadIdx.x;
    float v[3];
    float sum = 0.f, sumsq = 0.f;
#pragma unroll
    for (int i = 0; i < 3; i++) {
        v[i] = xr[tid + 256 * i];
        sum += v[i]; sumsq += v[i] * v[i];
    }
    __shared__ float s1[4], s2[4];
    for (int off = 32; off; off >>= 1) {
        sum   += __shfl_xor(sum, off);
        sumsq += __shfl_xor(sumsq, off);
    }
    int wave = tid >> 6, lane = tid & 63;
    if (lane == 0) { s1[wave] = sum; s2[wave] = sumsq; }
    __syncthreads();
    sum   = s1[0] + s1[1] + s1[2] + s1[3];
    sumsq = s2[0] + s2[1] + s2[2] + s2[3];
    float mu  = sum / C;
    float var = sumsq / C - mu * mu;
    float rstd = rsqrtf(fmaxf(var, 0.f) + 1e-5f);
    u16* outr = out + (size_t)row * C;
#pragma unroll
    for (int i = 0; i < 3; i++) {
        int c = tid + 256 * i;
        outr[c] = f2b((v[i] - mu) * rstd * g[c] + b[c]);
    }
}

// ---------------- weight transpose+convert: W[K][ldb] (first N cols) -> Wt[N][K] bf16 ----------
__global__ void wtrans_kernel(const float* __restrict__ W, u16* __restrict__ Wt,
                              int K, int N, int ldb) {
    __shared__ float tile[64][65];
    int nb = blockIdx.x * 64, kb = blockIdx.y * 64;
    int tx = threadIdx.x & 63, ty = threadIdx.x >> 6;
#pragma unroll
    for (int i = 0; i < 64; i += 4)
        tile[ty + i][tx] = W[(size_t)(kb + ty + i) * ldb + nb + tx];
    __syncthreads();
#pragma unroll
    for (int i = 0; i < 64; i += 4)
        Wt[(size_t)(nb + ty + i) * K + kb + tx] = f2b(tile[tx][ty + i]);
}

// ---------------- bf16 MFMA GEMM: C(MxN) = A(MxK) @ Bt(NxK)^T ----------------
// 128x128 tile, BK=32, 256 threads = 4 waves (2x2 of 64x64).
// MODE 0: bf16 out, no bias. MODE 1: bf16 out, bias + exact GELU. MODE 2: f32 out, bias + resid.
template<int MODE>
__global__ __launch_bounds__(256) void gemm_bf16(
    const u16* __restrict__ A, const u16* __restrict__ Bt,
    const float* __restrict__ bias, const float* resid, void* Cout,
    int M, int N, int K) {
    __shared__ char smem[16384];   // As 8KB (128 rows x 64B) + Bs 8KB
    int tid = threadIdx.x, lane = tid & 63, wave = tid >> 6;
    int wr = wave >> 1, wc = wave & 1;
    int r16 = lane & 15, kg = lane >> 4;
    int row0 = blockIdx.y * 128, col0 = blockIdx.x * 128;
    f32x4 acc[4][4];
#pragma unroll
    for (int mt = 0; mt < 4; mt++)
#pragma unroll
        for (int nt = 0; nt < 4; nt++) acc[mt][nt] = (f32x4){0.f, 0.f, 0.f, 0.f};

    int nsteps = K >> 5;
    for (int ks = 0; ks < nsteps; ks++) {
        int k0 = ks << 5;
        // stage A(128x32) + B(128x32) via global_load_lds, linear LDS dest,
        // source pre-swizzled: chunk s holds k-slice (s ^ ((row>>1)&3))
#pragma unroll
        for (int it = 0; it < 4; it++) {
            int c = it * 256 + wave * 64 + lane;
            const u16* src;
            if (c < 512) {
                int ml = c >> 2, s = c & 3;
                int kgs = s ^ ((ml >> 1) & 3);
                int gm = row0 + ml; if (gm >= M) gm = M - 1;
                src = A + (size_t)gm * K + k0 + kgs * 8;
            } else {
                int cc = c - 512;
                int nl = cc >> 2, s = cc & 3;
                int kgs = s ^ ((nl >> 1) & 3);
                src = Bt + (size_t)(col0 + nl) * K + k0 + kgs * 8;
            }
            gload_lds16(src, smem + it * 4096 + wave * 1024);
        }
        __syncthreads();
        short8 af[4], bfr[4];
#pragma unroll
        for (int mt = 0; mt < 4; mt++) {
            int ml = wr * 64 + mt * 16 + r16;
            af[mt] = *(const short8*)(smem + ml * 64 + ((kg ^ ((ml >> 1) & 3)) << 4));
        }
#pragma unroll
        for (int nt = 0; nt < 4; nt++) {
            int nl = wc * 64 + nt * 16 + r16;
            bfr[nt] = *(const short8*)(smem + 8192 + nl * 64 + ((kg ^ ((nl >> 1) & 3)) << 4));
        }
#pragma unroll
        for (int mt = 0; mt < 4; mt++)
#pragma unroll
            for (int nt = 0; nt < 4; nt++)
                acc[mt][nt] = __builtin_amdgcn_mfma_f32_16x16x32_bf16(af[mt], bfr[nt], acc[mt][nt], 0, 0, 0);
        __syncthreads();
    }
    // epilogue: row = kg*4+r within frag, col = r16
#pragma unroll
    for (int mt = 0; mt < 4; mt++) {
#pragma unroll
        for (int r = 0; r < 4; r++) {
            int gm = row0 + wr * 64 + mt * 16 + kg * 4 + r;
            if (gm >= M) continue;
#pragma unroll
            for (int nt = 0; nt < 4; nt++) {
                int gn = col0 + wc * 64 + nt * 16 + r16;
                float v = acc[mt][nt][r];
                if constexpr (MODE == 1) {
                    v += bias[gn];
                    v = 0.5f * v * (1.f + erff(v * 0.70710678118f));
                }
                if constexpr (MODE == 2) {
                    v += bias[gn] + resid[(size_t)gm * N + gn];
                    ((float*)Cout)[(size_t)gm * N + gn] = v;
                } else {
                    ((u16*)Cout)[(size_t)gm * N + gn] = f2b(v);
                }
            }
        }
    }
}

// ---------------- cls-token attention (bf16 qkv) ----------------
__global__ void cls_attn_kernel(const u16* __restrict__ qkv, u16* __restrict__ y) {
    int bh = blockIdx.x;
    int b = bh / HEADS, hh = bh % HEADS;
    int tid = threadIdx.x;
    __shared__ float s_q[HD];
    __shared__ float s_sc[NN];
    __shared__ float swm[4], sws[4];
    if (tid < HD) s_q[tid] = b2f(qkv[(size_t)(b * NN) * 2304 + hh * HD + tid]);
    __syncthreads();
    float pmax = -1e30f;
    for (int j = tid; j < NN; j += 256) {
        const short8* kp = (const short8*)(qkv + ((size_t)(b * NN) + j) * 2304 + C + hh * HD);
        float acc = 0.f;
#pragma unroll
        for (int u = 0; u < 8; u++) {
            short8 kv = kp[u];
#pragma unroll
            for (int e = 0; e < 8; e++) acc += s_q[u * 8 + e] * b2f((u16)kv[e]);
        }
        acc *= 0.125f;
        s_sc[j] = acc;
        pmax = fmaxf(pmax, acc);
    }
    for (int off = 32; off; off >>= 1) pmax = fmaxf(pmax, __shfl_xor(pmax, off));
    int wave = tid >> 6, lane = tid & 63;
    if (lane == 0) swm[wave] = pmax;
    __syncthreads();
    pmax = fmaxf(fmaxf(swm[0], swm[1]), fmaxf(swm[2], swm[3]));
    float psum = 0.f;
    for (int j = tid; j < NN; j += 256) {
        float e = __expf(s_sc[j] - pmax);
        s_sc[j] = e;
        psum += e;
    }
    for (int off = 32; off; off >>= 1) psum += __shfl_xor(psum, off);
    if (lane == 0) sws[wave] = psum;
    __syncthreads();
    psum = sws[0] + sws[1] + sws[2] + sws[3];
    float inv = 1.f / psum;
    if (tid < HD) {
        float acc = 0.f;
        for (int j = 0; j < NN; j++)
            acc += s_sc[j] * b2f(qkv[((size_t)(b * NN) + j) * 2304 + 2 * C + hh * HD + tid]);
        y[(size_t)(b * NN) * C + hh * HD + tid] = f2b(acc * inv);
    }
}

// ---------------- repack K: qkv_b -> Kb[bh][f][208][64], pad rows zeroed ----------------
__global__ void repack_k_kernel(const u16* __restrict__ qkv, u16* __restrict__ Kb) {
    int t = blockIdx.x * 256 + threadIdx.x;
    if (t >= 24 * NF * 208 * 8) return;
    int d8 = t & 7;
    int rest = t >> 3;
    int n = rest % 208;
    rest /= 208;
    int f = rest % NF;
    int bh = rest / NF;
    int b = bh / HEADS, h = bh % HEADS;
    short8 v = {0, 0, 0, 0, 0, 0, 0, 0};
    if (n < SL)
        v = *(const short8*)(qkv + ((size_t)(b * NN) + 1 + f * SL + n) * 2304 + C + h * HD + d8 * 8);
    *(short8*)(Kb + (((size_t)bh * NF + f) * 208 + n) * 64 + d8 * 8) = v;
}

// ---------------- repack V: qkv_b -> Vt[bh][f][d][224] (transposed, pad zeroed) ----------------
__global__ void repack_v_kernel(const u16* __restrict__ qkv, u16* __restrict__ Vt) {
    int t = blockIdx.x * 256 + threadIdx.x;
    if (t >= 24 * NF * 64 * 28) return;
    int n8 = t % 28;
    int rest = t / 28;
    int d = rest % 64;
    rest /= 64;
    int f = rest % NF;
    int bh = rest / NF;
    int b = bh / HEADS, h = bh % HEADS;
    int n0 = n8 * 8;
    const u16* src = qkv + ((size_t)(b * NN) + 1 + f * SL) * 2304 + 2 * C + h * HD + d;
    short8 v;
#pragma unroll
    for (int j = 0; j < 8; j++) {
        int n = n0 + j;
        v[j] = (n < SL) ? (short)src[(size_t)n * 2304] : (short)0;
    }
    *(short8*)(Vt + (((size_t)bh * NF + f) * 64 + d) * 224 + n0) = v;
}

// ---------------- MFMA spatial attention (Q direct from qkv_b, bf16 x1 out) ----------------
__global__ __launch_bounds__(64) void space_attn_mfma(
    const u16* __restrict__ qkv, const u16* __restrict__ Kb,
    const u16* __restrict__ Vt, u16* __restrict__ x1) {
    __shared__ u16 pbuf[16 * 232];
    int lane = threadIdx.x;
    int r16 = lane & 15, kg = lane >> 4;
    int qt = blockIdx.x, f = blockIdx.y, bh = blockIdx.z;
    int q0 = qt * 16;
    int b = bh / HEADS, h = bh % HEADS;

    const u16* qrow = qkv + ((size_t)(b * NN) + 1 + q0 + r16) * 2304 + h * HD + kg * 8;
    short8 aq0 = *(const short8*)(qrow);
    short8 aq1 = *(const short8*)(qrow + 32);

    f32x4 acc[13];
#pragma unroll
    for (int t = 0; t < 13; t++) acc[t] = (f32x4){0.f, 0.f, 0.f, 0.f};
    const u16* kbase = Kb + ((size_t)bh * NF + f) * 208 * 64;
#pragma unroll
    for (int t = 0; t < 13; t++) {
        const u16* krow = kbase + (t * 16 + r16) * 64 + kg * 8;
        short8 bk0 = *(const short8*)(krow);
        short8 bk1 = *(const short8*)(krow + 32);
        acc[t] = __builtin_amdgcn_mfma_f32_16x16x32_bf16(aq0, bk0, acc[t], 0, 0, 0);
        acc[t] = __builtin_amdgcn_mfma_f32_16x16x32_bf16(aq1, bk1, acc[t], 0, 0, 0);
    }

    bool tail_mask = (r16 >= 4);
    float mrow[4] = {-1e30f, -1e30f, -1e30f, -1e30f};
#pragma unroll
    for (int t = 0; t < 13; t++) {
        if (t == 12 && tail_mask) continue;
#pragma unroll
        for (int r = 0; r < 4; r++) mrow[r] = fmaxf(mrow[r], acc[t][r] * 0.125f);
    }
#pragma unroll
    for (int off = 8; off; off >>= 1)
#pragma unroll
        for (int r = 0; r < 4; r++) mrow[r] = fmaxf(mrow[r], __shfl_xor(mrow[r], off));

    float ssum[4] = {0.f, 0.f, 0.f, 0.f};
#pragma unroll
    for (int t = 0; t < 13; t++) {
#pragma unroll
        for (int r = 0; r < 4; r++) {
            float p = (t == 12 && tail_mask) ? 0.f : __expf(acc[t][r] * 0.125f - mrow[r]);
            acc[t][r] = p;
            ssum[r] += p;
        }
    }
#pragma unroll
    for (int off = 8; off; off >>= 1)
#pragma unroll
        for (int r = 0; r < 4; r++) ssum[r] += __shfl_xor(ssum[r], off);
    float inv[4];
#pragma unroll
    for (int r = 0; r < 4; r++) inv[r] = 1.f / ssum[r];

#pragma unroll
    for (int t = 0; t < 13; t++)
#pragma unroll
        for (int r = 0; r < 4; r++)
            pbuf[(kg * 4 + r) * 232 + t * 16 + r16] = f2b(acc[t][r]);
    {
        int zr = lane >> 2, zc = 208 + (lane & 3) * 4;
        *(uint2*)(&pbuf[zr * 232 + zc]) = (uint2){0u, 0u};
    }

    f32x4 o[4];
#pragma unroll
    for (int dt = 0; dt < 4; dt++) o[dt] = (f32x4){0.f, 0.f, 0.f, 0.f};
    const u16* vbase = Vt + ((size_t)bh * NF + f) * 64 * 224;
#pragma unroll
    for (int kc = 0; kc < 7; kc++) {
        short8 pa = *(const short8*)(&pbuf[r16 * 232 + kc * 32 + kg * 8]);
#pragma unroll
        for (int dt = 0; dt < 4; dt++) {
            short8 bv = *(const short8*)(vbase + (dt * 16 + r16) * 224 + kc * 32 + kg * 8);
            o[dt] = __builtin_amdgcn_mfma_f32_16x16x32_bf16(pa, bv, o[dt], 0, 0, 0);
        }
    }

#pragma unroll
    for (int dt = 0; dt < 4; dt++)
#pragma unroll
        for (int r = 0; r < 4; r++) {
            int q = q0 + kg * 4 + r;
            x1[(((size_t)(b * SS + q)) * NF + f) * C + h * HD + dt * 16 + r16] = f2b(o[dt][r] * inv[r]);
        }
}

// ---------------- diagonal gather (bf16): xd[b,s,:] = x1[b,s,s/SL,:] ----------------
__global__ void diag_kernel(const u16* __restrict__ x1, u16* __restrict__ xd) {
    int i = blockIdx.x * 256 + threadIdx.x;
    int total = BB * SS * (C / 8);
    if (i >= total) return;
    int c8 = i % (C / 8);
    int row = i / (C / 8);
    int s = row % SS;
    int f = s / SL;
    ((short8*)(xd + (size_t)row * C))[c8] =
        ((const short8*)(x1 + (((size_t)row) * NF + f) * C))[c8];
}

// ---------------- temporal attention (bf16 in, bf16 out) ----------------
__global__ void attn2_kernel(const u16* __restrict__ q2, const u16* __restrict__ k2,
                             const u16* __restrict__ x1, u16* __restrict__ y) {
    int item = blockIdx.x * 4 + (threadIdx.x >> 6);
    if (item >= BB * HEADS * SS) return;
    int lane = threadIdx.x & 63;
    int s = item % SS;
    int bh = item / SS;
    int b = bh / HEADS, hh = bh % HEADS;
    size_t rowbs = (size_t)(b * SS + s);
    float qv = b2f(q2[rowbs * C + hh * HD + lane]) * 0.125f;
    float lg[NF];
#pragma unroll
    for (int f = 0; f < NF; f++) {
        float p = qv * b2f(k2[(rowbs * NF + f) * C + hh * HD + lane]);
        for (int off = 32; off; off >>= 1) p += __shfl_xor(p, off);
        lg[f] = p;
    }
    float m = lg[0];
#pragma unroll
    for (int f = 1; f < NF; f++) m = fmaxf(m, lg[f]);
    float sum = 0.f;
#pragma unroll
    for (int f = 0; f < NF; f++) { lg[f] = __expf(lg[f] - m); sum += lg[f]; }
    float inv = 1.f / sum;
    float acc = 0.f;
#pragma unroll
    for (int f = 0; f < NF; f++) acc += lg[f] * b2f(x1[(rowbs * NF + f) * C + hh * HD + lane]);
    y[((size_t)(b * NN) + 1 + s) * C + hh * HD + lane] = f2b(acc * inv);
}

extern "C" void kernel_launch(void* const* d_in, const int* in_sizes, int n_in,
                              void* d_out, int out_size, void* d_ws, size_t ws_size,
                              hipStream_t stream) {
    const float* x    = (const float*)d_in[0];
    const float* g1   = (const float*)d_in[1];
    const float* b1   = (const float*)d_in[2];
    const float* Wqkv = (const float*)d_in[3];
    const float* Wq   = (const float*)d_in[4];
    const float* Wkv  = (const float*)d_in[5];
    const float* Wp   = (const float*)d_in[6];
    const float* bp   = (const float*)d_in[7];
    const float* g2   = (const float*)d_in[8];
    const float* b2_  = (const float*)d_in[9];
    const float* W1   = (const float*)d_in[10];
    const float* bf1  = (const float*)d_in[11];
    const float* W2   = (const float*)d_in[12];
    const float* bf2  = (const float*)d_in[13];
    float* out = (float*)d_out;

    // workspace layout (u16 elements)
    u16* us     = (u16*)d_ws;
    u16* xn_b   = us;                    // M1*768    (reused as hn after LN2)
    u16* qkv_b  = xn_b   + 2409984;      // M1*2304
    u16* Wt_qkv = qkv_b  + 7229952;      // 2304*768
    u16* Wt_q   = Wt_qkv + 1769472;      // 768*768
    u16* Wt_kv  = Wt_q   + 589824;       // 768*768 (first half of Wkv)
    u16* Wt_p   = Wt_kv  + 589824;       // 768*768
    u16* W1t    = Wt_p   + 589824;       // 3072*768
    u16* W2t    = W1t    + 2359296;      // 768*3072
    u16* Kb     = W2t    + 2359296;      // 24*8*208*64
    u16* Vt     = Kb     + 2555904;      // 24*8*64*224
    u16* x1b    = Vt     + 2752512;      // B*S*F*C
    u16* xdb    = x1b    + 19267584;     // B*S*C
    u16* q2b    = xdb    + 2408448;      // B*S*C
    u16* k2b    = q2b    + 2408448;      // B*S*F*C
    u16* y_b    = k2b    + 19267584;     // B*N*C
    u16* a1b    = y_b    + 2409984;      // B*N*HID

    const int M1 = BB * NN;       // 3138
    const int M2 = BB * SS;       // 3136
    const int M3 = BB * SS * NF;  // 25088

    // 0. weight transpose + bf16 convert
    wtrans_kernel<<<dim3(2304 / 64, 768 / 64), 256, 0, stream>>>(Wqkv, Wt_qkv, 768, 2304, 2304);
    wtrans_kernel<<<dim3(768 / 64, 768 / 64), 256, 0, stream>>>(Wq, Wt_q, 768, 768, 768);
    wtrans_kernel<<<dim3(768 / 64, 768 / 64), 256, 0, stream>>>(Wkv, Wt_kv, 768, 768, 1536);
    wtrans_kernel<<<dim3(768 / 64, 768 / 64), 256, 0, stream>>>(Wp, Wt_p, 768, 768, 768);
    wtrans_kernel<<<dim3(3072 / 64, 768 / 64), 256, 0, stream>>>(W1, W1t, 768, 3072, 3072);
    wtrans_kernel<<<dim3(768 / 64, 3072 / 64), 256, 0, stream>>>(W2, W2t, 3072, 768, 768);
    // 1. LN1 -> bf16
    ln_kernel<<<M1, 256, 0, stream>>>(x, g1, b1, xn_b, M1);
    // 2. qkv_b = xn_b @ Wqkv (bf16 out)
    gemm_bf16<0><<<dim3(2304 / 128, (M1 + 127) / 128), 256, 0, stream>>>(
        xn_b, Wt_qkv, nullptr, nullptr, qkv_b, M1, 2304, 768);
    // 3. repack K, V
    repack_k_kernel<<<(24 * NF * 208 * 8 + 255) / 256, 256, 0, stream>>>(qkv_b, Kb);
    repack_v_kernel<<<(24 * NF * 64 * 28 + 255) / 256, 256, 0, stream>>>(qkv_b, Vt);
    // 4. cls attention -> y_b row 0
    cls_attn_kernel<<<BB * HEADS, 256, 0, stream>>>(qkv_b, y_b);
    // 5. spatial attention -> x1b
    space_attn_mfma<<<dim3(SS / 16, NF, 24), 64, 0, stream>>>(qkv_b, Kb, Vt, x1b);
    // 6. diag gather
    diag_kernel<<<(BB * SS * (C / 8) + 255) / 256, 256, 0, stream>>>(x1b, xdb);
    // 7. q2 = xd @ Wq
    gemm_bf16<0><<<dim3(768 / 128, (M2 + 127) / 128), 256, 0, stream>>>(
        xdb, Wt_q, nullptr, nullptr, q2b, M2, 768, 768);
    // 8. k2 = x1 @ Wkv[:, :C]
    gemm_bf16<0><<<dim3(768 / 128, M3 / 128), 256, 0, stream>>>(
        x1b, Wt_kv, nullptr, nullptr, k2b, M3, 768, 768);
    // 9. temporal attention -> y_b rows 1..S
    attn2_kernel<<<(BB * HEADS * SS + 3) / 4, 256, 0, stream>>>(q2b, k2b, x1b, y_b);
    // 10. proj: out = y_b @ Wp + bp + x  (f32)
    gemm_bf16<2><<<dim3(768 / 128, (M1 + 127) / 128), 256, 0, stream>>>(
        y_b, Wt_p, bp, x, out, M1, 768, 768);
    // 11. LN2 -> bf16 (reuse xn_b)
    ln_kernel<<<M1, 256, 0, stream>>>(out, g2, b2_, xn_b, M1);
    // 12. fc1 + exact GELU -> bf16
    gemm_bf16<1><<<dim3(3072 / 128, (M1 + 127) / 128), 256, 0, stream>>>(
        xn_b, W1t, bf1, nullptr, a1b, M1, 3072, 768);
    // 13. fc2 + bias + residual (f32, in-place on d_out)
    gemm_bf16<2><<<dim3(768 / 128, (M1 + 127) / 128), 256, 0, stream>>>(
        a1b, W2t, bf2, out, out, M1, 768, 3072);
}

// Round 4
// 536.672 us; speedup vs baseline: 8.9236x; 1.1040x over previous
//
#include <hip/hip_runtime.h>
#include <math.h>

#define C     768
#define HEADS 12
#define HD    64
#define NF    8
#define SL    196
#define BB    2
#define NN    1569   // 1 + NF*SL
#define SS    1568   // NF*SL
#define HID   3072

typedef __attribute__((ext_vector_type(8))) short short8;
typedef __attribute__((ext_vector_type(4))) float f32x4;
typedef unsigned short u16;

__device__ inline u16 f2b(float f) {
    union { float f; unsigned u; } v; v.f = f;
    unsigned r = (v.u + 0x7FFFu + ((v.u >> 16) & 1u)) >> 16;
    return (u16)r;
}
__device__ inline float b2f(u16 u) {
    union { unsigned u; float f; } v; v.u = ((unsigned)u) << 16;
    return v.f;
}

__device__ inline void gload_lds16(const void* g, void* l) {
    __builtin_amdgcn_global_load_lds(
        (const __attribute__((address_space(1))) void*)g,
        (__attribute__((address_space(3))) void*)l, 16, 0, 0);
}

// ---------------- LayerNorm: f32 in -> bf16 out ----------------
__global__ void ln_kernel(const float* __restrict__ x, const float* __restrict__ g,
                          const float* __restrict__ b, u16* __restrict__ out, int rows) {
    int row = blockIdx.x;
    if (row >= rows) return;
    const float* xr = x + (size_t)row * C;
    int tid = threadIdx.x;
    float v[3];
    float sum = 0.f, sumsq = 0.f;
#pragma unroll
    for (int i = 0; i < 3; i++) {
        v[i] = xr[tid + 256 * i];
        sum += v[i]; sumsq += v[i] * v[i];
    }
    __shared__ float s1[4], s2[4];
    for (int off = 32; off; off >>= 1) {
        sum   += __shfl_xor(sum, off);
        sumsq += __shfl_xor(sumsq, off);
    }
    int wave = tid >> 6, lane = tid & 63;
    if (lane == 0) { s1[wave] = sum; s2[wave] = sumsq; }
    __syncthreads();
    sum   = s1[0] + s1[1] + s1[2] + s1[3];
    sumsq = s2[0] + s2[1] + s2[2] + s2[3];
    float mu  = sum / C;
    float var = sumsq / C - mu * mu;
    float rstd = rsqrtf(fmaxf(var, 0.f) + 1e-5f);
    u16* outr = out + (size_t)row * C;
#pragma unroll
    for (int i = 0; i < 3; i++) {
        int c = tid + 256 * i;
        outr[c] = f2b((v[i] - mu) * rstd * g[c] + b[c]);
    }
}

// ---------------- weight transpose+convert: W[K][ldb] (first N cols) -> Wt[N][K] bf16 ----------
__global__ void wtrans_kernel(const float* __restrict__ W, u16* __restrict__ Wt,
                              int K, int N, int ldb) {
    __shared__ float tile[64][65];
    int nb = blockIdx.x * 64, kb = blockIdx.y * 64;
    int tx = threadIdx.x & 63, ty = threadIdx.x >> 6;
#pragma unroll
    for (int i = 0; i < 64; i += 4)
        tile[ty + i][tx] = W[(size_t)(kb + ty + i) * ldb + nb + tx];
    __syncthreads();
#pragma unroll
    for (int i = 0; i < 64; i += 4)
        Wt[(size_t)(nb + ty + i) * K + kb + tx] = f2b(tile[tx][ty + i]);
}

// ---------------- bf16 MFMA GEMM: C(MxN) = A(MxK) @ Bt(NxK)^T ----------------
// 128x128 tile, BK=32, 256 threads = 4 waves (2x2 of 64x64).
// MODE 0: bf16 out, no bias. MODE 1: bf16 out, bias + exact GELU. MODE 2: f32 out, bias + resid.
template<int MODE>
__global__ __launch_bounds__(256) void gemm_bf16(
    const u16* __restrict__ A, const u16* __restrict__ Bt,
    const float* __restrict__ bias, const float* resid, void* Cout,
    int M, int N, int K) {
    __shared__ char smem[16384];   // As 8KB (128 rows x 64B) + Bs 8KB
    int tid = threadIdx.x, lane = tid & 63, wave = tid >> 6;
    int wr = wave >> 1, wc = wave & 1;
    int r16 = lane & 15, kg = lane >> 4;
    int row0 = blockIdx.y * 128, col0 = blockIdx.x * 128;
    f32x4 acc[4][4];
#pragma unroll
    for (int mt = 0; mt < 4; mt++)
#pragma unroll
        for (int nt = 0; nt < 4; nt++) acc[mt][nt] = (f32x4){0.f, 0.f, 0.f, 0.f};

    int nsteps = K >> 5;
    for (int ks = 0; ks < nsteps; ks++) {
        int k0 = ks << 5;
#pragma unroll
        for (int it = 0; it < 4; it++) {
            int c = it * 256 + wave * 64 + lane;
            const u16* src;
            if (c < 512) {
                int ml = c >> 2, s = c & 3;
                int kgs = s ^ ((ml >> 1) & 3);
                int gm = row0 + ml; if (gm >= M) gm = M - 1;
                src = A + (size_t)gm * K + k0 + kgs * 8;
            } else {
                int cc = c - 512;
                int nl = cc >> 2, s = cc & 3;
                int kgs = s ^ ((nl >> 1) & 3);
                src = Bt + (size_t)(col0 + nl) * K + k0 + kgs * 8;
            }
            gload_lds16(src, smem + it * 4096 + wave * 1024);
        }
        __syncthreads();
        short8 af[4], bfr[4];
#pragma unroll
        for (int mt = 0; mt < 4; mt++) {
            int ml = wr * 64 + mt * 16 + r16;
            af[mt] = *(const short8*)(smem + ml * 64 + ((kg ^ ((ml >> 1) & 3)) << 4));
        }
#pragma unroll
        for (int nt = 0; nt < 4; nt++) {
            int nl = wc * 64 + nt * 16 + r16;
            bfr[nt] = *(const short8*)(smem + 8192 + nl * 64 + ((kg ^ ((nl >> 1) & 3)) << 4));
        }
#pragma unroll
        for (int mt = 0; mt < 4; mt++)
#pragma unroll
            for (int nt = 0; nt < 4; nt++)
                acc[mt][nt] = __builtin_amdgcn_mfma_f32_16x16x32_bf16(af[mt], bfr[nt], acc[mt][nt], 0, 0, 0);
        __syncthreads();
    }
#pragma unroll
    for (int mt = 0; mt < 4; mt++) {
#pragma unroll
        for (int r = 0; r < 4; r++) {
            int gm = row0 + wr * 64 + mt * 16 + kg * 4 + r;
            if (gm >= M) continue;
#pragma unroll
            for (int nt = 0; nt < 4; nt++) {
                int gn = col0 + wc * 64 + nt * 16 + r16;
                float v = acc[mt][nt][r];
                if constexpr (MODE == 1) {
                    v += bias[gn];
                    v = 0.5f * v * (1.f + erff(v * 0.70710678118f));
                }
                if constexpr (MODE == 2) {
                    v += bias[gn] + resid[(size_t)gm * N + gn];
                    ((float*)Cout)[(size_t)gm * N + gn] = v;
                } else {
                    ((u16*)Cout)[(size_t)gm * N + gn] = f2b(v);
                }
            }
        }
    }
}

// ---------------- cls-token attention (bf16 qkv), fully parallel PV ----------------
__global__ void cls_attn_kernel(const u16* __restrict__ qkv, u16* __restrict__ y) {
    int bh = blockIdx.x;
    int b = bh / HEADS, hh = bh % HEADS;
    int tid = threadIdx.x;
    __shared__ float s_q[HD];
    __shared__ float s_sc[NN];
    __shared__ float swm[4], sws[4];
    __shared__ float sacc[4][HD];
    if (tid < HD) s_q[tid] = b2f(qkv[(size_t)(b * NN) * 2304 + hh * HD + tid]);
    __syncthreads();
    float pmax = -1e30f;
    for (int j = tid; j < NN; j += 256) {
        const short8* kp = (const short8*)(qkv + ((size_t)(b * NN) + j) * 2304 + C + hh * HD);
        float acc = 0.f;
#pragma unroll
        for (int u = 0; u < 8; u++) {
            short8 kv = kp[u];
#pragma unroll
            for (int e = 0; e < 8; e++) acc += s_q[u * 8 + e] * b2f((u16)kv[e]);
        }
        acc *= 0.125f;
        s_sc[j] = acc;
        pmax = fmaxf(pmax, acc);
    }
    for (int off = 32; off; off >>= 1) pmax = fmaxf(pmax, __shfl_xor(pmax, off));
    int wave = tid >> 6, lane = tid & 63;
    if (lane == 0) swm[wave] = pmax;
    __syncthreads();
    pmax = fmaxf(fmaxf(swm[0], swm[1]), fmaxf(swm[2], swm[3]));
    float psum = 0.f;
    for (int j = tid; j < NN; j += 256) {
        float e = __expf(s_sc[j] - pmax);
        s_sc[j] = e;
        psum += e;
    }
    for (int off = 32; off; off >>= 1) psum += __shfl_xor(psum, off);
    if (lane == 0) sws[wave] = psum;
    __syncthreads();
    psum = sws[0] + sws[1] + sws[2] + sws[3];
    float inv = 1.f / psum;
    // PV: thread (jj = tid>>6, d = tid&63); wave reads 128B contiguous per j
    int jj = tid >> 6, d = tid & 63;
    const u16* vcol = qkv + (size_t)(b * NN) * 2304 + 2 * C + hh * HD + d;
    float acc = 0.f;
    for (int j = jj; j < NN; j += 4)
        acc += s_sc[j] * b2f(vcol[(size_t)j * 2304]);
    sacc[jj][d] = acc;
    __syncthreads();
    if (tid < HD) {
        float tot = (sacc[0][tid] + sacc[1][tid] + sacc[2][tid] + sacc[3][tid]) * inv;
        y[(size_t)(b * NN) * C + hh * HD + tid] = f2b(tot);
    }
}

// ---------------- repack K: qkv_b -> Kb[bh][f][208][64], pad rows zeroed ----------------
__global__ void repack_k_kernel(const u16* __restrict__ qkv, u16* __restrict__ Kb) {
    int t = blockIdx.x * 256 + threadIdx.x;
    if (t >= 24 * NF * 208 * 8) return;
    int d8 = t & 7;
    int rest = t >> 3;
    int n = rest % 208;
    rest /= 208;
    int f = rest % NF;
    int bh = rest / NF;
    int b = bh / HEADS, h = bh % HEADS;
    short8 v = {0, 0, 0, 0, 0, 0, 0, 0};
    if (n < SL)
        v = *(const short8*)(qkv + ((size_t)(b * NN) + 1 + f * SL + n) * 2304 + C + h * HD + d8 * 8);
    *(short8*)(Kb + (((size_t)bh * NF + f) * 208 + n) * 64 + d8 * 8) = v;
}

// ---------------- repack V: qkv_b -> Vt[bh][f][d][224] (transposed, pad zeroed) ----------------
__global__ void repack_v_kernel(const u16* __restrict__ qkv, u16* __restrict__ Vt) {
    int t = blockIdx.x * 256 + threadIdx.x;
    if (t >= 24 * NF * 64 * 28) return;
    int n8 = t % 28;
    int rest = t / 28;
    int d = rest % 64;
    rest /= 64;
    int f = rest % NF;
    int bh = rest / NF;
    int b = bh / HEADS, h = bh % HEADS;
    int n0 = n8 * 8;
    const u16* src = qkv + ((size_t)(b * NN) + 1 + f * SL) * 2304 + 2 * C + h * HD + d;
    short8 v;
#pragma unroll
    for (int j = 0; j < 8; j++) {
        int n = n0 + j;
        v[j] = (n < SL) ? (short)src[(size_t)n * 2304] : (short)0;
    }
    *(short8*)(Vt + (((size_t)bh * NF + f) * 64 + d) * 224 + n0) = v;
}

// ---------------- MFMA spatial attention (Q direct from qkv_b, bf16 x1 out) ----------------
__global__ __launch_bounds__(64) void space_attn_mfma(
    const u16* __restrict__ qkv, const u16* __restrict__ Kb,
    const u16* __restrict__ Vt, u16* __restrict__ x1) {
    __shared__ u16 pbuf[16 * 232];
    int lane = threadIdx.x;
    int r16 = lane & 15, kg = lane >> 4;
    int qt = blockIdx.x, f = blockIdx.y, bh = blockIdx.z;
    int q0 = qt * 16;
    int b = bh / HEADS, h = bh % HEADS;

    const u16* qrow = qkv + ((size_t)(b * NN) + 1 + q0 + r16) * 2304 + h * HD + kg * 8;
    short8 aq0 = *(const short8*)(qrow);
    short8 aq1 = *(const short8*)(qrow + 32);

    f32x4 acc[13];
#pragma unroll
    for (int t = 0; t < 13; t++) acc[t] = (f32x4){0.f, 0.f, 0.f, 0.f};
    const u16* kbase = Kb + ((size_t)bh * NF + f) * 208 * 64;
#pragma unroll
    for (int t = 0; t < 13; t++) {
        const u16* krow = kbase + (t * 16 + r16) * 64 + kg * 8;
        short8 bk0 = *(const short8*)(krow);
        short8 bk1 = *(const short8*)(krow + 32);
        acc[t] = __builtin_amdgcn_mfma_f32_16x16x32_bf16(aq0, bk0, acc[t], 0, 0, 0);
        acc[t] = __builtin_amdgcn_mfma_f32_16x16x32_bf16(aq1, bk1, acc[t], 0, 0, 0);
    }

    bool tail_mask = (r16 >= 4);
    float mrow[4] = {-1e30f, -1e30f, -1e30f, -1e30f};
#pragma unroll
    for (int t = 0; t < 13; t++) {
        if (t == 12 && tail_mask) continue;
#pragma unroll
        for (int r = 0; r < 4; r++) mrow[r] = fmaxf(mrow[r], acc[t][r] * 0.125f);
    }
#pragma unroll
    for (int off = 8; off; off >>= 1)
#pragma unroll
        for (int r = 0; r < 4; r++) mrow[r] = fmaxf(mrow[r], __shfl_xor(mrow[r], off));

    float ssum[4] = {0.f, 0.f, 0.f, 0.f};
#pragma unroll
    for (int t = 0; t < 13; t++) {
#pragma unroll
        for (int r = 0; r < 4; r++) {
            float p = (t == 12 && tail_mask) ? 0.f : __expf(acc[t][r] * 0.125f - mrow[r]);
            acc[t][r] = p;
            ssum[r] += p;
        }
    }
#pragma unroll
    for (int off = 8; off; off >>= 1)
#pragma unroll
        for (int r = 0; r < 4; r++) ssum[r] += __shfl_xor(ssum[r], off);
    float inv[4];
#pragma unroll
    for (int r = 0; r < 4; r++) inv[r] = 1.f / ssum[r];

#pragma unroll
    for (int t = 0; t < 13; t++)
#pragma unroll
        for (int r = 0; r < 4; r++)
            pbuf[(kg * 4 + r) * 232 + t * 16 + r16] = f2b(acc[t][r]);
    {
        int zr = lane >> 2, zc = 208 + (lane & 3) * 4;
        *(uint2*)(&pbuf[zr * 232 + zc]) = (uint2){0u, 0u};
    }

    f32x4 o[4];
#pragma unroll
    for (int dt = 0; dt < 4; dt++) o[dt] = (f32x4){0.f, 0.f, 0.f, 0.f};
    const u16* vbase = Vt + ((size_t)bh * NF + f) * 64 * 224;
#pragma unroll
    for (int kc = 0; kc < 7; kc++) {
        short8 pa = *(const short8*)(&pbuf[r16 * 232 + kc * 32 + kg * 8]);
#pragma unroll
        for (int dt = 0; dt < 4; dt++) {
            short8 bv = *(const short8*)(vbase + (dt * 16 + r16) * 224 + kc * 32 + kg * 8);
            o[dt] = __builtin_amdgcn_mfma_f32_16x16x32_bf16(pa, bv, o[dt], 0, 0, 0);
        }
    }

#pragma unroll
    for (int dt = 0; dt < 4; dt++)
#pragma unroll
        for (int r = 0; r < 4; r++) {
            int q = q0 + kg * 4 + r;
            x1[(((size_t)(b * SS + q)) * NF + f) * C + h * HD + dt * 16 + r16] = f2b(o[dt][r] * inv[r]);
        }
}

// ---------------- diagonal gather (bf16): xd[b,s,:] = x1[b,s,s/SL,:] ----------------
__global__ void diag_kernel(const u16* __restrict__ x1, u16* __restrict__ xd) {
    int i = blockIdx.x * 256 + threadIdx.x;
    int total = BB * SS * (C / 8);
    if (i >= total) return;
    int c8 = i % (C / 8);
    int row = i / (C / 8);
    int s = row % SS;
    int f = s / SL;
    ((short8*)(xd + (size_t)row * C))[c8] =
        ((const short8*)(x1 + (((size_t)row) * NF + f) * C))[c8];
}

// ---------------- temporal attention (bf16 in, bf16 out) ----------------
__global__ void attn2_kernel(const u16* __restrict__ q2, const u16* __restrict__ k2,
                             const u16* __restrict__ x1, u16* __restrict__ y) {
    int item = blockIdx.x * 4 + (threadIdx.x >> 6);
    if (item >= BB * HEADS * SS) return;
    int lane = threadIdx.x & 63;
    int s = item % SS;
    int bh = item / SS;
    int b = bh / HEADS, hh = bh % HEADS;
    size_t rowbs = (size_t)(b * SS + s);
    float qv = b2f(q2[rowbs * C + hh * HD + lane]) * 0.125f;
    float lg[NF];
#pragma unroll
    for (int f = 0; f < NF; f++) {
        float p = qv * b2f(k2[(rowbs * NF + f) * C + hh * HD + lane]);
        for (int off = 32; off; off >>= 1) p += __shfl_xor(p, off);
        lg[f] = p;
    }
    float m = lg[0];
#pragma unroll
    for (int f = 1; f < NF; f++) m = fmaxf(m, lg[f]);
    float sum = 0.f;
#pragma unroll
    for (int f = 0; f < NF; f++) { lg[f] = __expf(lg[f] - m); sum += lg[f]; }
    float inv = 1.f / sum;
    float acc = 0.f;
#pragma unroll
    for (int f = 0; f < NF; f++) acc += lg[f] * b2f(x1[(rowbs * NF + f) * C + hh * HD + lane]);
    y[((size_t)(b * NN) + 1 + s) * C + hh * HD + lane] = f2b(acc * inv);
}

extern "C" void kernel_launch(void* const* d_in, const int* in_sizes, int n_in,
                              void* d_out, int out_size, void* d_ws, size_t ws_size,
                              hipStream_t stream) {
    const float* x    = (const float*)d_in[0];
    const float* g1   = (const float*)d_in[1];
    const float* b1   = (const float*)d_in[2];
    const float* Wqkv = (const float*)d_in[3];
    const float* Wq   = (const float*)d_in[4];
    const float* Wkv  = (const float*)d_in[5];
    const float* Wp   = (const float*)d_in[6];
    const float* bp   = (const float*)d_in[7];
    const float* g2   = (const float*)d_in[8];
    const float* b2_  = (const float*)d_in[9];
    const float* W1   = (const float*)d_in[10];
    const float* bf1  = (const float*)d_in[11];
    const float* W2   = (const float*)d_in[12];
    const float* bf2  = (const float*)d_in[13];
    float* out = (float*)d_out;

    // workspace layout (u16 elements)
    u16* us     = (u16*)d_ws;
    u16* xn_b   = us;                    // M1*768    (reused as hn after LN2)
    u16* qkv_b  = xn_b   + 2409984;      // M1*2304
    u16* Wt_qkv = qkv_b  + 7229952;      // 2304*768
    u16* Wt_q   = Wt_qkv + 1769472;      // 768*768
    u16* Wt_kv  = Wt_q   + 589824;       // 768*768 (first half of Wkv)
    u16* Wt_p   = Wt_kv  + 589824;       // 768*768
    u16* W1t    = Wt_p   + 589824;       // 3072*768
    u16* W2t    = W1t    + 2359296;      // 768*3072
    u16* Kb     = W2t    + 2359296;      // 24*8*208*64
    u16* Vt     = Kb     + 2555904;      // 24*8*64*224
    u16* x1b    = Vt     + 2752512;      // B*S*F*C
    u16* xdb    = x1b    + 19267584;     // B*S*C
    u16* q2b    = xdb    + 2408448;      // B*S*C
    u16* k2b    = q2b    + 2408448;      // B*S*F*C
    u16* y_b    = k2b    + 19267584;     // B*N*C
    u16* a1b    = y_b    + 2409984;      // B*N*HID

    const int M1 = BB * NN;       // 3138
    const int M2 = BB * SS;       // 3136
    const int M3 = BB * SS * NF;  // 25088

    // 0. weight transpose + bf16 convert
    wtrans_kernel<<<dim3(2304 / 64, 768 / 64), 256, 0, stream>>>(Wqkv, Wt_qkv, 768, 2304, 2304);
    wtrans_kernel<<<dim3(768 / 64, 768 / 64), 256, 0, stream>>>(Wq, Wt_q, 768, 768, 768);
    wtrans_kernel<<<dim3(768 / 64, 768 / 64), 256, 0, stream>>>(Wkv, Wt_kv, 768, 768, 1536);
    wtrans_kernel<<<dim3(768 / 64, 768 / 64), 256, 0, stream>>>(Wp, Wt_p, 768, 768, 768);
    wtrans_kernel<<<dim3(3072 / 64, 768 / 64), 256, 0, stream>>>(W1, W1t, 768, 3072, 3072);
    wtrans_kernel<<<dim3(768 / 64, 3072 / 64), 256, 0, stream>>>(W2, W2t, 3072, 768, 768);
    // 1. LN1 -> bf16
    ln_kernel<<<M1, 256, 0, stream>>>(x, g1, b1, xn_b, M1);
    // 2. qkv_b = xn_b @ Wqkv (bf16 out)
    gemm_bf16<0><<<dim3(2304 / 128, (M1 + 127) / 128), 256, 0, stream>>>(
        xn_b, Wt_qkv, nullptr, nullptr, qkv_b, M1, 2304, 768);
    // 3. repack K, V
    repack_k_kernel<<<(24 * NF * 208 * 8 + 255) / 256, 256, 0, stream>>>(qkv_b, Kb);
    repack_v_kernel<<<(24 * NF * 64 * 28 + 255) / 256, 256, 0, stream>>>(qkv_b, Vt);
    // 4. cls attention -> y_b row 0
    cls_attn_kernel<<<BB * HEADS, 256, 0, stream>>>(qkv_b, y_b);
    // 5. spatial attention -> x1b
    space_attn_mfma<<<dim3(SS / 16, NF, 24), 64, 0, stream>>>(qkv_b, Kb, Vt, x1b);
    // 6. diag gather
    diag_kernel<<<(BB * SS * (C / 8) + 255) / 256, 256, 0, stream>>>(x1b, xdb);
    // 7. q2 = xd @ Wq
    gemm_bf16<0><<<dim3(768 / 128, (M2 + 127) / 128), 256, 0, stream>>>(
        xdb, Wt_q, nullptr, nullptr, q2b, M2, 768, 768);
    // 8. k2 = x1 @ Wkv[:, :C]
    gemm_bf16<0><<<dim3(768 / 128, M3 / 128), 256, 0, stream>>>(
        x1b, Wt_kv, nullptr, nullptr, k2b, M3, 768, 768);
    // 9. temporal attention -> y_b rows 1..S
    attn2_kernel<<<(BB * HEADS * SS + 3) / 4, 256, 0, stream>>>(q2b, k2b, x1b, y_b);
    // 10. proj: out = y_b @ Wp + bp + x  (f32)
    gemm_bf16<2><<<dim3(768 / 128, (M1 + 127) / 128), 256, 0, stream>>>(
        y_b, Wt_p, bp, x, out, M1, 768, 768);
    // 11. LN2 -> bf16 (reuse xn_b)
    ln_kernel<<<M1, 256, 0, stream>>>(out, g2, b2_, xn_b, M1);
    // 12. fc1 + exact GELU -> bf16
    gemm_bf16<1><<<dim3(3072 / 128, (M1 + 127) / 128), 256, 0, stream>>>(
        xn_b, W1t, bf1, nullptr, a1b, M1, 3072, 768);
    // 13. fc2 + bias + residual (f32, in-place on d_out)
    gemm_bf16<2><<<dim3(768 / 128, (M1 + 127) / 128), 256, 0, stream>>>(
        a1b, W2t, bf2, out, out, M1, 768, 3072);
}

// Round 5
// 498.057 us; speedup vs baseline: 9.6155x; 1.0775x over previous
//
#include <hip/hip_runtime.h>
#include <math.h>

#define C     768
#define HEADS 12
#define HD    64
#define NF    8
#define SL    196
#define BB    2
#define NN    1569   // 1 + NF*SL
#define SS    1568   // NF*SL
#define HID   3072

typedef __attribute__((ext_vector_type(8))) short short8;
typedef __attribute__((ext_vector_type(4))) float f32x4;
typedef unsigned short u16;

__device__ inline u16 f2b(float f) {
    union { float f; unsigned u; } v; v.f = f;
    unsigned r = (v.u + 0x7FFFu + ((v.u >> 16) & 1u)) >> 16;
    return (u16)r;
}
__device__ inline float b2f(u16 u) {
    union { unsigned u; float f; } v; v.u = ((unsigned)u) << 16;
    return v.f;
}

__device__ inline void gload_lds16(const void* g, void* l) {
    __builtin_amdgcn_global_load_lds(
        (const __attribute__((address_space(1))) void*)g,
        (__attribute__((address_space(3))) void*)l, 16, 0, 0);
}

// ---------------- LayerNorm: f32 in -> bf16 out ----------------
__global__ void ln_kernel(const float* __restrict__ x, const float* __restrict__ g,
                          const float* __restrict__ b, u16* __restrict__ out, int rows) {
    int row = blockIdx.x;
    if (row >= rows) return;
    const float* xr = x + (size_t)row * C;
    int tid = threadIdx.x;
    float v[3];
    float sum = 0.f, sumsq = 0.f;
#pragma unroll
    for (int i = 0; i < 3; i++) {
        v[i] = xr[tid + 256 * i];
        sum += v[i]; sumsq += v[i] * v[i];
    }
    __shared__ float s1[4], s2[4];
    for (int off = 32; off; off >>= 1) {
        sum   += __shfl_xor(sum, off);
        sumsq += __shfl_xor(sumsq, off);
    }
    int wave = tid >> 6, lane = tid & 63;
    if (lane == 0) { s1[wave] = sum; s2[wave] = sumsq; }
    __syncthreads();
    sum   = s1[0] + s1[1] + s1[2] + s1[3];
    sumsq = s2[0] + s2[1] + s2[2] + s2[3];
    float mu  = sum / C;
    float var = sumsq / C - mu * mu;
    float rstd = rsqrtf(fmaxf(var, 0.f) + 1e-5f);
    u16* outr = out + (size_t)row * C;
#pragma unroll
    for (int i = 0; i < 3; i++) {
        int c = tid + 256 * i;
        outr[c] = f2b((v[i] - mu) * rstd * g[c] + b[c]);
    }
}

// ---------------- weight transpose+convert: W[K][ldb] (first N cols) -> Wt[N][K] bf16 ----------
__global__ void wtrans_kernel(const float* __restrict__ W, u16* __restrict__ Wt,
                              int K, int N, int ldb) {
    __shared__ float tile[64][65];
    int nb = blockIdx.x * 64, kb = blockIdx.y * 64;
    int tx = threadIdx.x & 63, ty = threadIdx.x >> 6;
#pragma unroll
    for (int i = 0; i < 64; i += 4)
        tile[ty + i][tx] = W[(size_t)(kb + ty + i) * ldb + nb + tx];
    __syncthreads();
#pragma unroll
    for (int i = 0; i < 64; i += 4)
        Wt[(size_t)(nb + ty + i) * K + kb + tx] = f2b(tile[tx][ty + i]);
}

// ---------------- bf16 MFMA GEMM: C(MxN) = A(MxK) @ Bt(NxK)^T ----------------
// 128x128 tile, BK=32, 256 threads = 4 waves (2x2 of 64x64).
// MODE 0: bf16 out, no bias. MODE 1: bf16 out, bias + exact GELU. MODE 2: f32 out, bias + resid.
template<int MODE>
__global__ __launch_bounds__(256) void gemm_bf16(
    const u16* __restrict__ A, const u16* __restrict__ Bt,
    const float* __restrict__ bias, const float* resid, void* Cout,
    int M, int N, int K) {
    __shared__ char smem[16384];   // As 8KB (128 rows x 64B) + Bs 8KB
    int tid = threadIdx.x, lane = tid & 63, wave = tid >> 6;
    int wr = wave >> 1, wc = wave & 1;
    int r16 = lane & 15, kg = lane >> 4;
    int row0 = blockIdx.y * 128, col0 = blockIdx.x * 128;
    f32x4 acc[4][4];
#pragma unroll
    for (int mt = 0; mt < 4; mt++)
#pragma unroll
        for (int nt = 0; nt < 4; nt++) acc[mt][nt] = (f32x4){0.f, 0.f, 0.f, 0.f};

    int nsteps = K >> 5;
    for (int ks = 0; ks < nsteps; ks++) {
        int k0 = ks << 5;
#pragma unroll
        for (int it = 0; it < 4; it++) {
            int c = it * 256 + wave * 64 + lane;
            const u16* src;
            if (c < 512) {
                int ml = c >> 2, s = c & 3;
                int kgs = s ^ ((ml >> 1) & 3);
                int gm = row0 + ml; if (gm >= M) gm = M - 1;
                src = A + (size_t)gm * K + k0 + kgs * 8;
            } else {
                int cc = c - 512;
                int nl = cc >> 2, s = cc & 3;
                int kgs = s ^ ((nl >> 1) & 3);
                src = Bt + (size_t)(col0 + nl) * K + k0 + kgs * 8;
            }
            gload_lds16(src, smem + it * 4096 + wave * 1024);
        }
        __syncthreads();
        short8 af[4], bfr[4];
#pragma unroll
        for (int mt = 0; mt < 4; mt++) {
            int ml = wr * 64 + mt * 16 + r16;
            af[mt] = *(const short8*)(smem + ml * 64 + ((kg ^ ((ml >> 1) & 3)) << 4));
        }
#pragma unroll
        for (int nt = 0; nt < 4; nt++) {
            int nl = wc * 64 + nt * 16 + r16;
            bfr[nt] = *(const short8*)(smem + 8192 + nl * 64 + ((kg ^ ((nl >> 1) & 3)) << 4));
        }
#pragma unroll
        for (int mt = 0; mt < 4; mt++)
#pragma unroll
            for (int nt = 0; nt < 4; nt++)
                acc[mt][nt] = __builtin_amdgcn_mfma_f32_16x16x32_bf16(af[mt], bfr[nt], acc[mt][nt], 0, 0, 0);
        __syncthreads();
    }
#pragma unroll
    for (int mt = 0; mt < 4; mt++) {
#pragma unroll
        for (int r = 0; r < 4; r++) {
            int gm = row0 + wr * 64 + mt * 16 + kg * 4 + r;
            if (gm >= M) continue;
#pragma unroll
            for (int nt = 0; nt < 4; nt++) {
                int gn = col0 + wc * 64 + nt * 16 + r16;
                float v = acc[mt][nt][r];
                if constexpr (MODE == 1) {
                    v += bias[gn];
                    v = 0.5f * v * (1.f + erff(v * 0.70710678118f));
                }
                if constexpr (MODE == 2) {
                    v += bias[gn] + resid[(size_t)gm * N + gn];
                    ((float*)Cout)[(size_t)gm * N + gn] = v;
                } else {
                    ((u16*)Cout)[(size_t)gm * N + gn] = f2b(v);
                }
            }
        }
    }
}

// ---------------- cls-token attention (bf16 qkv), fully parallel PV ----------------
__global__ void cls_attn_kernel(const u16* __restrict__ qkv, u16* __restrict__ y) {
    int bh = blockIdx.x;
    int b = bh / HEADS, hh = bh % HEADS;
    int tid = threadIdx.x;
    __shared__ float s_q[HD];
    __shared__ float s_sc[NN];
    __shared__ float swm[4], sws[4];
    __shared__ float sacc[4][HD];
    if (tid < HD) s_q[tid] = b2f(qkv[(size_t)(b * NN) * 2304 + hh * HD + tid]);
    __syncthreads();
    float pmax = -1e30f;
    for (int j = tid; j < NN; j += 256) {
        const short8* kp = (const short8*)(qkv + ((size_t)(b * NN) + j) * 2304 + C + hh * HD);
        float acc = 0.f;
#pragma unroll
        for (int u = 0; u < 8; u++) {
            short8 kv = kp[u];
#pragma unroll
            for (int e = 0; e < 8; e++) acc += s_q[u * 8 + e] * b2f((u16)kv[e]);
        }
        acc *= 0.125f;
        s_sc[j] = acc;
        pmax = fmaxf(pmax, acc);
    }
    for (int off = 32; off; off >>= 1) pmax = fmaxf(pmax, __shfl_xor(pmax, off));
    int wave = tid >> 6, lane = tid & 63;
    if (lane == 0) swm[wave] = pmax;
    __syncthreads();
    pmax = fmaxf(fmaxf(swm[0], swm[1]), fmaxf(swm[2], swm[3]));
    float psum = 0.f;
    for (int j = tid; j < NN; j += 256) {
        float e = __expf(s_sc[j] - pmax);
        s_sc[j] = e;
        psum += e;
    }
    for (int off = 32; off; off >>= 1) psum += __shfl_xor(psum, off);
    if (lane == 0) sws[wave] = psum;
    __syncthreads();
    psum = sws[0] + sws[1] + sws[2] + sws[3];
    float inv = 1.f / psum;
    int jj = tid >> 6, d = tid & 63;
    const u16* vcol = qkv + (size_t)(b * NN) * 2304 + 2 * C + hh * HD + d;
    float acc = 0.f;
    for (int j = jj; j < NN; j += 4)
        acc += s_sc[j] * b2f(vcol[(size_t)j * 2304]);
    sacc[jj][d] = acc;
    __syncthreads();
    if (tid < HD) {
        float tot = (sacc[0][tid] + sacc[1][tid] + sacc[2][tid] + sacc[3][tid]) * inv;
        y[(size_t)(b * NN) * C + hh * HD + tid] = f2b(tot);
    }
}

// ---------------- repack K: qkv_b -> Kb[bh][f][208][64], pad rows zeroed ----------------
__global__ void repack_k_kernel(const u16* __restrict__ qkv, u16* __restrict__ Kb) {
    int t = blockIdx.x * 256 + threadIdx.x;
    if (t >= 24 * NF * 208 * 8) return;
    int d8 = t & 7;
    int rest = t >> 3;
    int n = rest % 208;
    rest /= 208;
    int f = rest % NF;
    int bh = rest / NF;
    int b = bh / HEADS, h = bh % HEADS;
    short8 v = {0, 0, 0, 0, 0, 0, 0, 0};
    if (n < SL)
        v = *(const short8*)(qkv + ((size_t)(b * NN) + 1 + f * SL + n) * 2304 + C + h * HD + d8 * 8);
    *(short8*)(Kb + (((size_t)bh * NF + f) * 208 + n) * 64 + d8 * 8) = v;
}

// ---------------- repack V: qkv_b -> Vt[bh][f][d][224] (transposed, pad zeroed) ----------------
__global__ void repack_v_kernel(const u16* __restrict__ qkv, u16* __restrict__ Vt) {
    int t = blockIdx.x * 256 + threadIdx.x;
    if (t >= 24 * NF * 64 * 28) return;
    int n8 = t % 28;
    int rest = t / 28;
    int d = rest % 64;
    rest /= 64;
    int f = rest % NF;
    int bh = rest / NF;
    int b = bh / HEADS, h = bh % HEADS;
    int n0 = n8 * 8;
    const u16* src = qkv + ((size_t)(b * NN) + 1 + f * SL) * 2304 + 2 * C + h * HD + d;
    short8 v;
#pragma unroll
    for (int j = 0; j < 8; j++) {
        int n = n0 + j;
        v[j] = (n < SL) ? (short)src[(size_t)n * 2304] : (short)0;
    }
    *(short8*)(Vt + (((size_t)bh * NF + f) * 64 + d) * 224 + n0) = v;
}

// ---------------- MFMA spatial attention v2 ----------------
// block = 256 threads (4 waves) = one 64-query strip x one frame f.
// K_f (208x64 bf16 = 26624 B) staged in LDS once (XOR-swizzled, rule-#21 pattern),
// shared by all 4 waves; per-wave P buffer; V read from global (L2-resident).
__global__ void space_attn_mfma(
    const u16* __restrict__ qkv, const u16* __restrict__ Kb,
    const u16* __restrict__ Vt, u16* __restrict__ x1) {
    __shared__ u16 smem[28160];  // [0,26624)B: swizzled K_f; [26624,56320)B: 4 x 7424B P bufs
    int tid = threadIdx.x;
    int lane = tid & 63, wave = tid >> 6;
    int r16 = lane & 15, kg = lane >> 4;
    int f = blockIdx.y, bh = blockIdx.z;
    int b = bh / HEADS, h = bh % HEADS;

    // --- stage K_f into LDS: linear dest, pre-swizzled source (involution: byte^=((row&7)<<4)) ---
    const char* kb_g = (const char*)(Kb + ((size_t)bh * NF + f) * 208 * 64);
    for (int w = wave; w < 26; w += 4) {
        int p = w * 1024 + lane * 16;               // physical LDS byte
        int row = p >> 7;
        int src = (p & ~127) | ((p & 127) ^ ((row & 7) << 4));
        gload_lds16(kb_g + src, (char*)smem + p);
    }
    __syncthreads();   // drains global_load_lds (vmcnt) + barrier

    int strip = blockIdx.x * 4 + wave;
    if (strip >= 98) return;    // no barriers past this point
    int q0 = strip * 16;

    // --- A fragments (Q rows, direct from qkv) ---
    const u16* qrow = qkv + ((size_t)(b * NN) + 1 + q0 + r16) * 2304 + h * HD + kg * 8;
    short8 aq0 = *(const short8*)(qrow);
    short8 aq1 = *(const short8*)(qrow + 32);

    // --- QK^T: 13 n-tiles x 2 k-chunks, K frags from swizzled LDS ---
    f32x4 acc[13];
#pragma unroll
    for (int t = 0; t < 13; t++) acc[t] = (f32x4){0.f, 0.f, 0.f, 0.f};
    const char* ksm = (const char*)smem;
    int swz = (r16 & 7) << 4;
#pragma unroll
    for (int t = 0; t < 13; t++) {
        const char* krow = ksm + (t * 16 + r16) * 128;
        short8 bk0 = *(const short8*)(krow + ((kg * 16) ^ swz));
        short8 bk1 = *(const short8*)(krow + ((64 + kg * 16) ^ swz));
        acc[t] = __builtin_amdgcn_mfma_f32_16x16x32_bf16(aq0, bk0, acc[t], 0, 0, 0);
        acc[t] = __builtin_amdgcn_mfma_f32_16x16x32_bf16(aq1, bk1, acc[t], 0, 0, 0);
    }

    // --- per-row softmax (rows q=kg*4+r, cols n=t*16+r16) ---
    bool tail_mask = (r16 >= 4);  // t==12: n = 192+r16 >= 196
    float mrow[4] = {-1e30f, -1e30f, -1e30f, -1e30f};
#pragma unroll
    for (int t = 0; t < 13; t++) {
        if (t == 12 && tail_mask) continue;
#pragma unroll
        for (int r = 0; r < 4; r++) mrow[r] = fmaxf(mrow[r], acc[t][r] * 0.125f);
    }
#pragma unroll
    for (int off = 8; off; off >>= 1)
#pragma unroll
        for (int r = 0; r < 4; r++) mrow[r] = fmaxf(mrow[r], __shfl_xor(mrow[r], off));

    float ssum[4] = {0.f, 0.f, 0.f, 0.f};
#pragma unroll
    for (int t = 0; t < 13; t++) {
#pragma unroll
        for (int r = 0; r < 4; r++) {
            float p = (t == 12 && tail_mask) ? 0.f : __expf(acc[t][r] * 0.125f - mrow[r]);
            acc[t][r] = p;
            ssum[r] += p;
        }
    }
#pragma unroll
    for (int off = 8; off; off >>= 1)
#pragma unroll
        for (int r = 0; r < 4; r++) ssum[r] += __shfl_xor(ssum[r], off);
    float inv[4];
#pragma unroll
    for (int r = 0; r < 4; r++) inv[r] = 1.f / ssum[r];

    // --- write unnormalized P (bf16) to this wave's LDS P buffer ---
    u16* pb = smem + 13312 + wave * 3712;   // 7424 B per wave, stride 232 u16
#pragma unroll
    for (int t = 0; t < 13; t++)
#pragma unroll
        for (int r = 0; r < 4; r++)
            pb[(kg * 4 + r) * 232 + t * 16 + r16] = f2b(acc[t][r]);
    {   // zero pad cols 208..223 (16 rows x 16 cols)
        int zr = lane >> 2, zc = 208 + (lane & 3) * 4;
        *(uint2*)(&pb[zr * 232 + zc]) = (uint2){0u, 0u};
    }

    // --- PV: out(16x64) = P(16x224) @ V_f(224x64), V frags from global (L2) ---
    f32x4 o[4];
#pragma unroll
    for (int dt = 0; dt < 4; dt++) o[dt] = (f32x4){0.f, 0.f, 0.f, 0.f};
    const u16* vbase = Vt + ((size_t)bh * NF + f) * 64 * 224;
#pragma unroll
    for (int kc = 0; kc < 7; kc++) {
        short8 pa = *(const short8*)(&pb[r16 * 232 + kc * 32 + kg * 8]);
#pragma unroll
        for (int dt = 0; dt < 4; dt++) {
            short8 bv = *(const short8*)(vbase + (dt * 16 + r16) * 224 + kc * 32 + kg * 8);
            o[dt] = __builtin_amdgcn_mfma_f32_16x16x32_bf16(pa, bv, o[dt], 0, 0, 0);
        }
    }

    // --- epilogue: rows q=q0+kg*4+r, col d=dt*16+r16 ---
#pragma unroll
    for (int dt = 0; dt < 4; dt++)
#pragma unroll
        for (int r = 0; r < 4; r++) {
            int q = q0 + kg * 4 + r;
            x1[(((size_t)(b * SS + q)) * NF + f) * C + h * HD + dt * 16 + r16] = f2b(o[dt][r] * inv[r]);
        }
}

// ---------------- diagonal gather (bf16): xd[b,s,:] = x1[b,s,s/SL,:] ----------------
__global__ void diag_kernel(const u16* __restrict__ x1, u16* __restrict__ xd) {
    int i = blockIdx.x * 256 + threadIdx.x;
    int total = BB * SS * (C / 8);
    if (i >= total) return;
    int c8 = i % (C / 8);
    int row = i / (C / 8);
    int s = row % SS;
    int f = s / SL;
    ((short8*)(xd + (size_t)row * C))[c8] =
        ((const short8*)(x1 + (((size_t)row) * NF + f) * C))[c8];
}

// ---------------- temporal attention (bf16 in, bf16 out) ----------------
__global__ void attn2_kernel(const u16* __restrict__ q2, const u16* __restrict__ k2,
                             const u16* __restrict__ x1, u16* __restrict__ y) {
    int item = blockIdx.x * 4 + (threadIdx.x >> 6);
    if (item >= BB * HEADS * SS) return;
    int lane = threadIdx.x & 63;
    int s = item % SS;
    int bh = item / SS;
    int b = bh / HEADS, hh = bh % HEADS;
    size_t rowbs = (size_t)(b * SS + s);
    float qv = b2f(q2[rowbs * C + hh * HD + lane]) * 0.125f;
    float lg[NF];
#pragma unroll
    for (int f = 0; f < NF; f++) {
        float p = qv * b2f(k2[(rowbs * NF + f) * C + hh * HD + lane]);
        for (int off = 32; off; off >>= 1) p += __shfl_xor(p, off);
        lg[f] = p;
    }
    float m = lg[0];
#pragma unroll
    for (int f = 1; f < NF; f++) m = fmaxf(m, lg[f]);
    float sum = 0.f;
#pragma unroll
    for (int f = 0; f < NF; f++) { lg[f] = __expf(lg[f] - m); sum += lg[f]; }
    float inv = 1.f / sum;
    float acc = 0.f;
#pragma unroll
    for (int f = 0; f < NF; f++) acc += lg[f] * b2f(x1[(rowbs * NF + f) * C + hh * HD + lane]);
    y[((size_t)(b * NN) + 1 + s) * C + hh * HD + lane] = f2b(acc * inv);
}

extern "C" void kernel_launch(void* const* d_in, const int* in_sizes, int n_in,
                              void* d_out, int out_size, void* d_ws, size_t ws_size,
                              hipStream_t stream) {
    const float* x    = (const float*)d_in[0];
    const float* g1   = (const float*)d_in[1];
    const float* b1   = (const float*)d_in[2];
    const float* Wqkv = (const float*)d_in[3];
    const float* Wq   = (const float*)d_in[4];
    const float* Wkv  = (const float*)d_in[5];
    const float* Wp   = (const float*)d_in[6];
    const float* bp   = (const float*)d_in[7];
    const float* g2   = (const float*)d_in[8];
    const float* b2_  = (const float*)d_in[9];
    const float* W1   = (const float*)d_in[10];
    const float* bf1  = (const float*)d_in[11];
    const float* W2   = (const float*)d_in[12];
    const float* bf2  = (const float*)d_in[13];
    float* out = (float*)d_out;

    // workspace layout (u16 elements)
    u16* us     = (u16*)d_ws;
    u16* xn_b   = us;                    // M1*768    (reused as hn after LN2)
    u16* qkv_b  = xn_b   + 2409984;      // M1*2304
    u16* Wt_qkv = qkv_b  + 7229952;      // 2304*768
    u16* Wt_q   = Wt_qkv + 1769472;      // 768*768
    u16* Wt_kv  = Wt_q   + 589824;       // 768*768 (first half of Wkv)
    u16* Wt_p   = Wt_kv  + 589824;       // 768*768
    u16* W1t    = Wt_p   + 589824;       // 3072*768
    u16* W2t    = W1t    + 2359296;      // 768*3072
    u16* Kb     = W2t    + 2359296;      // 24*8*208*64
    u16* Vt     = Kb     + 2555904;      // 24*8*64*224
    u16* x1b    = Vt     + 2752512;      // B*S*F*C
    u16* xdb    = x1b    + 19267584;     // B*S*C
    u16* q2b    = xdb    + 2408448;      // B*S*C
    u16* k2b    = q2b    + 2408448;      // B*S*F*C
    u16* y_b    = k2b    + 19267584;     // B*N*C
    u16* a1b    = y_b    + 2409984;      // B*N*HID

    const int M1 = BB * NN;       // 3138
    const int M2 = BB * SS;       // 3136
    const int M3 = BB * SS * NF;  // 25088

    // 0. weight transpose + bf16 convert
    wtrans_kernel<<<dim3(2304 / 64, 768 / 64), 256, 0, stream>>>(Wqkv, Wt_qkv, 768, 2304, 2304);
    wtrans_kernel<<<dim3(768 / 64, 768 / 64), 256, 0, stream>>>(Wq, Wt_q, 768, 768, 768);
    wtrans_kernel<<<dim3(768 / 64, 768 / 64), 256, 0, stream>>>(Wkv, Wt_kv, 768, 768, 1536);
    wtrans_kernel<<<dim3(768 / 64, 768 / 64), 256, 0, stream>>>(Wp, Wt_p, 768, 768, 768);
    wtrans_kernel<<<dim3(3072 / 64, 768 / 64), 256, 0, stream>>>(W1, W1t, 768, 3072, 3072);
    wtrans_kernel<<<dim3(768 / 64, 3072 / 64), 256, 0, stream>>>(W2, W2t, 3072, 768, 768);
    // 1. LN1 -> bf16
    ln_kernel<<<M1, 256, 0, stream>>>(x, g1, b1, xn_b, M1);
    // 2. qkv_b = xn_b @ Wqkv (bf16 out)
    gemm_bf16<0><<<dim3(2304 / 128, (M1 + 127) / 128), 256, 0, stream>>>(
        xn_b, Wt_qkv, nullptr, nullptr, qkv_b, M1, 2304, 768);
    // 3. repack K, V
    repack_k_kernel<<<(24 * NF * 208 * 8 + 255) / 256, 256, 0, stream>>>(qkv_b, Kb);
    repack_v_kernel<<<(24 * NF * 64 * 28 + 255) / 256, 256, 0, stream>>>(qkv_b, Vt);
    // 4. cls attention -> y_b row 0
    cls_attn_kernel<<<BB * HEADS, 256, 0, stream>>>(qkv_b, y_b);
    // 5. spatial attention -> x1b (4-wave blocks, K in LDS)
    space_attn_mfma<<<dim3(25, NF, 24), 256, 0, stream>>>(qkv_b, Kb, Vt, x1b);
    // 6. diag gather
    diag_kernel<<<(BB * SS * (C / 8) + 255) / 256, 256, 0, stream>>>(x1b, xdb);
    // 7. q2 = xd @ Wq
    gemm_bf16<0><<<dim3(768 / 128, (M2 + 127) / 128), 256, 0, stream>>>(
        xdb, Wt_q, nullptr, nullptr, q2b, M2, 768, 768);
    // 8. k2 = x1 @ Wkv[:, :C]
    gemm_bf16<0><<<dim3(768 / 128, M3 / 128), 256, 0, stream>>>(
        x1b, Wt_kv, nullptr, nullptr, k2b, M3, 768, 768);
    // 9. temporal attention -> y_b rows 1..S
    attn2_kernel<<<(BB * HEADS * SS + 3) / 4, 256, 0, stream>>>(q2b, k2b, x1b, y_b);
    // 10. proj: out = y_b @ Wp + bp + x  (f32)
    gemm_bf16<2><<<dim3(768 / 128, (M1 + 127) / 128), 256, 0, stream>>>(
        y_b, Wt_p, bp, x, out, M1, 768, 768);
    // 11. LN2 -> bf16 (reuse xn_b)
    ln_kernel<<<M1, 256, 0, stream>>>(out, g2, b2_, xn_b, M1);
    // 12. fc1 + exact GELU -> bf16
    gemm_bf16<1><<<dim3(3072 / 128, (M1 + 127) / 128), 256, 0, stream>>>(
        xn_b, W1t, bf1, nullptr, a1b, M1, 3072, 768);
    // 13. fc2 + bias + residual (f32, in-place on d_out)
    gemm_bf16<2><<<dim3(768 / 128, (M1 + 127) / 128), 256, 0, stream>>>(
        a1b, W2t, bf2, out, out, M1, 768, 3072);
}

// Round 6
// 413.702 us; speedup vs baseline: 11.5761x; 1.2039x over previous
//
#include <hip/hip_runtime.h>
#include <math.h>

#define C     768
#define HEADS 12
#define HD    64
#define NF    8
#define SL    196
#define BB    2
#define NN    1569   // 1 + NF*SL
#define SS    1568   // NF*SL
#define HID   3072
#define CLS_CH 256
#define CLS_NC 7     // ceil(NN / CLS_CH)

typedef __attribute__((ext_vector_type(8))) short short8;
typedef __attribute__((ext_vector_type(4))) float f32x4;
typedef unsigned short u16;

__device__ inline u16 f2b(float f) {
    union { float f; unsigned u; } v; v.f = f;
    unsigned r = (v.u + 0x7FFFu + ((v.u >> 16) & 1u)) >> 16;
    return (u16)r;
}
__device__ inline float b2f(u16 u) {
    union { unsigned u; float f; } v; v.u = ((unsigned)u) << 16;
    return v.f;
}

__device__ inline void gload_lds16(const void* g, void* l) {
    __builtin_amdgcn_global_load_lds(
        (const __attribute__((address_space(1))) void*)g,
        (__attribute__((address_space(3))) void*)l, 16, 0, 0);
}

// ---------------- LayerNorm: f32 in -> bf16 out ----------------
__global__ void ln_kernel(const float* __restrict__ x, const float* __restrict__ g,
                          const float* __restrict__ b, u16* __restrict__ out, int rows) {
    int row = blockIdx.x;
    if (row >= rows) return;
    const float* xr = x + (size_t)row * C;
    int tid = threadIdx.x;
    float v[3];
    float sum = 0.f, sumsq = 0.f;
#pragma unroll
    for (int i = 0; i < 3; i++) {
        v[i] = xr[tid + 256 * i];
        sum += v[i]; sumsq += v[i] * v[i];
    }
    __shared__ float s1[4], s2[4];
    for (int off = 32; off; off >>= 1) {
        sum   += __shfl_xor(sum, off);
        sumsq += __shfl_xor(sumsq, off);
    }
    int wave = tid >> 6, lane = tid & 63;
    if (lane == 0) { s1[wave] = sum; s2[wave] = sumsq; }
    __syncthreads();
    sum   = s1[0] + s1[1] + s1[2] + s1[3];
    sumsq = s2[0] + s2[1] + s2[2] + s2[3];
    float mu  = sum / C;
    float var = sumsq / C - mu * mu;
    float rstd = rsqrtf(fmaxf(var, 0.f) + 1e-5f);
    u16* outr = out + (size_t)row * C;
#pragma unroll
    for (int i = 0; i < 3; i++) {
        int c = tid + 256 * i;
        outr[c] = f2b((v[i] - mu) * rstd * g[c] + b[c]);
    }
}

// ---------------- weight transpose+convert: W[K][ldb] (first N cols) -> Wt[N][K] bf16 ----------
__global__ void wtrans_kernel(const float* __restrict__ W, u16* __restrict__ Wt,
                              int K, int N, int ldb) {
    __shared__ float tile[64][65];
    int nb = blockIdx.x * 64, kb = blockIdx.y * 64;
    int tx = threadIdx.x & 63, ty = threadIdx.x >> 6;
#pragma unroll
    for (int i = 0; i < 64; i += 4)
        tile[ty + i][tx] = W[(size_t)(kb + ty + i) * ldb + nb + tx];
    __syncthreads();
#pragma unroll
    for (int i = 0; i < 64; i += 4)
        Wt[(size_t)(nb + ty + i) * K + kb + tx] = f2b(tile[tx][ty + i]);
}

// ---------------- bf16 MFMA GEMM: C(MxN) = A(MxK) @ Bt(NxK)^T ----------------
// 128x128 tile, BK=32, 256 threads = 4 waves (2x2 of 64x64).
// MODE 0: bf16 out, no bias. MODE 1: bf16 out, bias + exact GELU. MODE 2: f32 out, bias + resid.
template<int MODE>
__global__ __launch_bounds__(256) void gemm_bf16(
    const u16* __restrict__ A, const u16* __restrict__ Bt,
    const float* __restrict__ bias, const float* resid, void* Cout,
    int M, int N, int K) {
    __shared__ char smem[16384];   // As 8KB (128 rows x 64B) + Bs 8KB
    int tid = threadIdx.x, lane = tid & 63, wave = tid >> 6;
    int wr = wave >> 1, wc = wave & 1;
    int r16 = lane & 15, kg = lane >> 4;
    int row0 = blockIdx.y * 128, col0 = blockIdx.x * 128;
    f32x4 acc[4][4];
#pragma unroll
    for (int mt = 0; mt < 4; mt++)
#pragma unroll
        for (int nt = 0; nt < 4; nt++) acc[mt][nt] = (f32x4){0.f, 0.f, 0.f, 0.f};

    int nsteps = K >> 5;
    for (int ks = 0; ks < nsteps; ks++) {
        int k0 = ks << 5;
#pragma unroll
        for (int it = 0; it < 4; it++) {
            int c = it * 256 + wave * 64 + lane;
            const u16* src;
            if (c < 512) {
                int ml = c >> 2, s = c & 3;
                int kgs = s ^ ((ml >> 1) & 3);
                int gm = row0 + ml; if (gm >= M) gm = M - 1;
                src = A + (size_t)gm * K + k0 + kgs * 8;
            } else {
                int cc = c - 512;
                int nl = cc >> 2, s = cc & 3;
                int kgs = s ^ ((nl >> 1) & 3);
                src = Bt + (size_t)(col0 + nl) * K + k0 + kgs * 8;
            }
            gload_lds16(src, smem + it * 4096 + wave * 1024);
        }
        __syncthreads();
        short8 af[4], bfr[4];
#pragma unroll
        for (int mt = 0; mt < 4; mt++) {
            int ml = wr * 64 + mt * 16 + r16;
            af[mt] = *(const short8*)(smem + ml * 64 + ((kg ^ ((ml >> 1) & 3)) << 4));
        }
#pragma unroll
        for (int nt = 0; nt < 4; nt++) {
            int nl = wc * 64 + nt * 16 + r16;
            bfr[nt] = *(const short8*)(smem + 8192 + nl * 64 + ((kg ^ ((nl >> 1) & 3)) << 4));
        }
#pragma unroll
        for (int mt = 0; mt < 4; mt++)
#pragma unroll
            for (int nt = 0; nt < 4; nt++)
                acc[mt][nt] = __builtin_amdgcn_mfma_f32_16x16x32_bf16(af[mt], bfr[nt], acc[mt][nt], 0, 0, 0);
        __syncthreads();
    }
#pragma unroll
    for (int mt = 0; mt < 4; mt++) {
#pragma unroll
        for (int r = 0; r < 4; r++) {
            int gm = row0 + wr * 64 + mt * 16 + kg * 4 + r;
            if (gm >= M) continue;
#pragma unroll
            for (int nt = 0; nt < 4; nt++) {
                int gn = col0 + wc * 64 + nt * 16 + r16;
                float v = acc[mt][nt][r];
                if constexpr (MODE == 1) {
                    v += bias[gn];
                    v = 0.5f * v * (1.f + erff(v * 0.70710678118f));
                }
                if constexpr (MODE == 2) {
                    v += bias[gn] + resid[(size_t)gm * N + gn];
                    ((float*)Cout)[(size_t)gm * N + gn] = v;
                } else {
                    ((u16*)Cout)[(size_t)gm * N + gn] = f2b(v);
                }
            }
        }
    }
}

// ---------------- cls attention pass 1: per-chunk partial softmax + PV ----------------
// grid (CLS_NC, B*HEADS), 256 threads. part[bh][c] = {m, s, pv[64]}
__global__ void cls_partial_kernel(const u16* __restrict__ qkv, float* __restrict__ part) {
    int c = blockIdx.x, bh = blockIdx.y;
    int b = bh / HEADS, hh = bh % HEADS;
    int tid = threadIdx.x;
    int wave = tid >> 6, lane = tid & 63;
    __shared__ float s_q[HD];
    __shared__ float s_sc[CLS_CH];
    __shared__ float sm[4], ss[4];
    __shared__ float sacc[4][HD];
    if (tid < HD) s_q[tid] = b2f(qkv[(size_t)(b * NN) * 2304 + hh * HD + tid]);
    __syncthreads();

    int j0 = c * CLS_CH;
    int j = j0 + tid;
    float sc = -1e30f;
    if (j < NN) {
        const short8* kp = (const short8*)(qkv + ((size_t)(b * NN) + j) * 2304 + C + hh * HD);
        float acc = 0.f;
#pragma unroll
        for (int u = 0; u < 8; u++) {
            short8 kv = kp[u];
#pragma unroll
            for (int e = 0; e < 8; e++) acc += s_q[u * 8 + e] * b2f((u16)kv[e]);
        }
        sc = acc * 0.125f;
    }
    // block max
    float m = sc;
    for (int off = 32; off; off >>= 1) m = fmaxf(m, __shfl_xor(m, off));
    if (lane == 0) sm[wave] = m;
    __syncthreads();
    m = fmaxf(fmaxf(sm[0], sm[1]), fmaxf(sm[2], sm[3]));
    // exp + block sum
    float e = (j < NN) ? __expf(sc - m) : 0.f;
    s_sc[tid] = e;
    float su = e;
    for (int off = 32; off; off >>= 1) su += __shfl_xor(su, off);
    if (lane == 0) ss[wave] = su;
    __syncthreads();
    float ssum = ss[0] + ss[1] + ss[2] + ss[3];

    // PV partial: thread (jj, d), coalesced 128B per key row
    int jj = tid >> 6, d = tid & 63;
    int jmax = NN - j0; if (jmax > CLS_CH) jmax = CLS_CH;
    const u16* vcol = qkv + ((size_t)(b * NN) + j0) * 2304 + 2 * C + hh * HD + d;
    float acc = 0.f;
    for (int t = jj; t < jmax; t += 4)
        acc += s_sc[t] * b2f(vcol[(size_t)t * 2304]);
    sacc[jj][d] = acc;
    __syncthreads();
    if (tid < HD) {
        float pv = sacc[0][tid] + sacc[1][tid] + sacc[2][tid] + sacc[3][tid];
        float* pp = part + ((size_t)bh * CLS_NC + c) * 66;
        pp[2 + tid] = pv;
        if (tid == 0) { pp[0] = m; pp[1] = ssum; }
    }
}

// ---------------- cls attention pass 2: merge chunk partials ----------------
__global__ void cls_reduce_kernel(const float* __restrict__ part, u16* __restrict__ y) {
    int bh = blockIdx.x;
    int b = bh / HEADS, hh = bh % HEADS;
    int d = threadIdx.x;   // 64
    float gm = -1e30f;
#pragma unroll
    for (int c = 0; c < CLS_NC; c++)
        gm = fmaxf(gm, part[((size_t)bh * CLS_NC + c) * 66]);
    float tot = 0.f, pv = 0.f;
#pragma unroll
    for (int c = 0; c < CLS_NC; c++) {
        const float* pp = part + ((size_t)bh * CLS_NC + c) * 66;
        float w = __expf(pp[0] - gm);
        tot += pp[1] * w;
        pv  += pp[2 + d] * w;
    }
    y[(size_t)(b * NN) * C + hh * HD + d] = f2b(pv / tot);
}

// ---------------- repack K: qkv_b -> Kb[bh][f][208][64], pad rows zeroed ----------------
__global__ void repack_k_kernel(const u16* __restrict__ qkv, u16* __restrict__ Kb) {
    int t = blockIdx.x * 256 + threadIdx.x;
    if (t >= 24 * NF * 208 * 8) return;
    int d8 = t & 7;
    int rest = t >> 3;
    int n = rest % 208;
    rest /= 208;
    int f = rest % NF;
    int bh = rest / NF;
    int b = bh / HEADS, h = bh % HEADS;
    short8 v = {0, 0, 0, 0, 0, 0, 0, 0};
    if (n < SL)
        v = *(const short8*)(qkv + ((size_t)(b * NN) + 1 + f * SL + n) * 2304 + C + h * HD + d8 * 8);
    *(short8*)(Kb + (((size_t)bh * NF + f) * 208 + n) * 64 + d8 * 8) = v;
}

// ---------------- repack V: qkv_b -> Vt[bh][f][d][224] (transposed, pad zeroed) ----------------
__global__ void repack_v_kernel(const u16* __restrict__ qkv, u16* __restrict__ Vt) {
    int t = blockIdx.x * 256 + threadIdx.x;
    if (t >= 24 * NF * 64 * 28) return;
    int n8 = t % 28;
    int rest = t / 28;
    int d = rest % 64;
    rest /= 64;
    int f = rest % NF;
    int bh = rest / NF;
    int b = bh / HEADS, h = bh % HEADS;
    int n0 = n8 * 8;
    const u16* src = qkv + ((size_t)(b * NN) + 1 + f * SL) * 2304 + 2 * C + h * HD + d;
    short8 v;
#pragma unroll
    for (int j = 0; j < 8; j++) {
        int n = n0 + j;
        v[j] = (n < SL) ? (short)src[(size_t)n * 2304] : (short)0;
    }
    *(short8*)(Vt + (((size_t)bh * NF + f) * 64 + d) * 224 + n0) = v;
}

// ---------------- MFMA spatial attention v2 ----------------
__global__ void space_attn_mfma(
    const u16* __restrict__ qkv, const u16* __restrict__ Kb,
    const u16* __restrict__ Vt, u16* __restrict__ x1) {
    __shared__ u16 smem[28160];  // [0,26624)B: swizzled K_f; rest: 4 x 7424B P bufs
    int tid = threadIdx.x;
    int lane = tid & 63, wave = tid >> 6;
    int r16 = lane & 15, kg = lane >> 4;
    int f = blockIdx.y, bh = blockIdx.z;
    int b = bh / HEADS, h = bh % HEADS;

    const char* kb_g = (const char*)(Kb + ((size_t)bh * NF + f) * 208 * 64);
    for (int w = wave; w < 26; w += 4) {
        int p = w * 1024 + lane * 16;
        int row = p >> 7;
        int src = (p & ~127) | ((p & 127) ^ ((row & 7) << 4));
        gload_lds16(kb_g + src, (char*)smem + p);
    }
    __syncthreads();

    int strip = blockIdx.x * 4 + wave;
    if (strip >= 98) return;
    int q0 = strip * 16;

    const u16* qrow = qkv + ((size_t)(b * NN) + 1 + q0 + r16) * 2304 + h * HD + kg * 8;
    short8 aq0 = *(const short8*)(qrow);
    short8 aq1 = *(const short8*)(qrow + 32);

    f32x4 acc[13];
#pragma unroll
    for (int t = 0; t < 13; t++) acc[t] = (f32x4){0.f, 0.f, 0.f, 0.f};
    const char* ksm = (const char*)smem;
    int swz = (r16 & 7) << 4;
#pragma unroll
    for (int t = 0; t < 13; t++) {
        const char* krow = ksm + (t * 16 + r16) * 128;
        short8 bk0 = *(const short8*)(krow + ((kg * 16) ^ swz));
        short8 bk1 = *(const short8*)(krow + ((64 + kg * 16) ^ swz));
        acc[t] = __builtin_amdgcn_mfma_f32_16x16x32_bf16(aq0, bk0, acc[t], 0, 0, 0);
        acc[t] = __builtin_amdgcn_mfma_f32_16x16x32_bf16(aq1, bk1, acc[t], 0, 0, 0);
    }

    bool tail_mask = (r16 >= 4);
    float mrow[4] = {-1e30f, -1e30f, -1e30f, -1e30f};
#pragma unroll
    for (int t = 0; t < 13; t++) {
        if (t == 12 && tail_mask) continue;
#pragma unroll
        for (int r = 0; r < 4; r++) mrow[r] = fmaxf(mrow[r], acc[t][r] * 0.125f);
    }
#pragma unroll
    for (int off = 8; off; off >>= 1)
#pragma unroll
        for (int r = 0; r < 4; r++) mrow[r] = fmaxf(mrow[r], __shfl_xor(mrow[r], off));

    float ssum[4] = {0.f, 0.f, 0.f, 0.f};
#pragma unroll
    for (int t = 0; t < 13; t++) {
#pragma unroll
        for (int r = 0; r < 4; r++) {
            float p = (t == 12 && tail_mask) ? 0.f : __expf(acc[t][r] * 0.125f - mrow[r]);
            acc[t][r] = p;
            ssum[r] += p;
        }
    }
#pragma unroll
    for (int off = 8; off; off >>= 1)
#pragma unroll
        for (int r = 0; r < 4; r++) ssum[r] += __shfl_xor(ssum[r], off);
    float inv[4];
#pragma unroll
    for (int r = 0; r < 4; r++) inv[r] = 1.f / ssum[r];

    u16* pb = smem + 13312 + wave * 3712;
#pragma unroll
    for (int t = 0; t < 13; t++)
#pragma unroll
        for (int r = 0; r < 4; r++)
            pb[(kg * 4 + r) * 232 + t * 16 + r16] = f2b(acc[t][r]);
    {
        int zr = lane >> 2, zc = 208 + (lane & 3) * 4;
        *(uint2*)(&pb[zr * 232 + zc]) = (uint2){0u, 0u};
    }

    f32x4 o[4];
#pragma unroll
    for (int dt = 0; dt < 4; dt++) o[dt] = (f32x4){0.f, 0.f, 0.f, 0.f};
    const u16* vbase = Vt + ((size_t)bh * NF + f) * 64 * 224;
#pragma unroll
    for (int kc = 0; kc < 7; kc++) {
        short8 pa = *(const short8*)(&pb[r16 * 232 + kc * 32 + kg * 8]);
#pragma unroll
        for (int dt = 0; dt < 4; dt++) {
            short8 bv = *(const short8*)(vbase + (dt * 16 + r16) * 224 + kc * 32 + kg * 8);
            o[dt] = __builtin_amdgcn_mfma_f32_16x16x32_bf16(pa, bv, o[dt], 0, 0, 0);
        }
    }

#pragma unroll
    for (int dt = 0; dt < 4; dt++)
#pragma unroll
        for (int r = 0; r < 4; r++) {
            int q = q0 + kg * 4 + r;
            x1[(((size_t)(b * SS + q)) * NF + f) * C + h * HD + dt * 16 + r16] = f2b(o[dt][r] * inv[r]);
        }
}

// ---------------- diagonal gather (bf16): xd[b,s,:] = x1[b,s,s/SL,:] ----------------
__global__ void diag_kernel(const u16* __restrict__ x1, u16* __restrict__ xd) {
    int i = blockIdx.x * 256 + threadIdx.x;
    int total = BB * SS * (C / 8);
    if (i >= total) return;
    int c8 = i % (C / 8);
    int row = i / (C / 8);
    int s = row % SS;
    int f = s / SL;
    ((short8*)(xd + (size_t)row * C))[c8] =
        ((const short8*)(x1 + (((size_t)row) * NF + f) * C))[c8];
}

// ---------------- temporal attention (bf16 in, bf16 out) ----------------
__global__ void attn2_kernel(const u16* __restrict__ q2, const u16* __restrict__ k2,
                             const u16* __restrict__ x1, u16* __restrict__ y) {
    int item = blockIdx.x * 4 + (threadIdx.x >> 6);
    if (item >= BB * HEADS * SS) return;
    int lane = threadIdx.x & 63;
    int s = item % SS;
    int bh = item / SS;
    int b = bh / HEADS, hh = bh % HEADS;
    size_t rowbs = (size_t)(b * SS + s);
    float qv = b2f(q2[rowbs * C + hh * HD + lane]) * 0.125f;
    float lg[NF];
#pragma unroll
    for (int f = 0; f < NF; f++) {
        float p = qv * b2f(k2[(rowbs * NF + f) * C + hh * HD + lane]);
        for (int off = 32; off; off >>= 1) p += __shfl_xor(p, off);
        lg[f] = p;
    }
    float m = lg[0];
#pragma unroll
    for (int f = 1; f < NF; f++) m = fmaxf(m, lg[f]);
    float sum = 0.f;
#pragma unroll
    for (int f = 0; f < NF; f++) { lg[f] = __expf(lg[f] - m); sum += lg[f]; }
    float inv = 1.f / sum;
    float acc = 0.f;
#pragma unroll
    for (int f = 0; f < NF; f++) acc += lg[f] * b2f(x1[(rowbs * NF + f) * C + hh * HD + lane]);
    y[((size_t)(b * NN) + 1 + s) * C + hh * HD + lane] = f2b(acc * inv);
}

extern "C" void kernel_launch(void* const* d_in, const int* in_sizes, int n_in,
                              void* d_out, int out_size, void* d_ws, size_t ws_size,
                              hipStream_t stream) {
    const float* x    = (const float*)d_in[0];
    const float* g1   = (const float*)d_in[1];
    const float* b1   = (const float*)d_in[2];
    const float* Wqkv = (const float*)d_in[3];
    const float* Wq   = (const float*)d_in[4];
    const float* Wkv  = (const float*)d_in[5];
    const float* Wp   = (const float*)d_in[6];
    const float* bp   = (const float*)d_in[7];
    const float* g2   = (const float*)d_in[8];
    const float* b2_  = (const float*)d_in[9];
    const float* W1   = (const float*)d_in[10];
    const float* bf1  = (const float*)d_in[11];
    const float* W2   = (const float*)d_in[12];
    const float* bf2  = (const float*)d_in[13];
    float* out = (float*)d_out;

    // workspace layout (u16 elements)
    u16* us     = (u16*)d_ws;
    u16* xn_b   = us;                    // M1*768    (reused as hn after LN2)
    u16* qkv_b  = xn_b   + 2409984;      // M1*2304
    u16* Wt_qkv = qkv_b  + 7229952;      // 2304*768
    u16* Wt_q   = Wt_qkv + 1769472;      // 768*768
    u16* Wt_kv  = Wt_q   + 589824;       // 768*768 (first half of Wkv)
    u16* Wt_p   = Wt_kv  + 589824;       // 768*768
    u16* W1t    = Wt_p   + 589824;       // 3072*768
    u16* W2t    = W1t    + 2359296;      // 768*3072
    u16* Kb     = W2t    + 2359296;      // 24*8*208*64
    u16* Vt     = Kb     + 2555904;      // 24*8*64*224
    u16* x1b    = Vt     + 2752512;      // B*S*F*C
    u16* xdb    = x1b    + 19267584;     // B*S*C
    u16* q2b    = xdb    + 2408448;      // B*S*C
    u16* k2b    = q2b    + 2408448;      // B*S*F*C
    u16* y_b    = k2b    + 19267584;     // B*N*C
    u16* a1b    = y_b    + 2409984;      // B*N*HID
    float* cls_ws = (float*)(a1b + 9639936);  // 24*7*66 floats

    const int M1 = BB * NN;       // 3138
    const int M2 = BB * SS;       // 3136
    const int M3 = BB * SS * NF;  // 25088

    // 0. weight transpose + bf16 convert
    wtrans_kernel<<<dim3(2304 / 64, 768 / 64), 256, 0, stream>>>(Wqkv, Wt_qkv, 768, 2304, 2304);
    wtrans_kernel<<<dim3(768 / 64, 768 / 64), 256, 0, stream>>>(Wq, Wt_q, 768, 768, 768);
    wtrans_kernel<<<dim3(768 / 64, 768 / 64), 256, 0, stream>>>(Wkv, Wt_kv, 768, 768, 1536);
    wtrans_kernel<<<dim3(768 / 64, 768 / 64), 256, 0, stream>>>(Wp, Wt_p, 768, 768, 768);
    wtrans_kernel<<<dim3(3072 / 64, 768 / 64), 256, 0, stream>>>(W1, W1t, 768, 3072, 3072);
    wtrans_kernel<<<dim3(768 / 64, 3072 / 64), 256, 0, stream>>>(W2, W2t, 3072, 768, 768);
    // 1. LN1 -> bf16
    ln_kernel<<<M1, 256, 0, stream>>>(x, g1, b1, xn_b, M1);
    // 2. qkv_b = xn_b @ Wqkv (bf16 out)
    gemm_bf16<0><<<dim3(2304 / 128, (M1 + 127) / 128), 256, 0, stream>>>(
        xn_b, Wt_qkv, nullptr, nullptr, qkv_b, M1, 2304, 768);
    // 3. repack K, V
    repack_k_kernel<<<(24 * NF * 208 * 8 + 255) / 256, 256, 0, stream>>>(qkv_b, Kb);
    repack_v_kernel<<<(24 * NF * 64 * 28 + 255) / 256, 256, 0, stream>>>(qkv_b, Vt);
    // 4. cls attention (two-pass flash-style) -> y_b row 0
    cls_partial_kernel<<<dim3(CLS_NC, BB * HEADS), 256, 0, stream>>>(qkv_b, cls_ws);
    cls_reduce_kernel<<<BB * HEADS, 64, 0, stream>>>(cls_ws, y_b);
    // 5. spatial attention -> x1b (4-wave blocks, K in LDS)
    space_attn_mfma<<<dim3(25, NF, 24), 256, 0, stream>>>(qkv_b, Kb, Vt, x1b);
    // 6. diag gather
    diag_kernel<<<(BB * SS * (C / 8) + 255) / 256, 256, 0, stream>>>(x1b, xdb);
    // 7. q2 = xd @ Wq
    gemm_bf16<0><<<dim3(768 / 128, (M2 + 127) / 128), 256, 0, stream>>>(
        xdb, Wt_q, nullptr, nullptr, q2b, M2, 768, 768);
    // 8. k2 = x1 @ Wkv[:, :C]
    gemm_bf16<0><<<dim3(768 / 128, M3 / 128), 256, 0, stream>>>(
        x1b, Wt_kv, nullptr, nullptr, k2b, M3, 768, 768);
    // 9. temporal attention -> y_b rows 1..S
    attn2_kernel<<<(BB * HEADS * SS + 3) / 4, 256, 0, stream>>>(q2b, k2b, x1b, y_b);
    // 10. proj: out = y_b @ Wp + bp + x  (f32)
    gemm_bf16<2><<<dim3(768 / 128, (M1 + 127) / 128), 256, 0, stream>>>(
        y_b, Wt_p, bp, x, out, M1, 768, 768);
    // 11. LN2 -> bf16 (reuse xn_b)
    ln_kernel<<<M1, 256, 0, stream>>>(out, g2, b2_, xn_b, M1);
    // 12. fc1 + exact GELU -> bf16
    gemm_bf16<1><<<dim3(3072 / 128, (M1 + 127) / 128), 256, 0, stream>>>(
        xn_b, W1t, bf1, nullptr, a1b, M1, 3072, 768);
    // 13. fc2 + bias + residual (f32, in-place on d_out)
    gemm_bf16<2><<<dim3(768 / 128, (M1 + 127) / 128), 256, 0, stream>>>(
        a1b, W2t, bf2, out, out, M1, 768, 3072);
}

// Round 7
// 368.502 us; speedup vs baseline: 12.9960x; 1.1227x over previous
//
#include <hip/hip_runtime.h>
#include <math.h>

#define C     768
#define HEADS 12
#define HD    64
#define NF    8
#define SL    196
#define BB    2
#define NN    1569   // 1 + NF*SL
#define SS    1568   // NF*SL
#define HID   3072
#define CLS_CH 256
#define CLS_NC 7     // ceil(NN / CLS_CH)

typedef __attribute__((ext_vector_type(8))) short short8;
typedef __attribute__((ext_vector_type(4))) float f32x4;
typedef unsigned short u16;

__device__ inline u16 f2b(float f) {
    union { float f; unsigned u; } v; v.f = f;
    unsigned r = (v.u + 0x7FFFu + ((v.u >> 16) & 1u)) >> 16;
    return (u16)r;
}
__device__ inline float b2f(u16 u) {
    union { unsigned u; float f; } v; v.u = ((unsigned)u) << 16;
    return v.f;
}

__device__ inline void gload_lds16(const void* g, void* l) {
    __builtin_amdgcn_global_load_lds(
        (const __attribute__((address_space(1))) void*)g,
        (__attribute__((address_space(3))) void*)l, 16, 0, 0);
}

// ---------------- LayerNorm: f32 in -> bf16 out ----------------
__global__ void ln_kernel(const float* __restrict__ x, const float* __restrict__ g,
                          const float* __restrict__ b, u16* __restrict__ out, int rows) {
    int row = blockIdx.x;
    if (row >= rows) return;
    const float* xr = x + (size_t)row * C;
    int tid = threadIdx.x;
    float v[3];
    float sum = 0.f, sumsq = 0.f;
#pragma unroll
    for (int i = 0; i < 3; i++) {
        v[i] = xr[tid + 256 * i];
        sum += v[i]; sumsq += v[i] * v[i];
    }
    __shared__ float s1[4], s2[4];
    for (int off = 32; off; off >>= 1) {
        sum   += __shfl_xor(sum, off);
        sumsq += __shfl_xor(sumsq, off);
    }
    int wave = tid >> 6, lane = tid & 63;
    if (lane == 0) { s1[wave] = sum; s2[wave] = sumsq; }
    __syncthreads();
    sum   = s1[0] + s1[1] + s1[2] + s1[3];
    sumsq = s2[0] + s2[1] + s2[2] + s2[3];
    float mu  = sum / C;
    float var = sumsq / C - mu * mu;
    float rstd = rsqrtf(fmaxf(var, 0.f) + 1e-5f);
    u16* outr = out + (size_t)row * C;
#pragma unroll
    for (int i = 0; i < 3; i++) {
        int c = tid + 256 * i;
        outr[c] = f2b((v[i] - mu) * rstd * g[c] + b[c]);
    }
}

// ---------------- weight transpose+convert: W[K][ldb] (first N cols) -> Wt[N][K] bf16 ----------
__global__ void wtrans_kernel(const float* __restrict__ W, u16* __restrict__ Wt,
                              int K, int N, int ldb) {
    __shared__ float tile[64][65];
    int nb = blockIdx.x * 64, kb = blockIdx.y * 64;
    int tx = threadIdx.x & 63, ty = threadIdx.x >> 6;
#pragma unroll
    for (int i = 0; i < 64; i += 4)
        tile[ty + i][tx] = W[(size_t)(kb + ty + i) * ldb + nb + tx];
    __syncthreads();
#pragma unroll
    for (int i = 0; i < 64; i += 4)
        Wt[(size_t)(nb + ty + i) * K + kb + tx] = f2b(tile[tx][ty + i]);
}

// ---------------- bf16 MFMA GEMM (2-phase double-buffered): C = A(MxK) @ Bt(NxK)^T ----------
// 128x128 tile, BK=32, 256 threads = 4 waves (2x2 of 64x64). LDS 2 x 16KB ping-pong;
// next K-tile's global_load_lds is issued BEFORE computing the current tile (T3 minimum).
// MODE 0: bf16 out. MODE 1: bf16 out, bias + exact GELU. MODE 2: f32 out, bias + resid.
template<int MODE>
__global__ __launch_bounds__(256) void gemm_bf16(
    const u16* __restrict__ A, const u16* __restrict__ Bt,
    const float* __restrict__ bias, const float* resid, void* Cout,
    int M, int N, int K) {
    __shared__ char smem[32768];   // 2 x (As 8KB + Bs 8KB)
    int tid = threadIdx.x, lane = tid & 63, wave = tid >> 6;
    int wr = wave >> 1, wc = wave & 1;
    int r16 = lane & 15, kg = lane >> 4;
    int row0 = blockIdx.y * 128, col0 = blockIdx.x * 128;
    f32x4 acc[4][4];
#pragma unroll
    for (int mt = 0; mt < 4; mt++)
#pragma unroll
        for (int nt = 0; nt < 4; nt++) acc[mt][nt] = (f32x4){0.f, 0.f, 0.f, 0.f};

    auto stage = [&](char* dstbase, int ks) {
        int k0 = ks << 5;
#pragma unroll
        for (int it = 0; it < 4; it++) {
            int c = it * 256 + tid;
            const u16* src;
            if (c < 512) {
                int ml = c >> 2, s = c & 3;
                int kgs = s ^ ((ml >> 1) & 3);
                int gm = row0 + ml; if (gm >= M) gm = M - 1;
                src = A + (size_t)gm * K + k0 + kgs * 8;
            } else {
                int cc = c - 512;
                int nl = cc >> 2, s = cc & 3;
                int kgs = s ^ ((nl >> 1) & 3);
                src = Bt + (size_t)(col0 + nl) * K + k0 + kgs * 8;
            }
            gload_lds16(src, dstbase + it * 4096 + wave * 1024);
        }
    };

    int nsteps = K >> 5;
    stage(smem, 0);
    __syncthreads();               // drains vmcnt: tile 0 resident
    for (int ks = 0; ks < nsteps; ks++) {
        char* curb = smem + (ks & 1) * 16384;
        if (ks + 1 < nsteps) stage(smem + ((ks + 1) & 1) * 16384, ks + 1);
        short8 af[4], bfr[4];
#pragma unroll
        for (int mt = 0; mt < 4; mt++) {
            int ml = wr * 64 + mt * 16 + r16;
            af[mt] = *(const short8*)(curb + ml * 64 + ((kg ^ ((ml >> 1) & 3)) << 4));
        }
#pragma unroll
        for (int nt = 0; nt < 4; nt++) {
            int nl = wc * 64 + nt * 16 + r16;
            bfr[nt] = *(const short8*)(curb + 8192 + nl * 64 + ((kg ^ ((nl >> 1) & 3)) << 4));
        }
#pragma unroll
        for (int mt = 0; mt < 4; mt++)
#pragma unroll
            for (int nt = 0; nt < 4; nt++)
                acc[mt][nt] = __builtin_amdgcn_mfma_f32_16x16x32_bf16(af[mt], bfr[nt], acc[mt][nt], 0, 0, 0);
        __syncthreads();           // next tile landed; curb reads done before overwrite
    }
#pragma unroll
    for (int mt = 0; mt < 4; mt++) {
#pragma unroll
        for (int r = 0; r < 4; r++) {
            int gm = row0 + wr * 64 + mt * 16 + kg * 4 + r;
            if (gm >= M) continue;
#pragma unroll
            for (int nt = 0; nt < 4; nt++) {
                int gn = col0 + wc * 64 + nt * 16 + r16;
                float v = acc[mt][nt][r];
                if constexpr (MODE == 1) {
                    v += bias[gn];
                    v = 0.5f * v * (1.f + erff(v * 0.70710678118f));
                }
                if constexpr (MODE == 2) {
                    v += bias[gn] + resid[(size_t)gm * N + gn];
                    ((float*)Cout)[(size_t)gm * N + gn] = v;
                } else {
                    ((u16*)Cout)[(size_t)gm * N + gn] = f2b(v);
                }
            }
        }
    }
}

// ---------------- cls attention pass 1: per-chunk partial softmax + PV ----------------
__global__ void cls_partial_kernel(const u16* __restrict__ qkv, float* __restrict__ part) {
    int c = blockIdx.x, bh = blockIdx.y;
    int b = bh / HEADS, hh = bh % HEADS;
    int tid = threadIdx.x;
    int wave = tid >> 6, lane = tid & 63;
    __shared__ float s_q[HD];
    __shared__ float s_sc[CLS_CH];
    __shared__ float sm[4], ss[4];
    __shared__ float sacc[4][HD];
    if (tid < HD) s_q[tid] = b2f(qkv[(size_t)(b * NN) * 2304 + hh * HD + tid]);
    __syncthreads();

    int j0 = c * CLS_CH;
    int j = j0 + tid;
    float sc = -1e30f;
    if (j < NN) {
        const short8* kp = (const short8*)(qkv + ((size_t)(b * NN) + j) * 2304 + C + hh * HD);
        float acc = 0.f;
#pragma unroll
        for (int u = 0; u < 8; u++) {
            short8 kv = kp[u];
#pragma unroll
            for (int e = 0; e < 8; e++) acc += s_q[u * 8 + e] * b2f((u16)kv[e]);
        }
        sc = acc * 0.125f;
    }
    float m = sc;
    for (int off = 32; off; off >>= 1) m = fmaxf(m, __shfl_xor(m, off));
    if (lane == 0) sm[wave] = m;
    __syncthreads();
    m = fmaxf(fmaxf(sm[0], sm[1]), fmaxf(sm[2], sm[3]));
    float e = (j < NN) ? __expf(sc - m) : 0.f;
    s_sc[tid] = e;
    float su = e;
    for (int off = 32; off; off >>= 1) su += __shfl_xor(su, off);
    if (lane == 0) ss[wave] = su;
    __syncthreads();
    float ssum = ss[0] + ss[1] + ss[2] + ss[3];

    int jj = tid >> 6, d = tid & 63;
    int jmax = NN - j0; if (jmax > CLS_CH) jmax = CLS_CH;
    const u16* vcol = qkv + ((size_t)(b * NN) + j0) * 2304 + 2 * C + hh * HD + d;
    float acc = 0.f;
    for (int t = jj; t < jmax; t += 4)
        acc += s_sc[t] * b2f(vcol[(size_t)t * 2304]);
    sacc[jj][d] = acc;
    __syncthreads();
    if (tid < HD) {
        float pv = sacc[0][tid] + sacc[1][tid] + sacc[2][tid] + sacc[3][tid];
        float* pp = part + ((size_t)bh * CLS_NC + c) * 66;
        pp[2 + tid] = pv;
        if (tid == 0) { pp[0] = m; pp[1] = ssum; }
    }
}

// ---------------- cls attention pass 2: merge chunk partials ----------------
__global__ void cls_reduce_kernel(const float* __restrict__ part, u16* __restrict__ y) {
    int bh = blockIdx.x;
    int b = bh / HEADS, hh = bh % HEADS;
    int d = threadIdx.x;   // 64
    float gm = -1e30f;
#pragma unroll
    for (int c = 0; c < CLS_NC; c++)
        gm = fmaxf(gm, part[((size_t)bh * CLS_NC + c) * 66]);
    float tot = 0.f, pv = 0.f;
#pragma unroll
    for (int c = 0; c < CLS_NC; c++) {
        const float* pp = part + ((size_t)bh * CLS_NC + c) * 66;
        float w = __expf(pp[0] - gm);
        tot += pp[1] * w;
        pv  += pp[2 + d] * w;
    }
    y[(size_t)(b * NN) * C + hh * HD + d] = f2b(pv / tot);
}

// ---------------- repack K: qkv_b -> Kb[bh][f][208][64], pad rows zeroed ----------------
__global__ void repack_k_kernel(const u16* __restrict__ qkv, u16* __restrict__ Kb) {
    int t = blockIdx.x * 256 + threadIdx.x;
    if (t >= 24 * NF * 208 * 8) return;
    int d8 = t & 7;
    int rest = t >> 3;
    int n = rest % 208;
    rest /= 208;
    int f = rest % NF;
    int bh = rest / NF;
    int b = bh / HEADS, h = bh % HEADS;
    short8 v = {0, 0, 0, 0, 0, 0, 0, 0};
    if (n < SL)
        v = *(const short8*)(qkv + ((size_t)(b * NN) + 1 + f * SL + n) * 2304 + C + h * HD + d8 * 8);
    *(short8*)(Kb + (((size_t)bh * NF + f) * 208 + n) * 64 + d8 * 8) = v;
}

// ---------------- repack V: qkv_b -> Vt[bh][f][d][224] (transposed, pad zeroed) ----------------
__global__ void repack_v_kernel(const u16* __restrict__ qkv, u16* __restrict__ Vt) {
    int t = blockIdx.x * 256 + threadIdx.x;
    if (t >= 24 * NF * 64 * 28) return;
    int n8 = t % 28;
    int rest = t / 28;
    int d = rest % 64;
    rest /= 64;
    int f = rest % NF;
    int bh = rest / NF;
    int b = bh / HEADS, h = bh % HEADS;
    int n0 = n8 * 8;
    const u16* src = qkv + ((size_t)(b * NN) + 1 + f * SL) * 2304 + 2 * C + h * HD + d;
    short8 v;
#pragma unroll
    for (int j = 0; j < 8; j++) {
        int n = n0 + j;
        v[j] = (n < SL) ? (short)src[(size_t)n * 2304] : (short)0;
    }
    *(short8*)(Vt + (((size_t)bh * NF + f) * 64 + d) * 224 + n0) = v;
}

// ---------------- MFMA spatial attention v2 ----------------
__global__ void space_attn_mfma(
    const u16* __restrict__ qkv, const u16* __restrict__ Kb,
    const u16* __restrict__ Vt, u16* __restrict__ x1) {
    __shared__ u16 smem[28160];  // [0,26624)B: swizzled K_f; rest: 4 x 7424B P bufs
    int tid = threadIdx.x;
    int lane = tid & 63, wave = tid >> 6;
    int r16 = lane & 15, kg = lane >> 4;
    int f = blockIdx.y, bh = blockIdx.z;
    int b = bh / HEADS, h = bh % HEADS;

    const char* kb_g = (const char*)(Kb + ((size_t)bh * NF + f) * 208 * 64);
    for (int w = wave; w < 26; w += 4) {
        int p = w * 1024 + lane * 16;
        int row = p >> 7;
        int src = (p & ~127) | ((p & 127) ^ ((row & 7) << 4));
        gload_lds16(kb_g + src, (char*)smem + p);
    }
    __syncthreads();

    int strip = blockIdx.x * 4 + wave;
    if (strip >= 98) return;
    int q0 = strip * 16;

    const u16* qrow = qkv + ((size_t)(b * NN) + 1 + q0 + r16) * 2304 + h * HD + kg * 8;
    short8 aq0 = *(const short8*)(qrow);
    short8 aq1 = *(const short8*)(qrow + 32);

    f32x4 acc[13];
#pragma unroll
    for (int t = 0; t < 13; t++) acc[t] = (f32x4){0.f, 0.f, 0.f, 0.f};
    const char* ksm = (const char*)smem;
    int swz = (r16 & 7) << 4;
#pragma unroll
    for (int t = 0; t < 13; t++) {
        const char* krow = ksm + (t * 16 + r16) * 128;
        short8 bk0 = *(const short8*)(krow + ((kg * 16) ^ swz));
        short8 bk1 = *(const short8*)(krow + ((64 + kg * 16) ^ swz));
        acc[t] = __builtin_amdgcn_mfma_f32_16x16x32_bf16(aq0, bk0, acc[t], 0, 0, 0);
        acc[t] = __builtin_amdgcn_mfma_f32_16x16x32_bf16(aq1, bk1, acc[t], 0, 0, 0);
    }

    bool tail_mask = (r16 >= 4);
    float mrow[4] = {-1e30f, -1e30f, -1e30f, -1e30f};
#pragma unroll
    for (int t = 0; t < 13; t++) {
        if (t == 12 && tail_mask) continue;
#pragma unroll
        for (int r = 0; r < 4; r++) mrow[r] = fmaxf(mrow[r], acc[t][r] * 0.125f);
    }
#pragma unroll
    for (int off = 8; off; off >>= 1)
#pragma unroll
        for (int r = 0; r < 4; r++) mrow[r] = fmaxf(mrow[r], __shfl_xor(mrow[r], off));

    float ssum[4] = {0.f, 0.f, 0.f, 0.f};
#pragma unroll
    for (int t = 0; t < 13; t++) {
#pragma unroll
        for (int r = 0; r < 4; r++) {
            float p = (t == 12 && tail_mask) ? 0.f : __expf(acc[t][r] * 0.125f - mrow[r]);
            acc[t][r] = p;
            ssum[r] += p;
        }
    }
#pragma unroll
    for (int off = 8; off; off >>= 1)
#pragma unroll
        for (int r = 0; r < 4; r++) ssum[r] += __shfl_xor(ssum[r], off);
    float inv[4];
#pragma unroll
    for (int r = 0; r < 4; r++) inv[r] = 1.f / ssum[r];

    u16* pb = smem + 13312 + wave * 3712;
#pragma unroll
    for (int t = 0; t < 13; t++)
#pragma unroll
        for (int r = 0; r < 4; r++)
            pb[(kg * 4 + r) * 232 + t * 16 + r16] = f2b(acc[t][r]);
    {
        int zr = lane >> 2, zc = 208 + (lane & 3) * 4;
        *(uint2*)(&pb[zr * 232 + zc]) = (uint2){0u, 0u};
    }

    f32x4 o[4];
#pragma unroll
    for (int dt = 0; dt < 4; dt++) o[dt] = (f32x4){0.f, 0.f, 0.f, 0.f};
    const u16* vbase = Vt + ((size_t)bh * NF + f) * 64 * 224;
#pragma unroll
    for (int kc = 0; kc < 7; kc++) {
        short8 pa = *(const short8*)(&pb[r16 * 232 + kc * 32 + kg * 8]);
#pragma unroll
        for (int dt = 0; dt < 4; dt++) {
            short8 bv = *(const short8*)(vbase + (dt * 16 + r16) * 224 + kc * 32 + kg * 8);
            o[dt] = __builtin_amdgcn_mfma_f32_16x16x32_bf16(pa, bv, o[dt], 0, 0, 0);
        }
    }

#pragma unroll
    for (int dt = 0; dt < 4; dt++)
#pragma unroll
        for (int r = 0; r < 4; r++) {
            int q = q0 + kg * 4 + r;
            x1[(((size_t)(b * SS + q)) * NF + f) * C + h * HD + dt * 16 + r16] = f2b(o[dt][r] * inv[r]);
        }
}

// ---------------- diagonal gather (bf16): xd[b,s,:] = x1[b,s,s/SL,:] ----------------
__global__ void diag_kernel(const u16* __restrict__ x1, u16* __restrict__ xd) {
    int i = blockIdx.x * 256 + threadIdx.x;
    int total = BB * SS * (C / 8);
    if (i >= total) return;
    int c8 = i % (C / 8);
    int row = i / (C / 8);
    int s = row % SS;
    int f = s / SL;
    ((short8*)(xd + (size_t)row * C))[c8] =
        ((const short8*)(x1 + (((size_t)row) * NF + f) * C))[c8];
}

// ---------------- temporal attention (bf16 in, bf16 out) ----------------
__global__ void attn2_kernel(const u16* __restrict__ q2, const u16* __restrict__ k2,
                             const u16* __restrict__ x1, u16* __restrict__ y) {
    int item = blockIdx.x * 4 + (threadIdx.x >> 6);
    if (item >= BB * HEADS * SS) return;
    int lane = threadIdx.x & 63;
    int s = item % SS;
    int bh = item / SS;
    int b = bh / HEADS, hh = bh % HEADS;
    size_t rowbs = (size_t)(b * SS + s);
    float qv = b2f(q2[rowbs * C + hh * HD + lane]) * 0.125f;
    float lg[NF];
#pragma unroll
    for (int f = 0; f < NF; f++) {
        float p = qv * b2f(k2[(rowbs * NF + f) * C + hh * HD + lane]);
        for (int off = 32; off; off >>= 1) p += __shfl_xor(p, off);
        lg[f] = p;
    }
    float m = lg[0];
#pragma unroll
    for (int f = 1; f < NF; f++) m = fmaxf(m, lg[f]);
    float sum = 0.f;
#pragma unroll
    for (int f = 0; f < NF; f++) { lg[f] = __expf(lg[f] - m); sum += lg[f]; }
    float inv = 1.f / sum;
    float acc = 0.f;
#pragma unroll
    for (int f = 0; f < NF; f++) acc += lg[f] * b2f(x1[(rowbs * NF + f) * C + hh * HD + lane]);
    y[((size_t)(b * NN) + 1 + s) * C + hh * HD + lane] = f2b(acc * inv);
}

extern "C" void kernel_launch(void* const* d_in, const int* in_sizes, int n_in,
                              void* d_out, int out_size, void* d_ws, size_t ws_size,
                              hipStream_t stream) {
    const float* x    = (const float*)d_in[0];
    const float* g1   = (const float*)d_in[1];
    const float* b1   = (const float*)d_in[2];
    const float* Wqkv = (const float*)d_in[3];
    const float* Wq   = (const float*)d_in[4];
    const float* Wkv  = (const float*)d_in[5];
    const float* Wp   = (const float*)d_in[6];
    const float* bp   = (const float*)d_in[7];
    const float* g2   = (const float*)d_in[8];
    const float* b2_  = (const float*)d_in[9];
    const float* W1   = (const float*)d_in[10];
    const float* bf1  = (const float*)d_in[11];
    const float* W2   = (const float*)d_in[12];
    const float* bf2  = (const float*)d_in[13];
    float* out = (float*)d_out;

    // workspace layout (u16 elements)
    u16* us     = (u16*)d_ws;
    u16* xn_b   = us;                    // M1*768    (reused as hn after LN2)
    u16* qkv_b  = xn_b   + 2409984;      // M1*2304
    u16* Wt_qkv = qkv_b  + 7229952;      // 2304*768
    u16* Wt_q   = Wt_qkv + 1769472;      // 768*768
    u16* Wt_kv  = Wt_q   + 589824;       // 768*768 (first half of Wkv)
    u16* Wt_p   = Wt_kv  + 589824;       // 768*768
    u16* W1t    = Wt_p   + 589824;       // 3072*768
    u16* W2t    = W1t    + 2359296;      // 768*3072
    u16* Kb     = W2t    + 2359296;      // 24*8*208*64
    u16* Vt     = Kb     + 2555904;      // 24*8*64*224
    u16* x1b    = Vt     + 2752512;      // B*S*F*C
    u16* xdb    = x1b    + 19267584;     // B*S*C
    u16* q2b    = xdb    + 2408448;      // B*S*C
    u16* k2b    = q2b    + 2408448;      // B*S*F*C
    u16* y_b    = k2b    + 19267584;     // B*N*C
    u16* a1b    = y_b    + 2409984;      // B*N*HID
    float* cls_ws = (float*)(a1b + 9639936);  // 24*7*66 floats

    const int M1 = BB * NN;       // 3138
    const int M2 = BB * SS;       // 3136
    const int M3 = BB * SS * NF;  // 25088

    // 0. weight transpose + bf16 convert
    wtrans_kernel<<<dim3(2304 / 64, 768 / 64), 256, 0, stream>>>(Wqkv, Wt_qkv, 768, 2304, 2304);
    wtrans_kernel<<<dim3(768 / 64, 768 / 64), 256, 0, stream>>>(Wq, Wt_q, 768, 768, 768);
    wtrans_kernel<<<dim3(768 / 64, 768 / 64), 256, 0, stream>>>(Wkv, Wt_kv, 768, 768, 1536);
    wtrans_kernel<<<dim3(768 / 64, 768 / 64), 256, 0, stream>>>(Wp, Wt_p, 768, 768, 768);
    wtrans_kernel<<<dim3(3072 / 64, 768 / 64), 256, 0, stream>>>(W1, W1t, 768, 3072, 3072);
    wtrans_kernel<<<dim3(768 / 64, 3072 / 64), 256, 0, stream>>>(W2, W2t, 3072, 768, 768);
    // 1. LN1 -> bf16
    ln_kernel<<<M1, 256, 0, stream>>>(x, g1, b1, xn_b, M1);
    // 2. qkv_b = xn_b @ Wqkv (bf16 out)
    gemm_bf16<0><<<dim3(2304 / 128, (M1 + 127) / 128), 256, 0, stream>>>(
        xn_b, Wt_qkv, nullptr, nullptr, qkv_b, M1, 2304, 768);
    // 3. repack K, V
    repack_k_kernel<<<(24 * NF * 208 * 8 + 255) / 256, 256, 0, stream>>>(qkv_b, Kb);
    repack_v_kernel<<<(24 * NF * 64 * 28 + 255) / 256, 256, 0, stream>>>(qkv_b, Vt);
    // 4. cls attention (two-pass flash-style) -> y_b row 0
    cls_partial_kernel<<<dim3(CLS_NC, BB * HEADS), 256, 0, stream>>>(qkv_b, cls_ws);
    cls_reduce_kernel<<<BB * HEADS, 64, 0, stream>>>(cls_ws, y_b);
    // 5. spatial attention -> x1b (4-wave blocks, K in LDS)
    space_attn_mfma<<<dim3(25, NF, 24), 256, 0, stream>>>(qkv_b, Kb, Vt, x1b);
    // 6. diag gather
    diag_kernel<<<(BB * SS * (C / 8) + 255) / 256, 256, 0, stream>>>(x1b, xdb);
    // 7. q2 = xd @ Wq
    gemm_bf16<0><<<dim3(768 / 128, (M2 + 127) / 128), 256, 0, stream>>>(
        xdb, Wt_q, nullptr, nullptr, q2b, M2, 768, 768);
    // 8. k2 = x1 @ Wkv[:, :C]
    gemm_bf16<0><<<dim3(768 / 128, M3 / 128), 256, 0, stream>>>(
        x1b, Wt_kv, nullptr, nullptr, k2b, M3, 768, 768);
    // 9. temporal attention -> y_b rows 1..S
    attn2_kernel<<<(BB * HEADS * SS + 3) / 4, 256, 0, stream>>>(q2b, k2b, x1b, y_b);
    // 10. proj: out = y_b @ Wp + bp + x  (f32)
    gemm_bf16<2><<<dim3(768 / 128, (M1 + 127) / 128), 256, 0, stream>>>(
        y_b, Wt_p, bp, x, out, M1, 768, 768);
    // 11. LN2 -> bf16 (reuse xn_b)
    ln_kernel<<<M1, 256, 0, stream>>>(out, g2, b2_, xn_b, M1);
    // 12. fc1 + exact GELU -> bf16
    gemm_bf16<1><<<dim3(3072 / 128, (M1 + 127) / 128), 256, 0, stream>>>(
        xn_b, W1t, bf1, nullptr, a1b, M1, 3072, 768);
    // 13. fc2 + bias + residual (f32, in-place on d_out)
    gemm_bf16<2><<<dim3(768 / 128, (M1 + 127) / 128), 256, 0, stream>>>(
        a1b, W2t, bf2, out, out, M1, 768, 3072);
}

// Round 9
// 365.732 us; speedup vs baseline: 13.0944x; 1.0076x over previous
//
#include <hip/hip_runtime.h>
#include <hip/hip_bf16.h>
#include <math.h>

#define C     768
#define HEADS 12
#define HD    64
#define NF    8
#define SL    196
#define BB    2
#define NN    1569   // 1 + NF*SL
#define SS    1568   // NF*SL
#define HID   3072
#define CLS_CH 256
#define CLS_NC 7     // ceil(NN / CLS_CH)
#define QSCALE 0.18033688011112042f   // 0.125 * log2(e); scores live in log2 domain

typedef __attribute__((ext_vector_type(8))) short short8;
typedef __attribute__((ext_vector_type(4))) float f32x4;
typedef unsigned short u16;

__device__ inline float fast_exp2(float x) { return __builtin_amdgcn_exp2f(x); }

__device__ inline u16 f2b(float f) {
    __hip_bfloat16 h = __float2bfloat16(f);   // HW v_cvt path (RNE)
    return *reinterpret_cast<u16*>(&h);
}
__device__ inline float b2f(u16 u) {
    union { unsigned u; float f; } v; v.u = ((unsigned)u) << 16;
    return v.f;
}

__device__ inline void gload_lds16(const void* g, void* l) {
    __builtin_amdgcn_global_load_lds(
        (const __attribute__((address_space(1))) void*)g,
        (__attribute__((address_space(3))) void*)l, 16, 0, 0);
}

// ---------------- LayerNorm: f32 in -> bf16 out ----------------
__global__ void ln_kernel(const float* __restrict__ x, const float* __restrict__ g,
                          const float* __restrict__ b, u16* __restrict__ out, int rows) {
    int row = blockIdx.x;
    if (row >= rows) return;
    const float* xr = x + (size_t)row * C;
    int tid = threadIdx.x;
    float v[3];
    float sum = 0.f, sumsq = 0.f;
#pragma unroll
    for (int i = 0; i < 3; i++) {
        v[i] = xr[tid + 256 * i];
        sum += v[i]; sumsq += v[i] * v[i];
    }
    __shared__ float s1[4], s2[4];
    for (int off = 32; off; off >>= 1) {
        sum   += __shfl_xor(sum, off);
        sumsq += __shfl_xor(sumsq, off);
    }
    int wave = tid >> 6, lane = tid & 63;
    if (lane == 0) { s1[wave] = sum; s2[wave] = sumsq; }
    __syncthreads();
    sum   = s1[0] + s1[1] + s1[2] + s1[3];
    sumsq = s2[0] + s2[1] + s2[2] + s2[3];
    float mu  = sum / C;
    float var = sumsq / C - mu * mu;
    float rstd = rsqrtf(fmaxf(var, 0.f) + 1e-5f);
    u16* outr = out + (size_t)row * C;
#pragma unroll
    for (int i = 0; i < 3; i++) {
        int c = tid + 256 * i;
        outr[c] = f2b((v[i] - mu) * rstd * g[c] + b[c]);
    }
}

// ---------------- weight transpose+convert: W[K][ldb] (first N cols) -> Wt[N][K] bf16 ----------
__global__ void wtrans_kernel(const float* __restrict__ W, u16* __restrict__ Wt,
                              int K, int N, int ldb) {
    __shared__ float tile[64][65];
    int nb = blockIdx.x * 64, kb = blockIdx.y * 64;
    int tx = threadIdx.x & 63, ty = threadIdx.x >> 6;
#pragma unroll
    for (int i = 0; i < 64; i += 4)
        tile[ty + i][tx] = W[(size_t)(kb + ty + i) * ldb + nb + tx];
    __syncthreads();
#pragma unroll
    for (int i = 0; i < 64; i += 4)
        Wt[(size_t)(nb + ty + i) * K + kb + tx] = f2b(tile[tx][ty + i]);
}

// ---------------- bf16 MFMA GEMM (2-phase double-buffered): C = A(MxK) @ Bt(NxK)^T ----------
// MODE 0: bf16 out. MODE 1: bf16 out, bias + exact GELU. MODE 2: f32 out, bias + resid.
// MODE 3: bf16 out, cols < 768 scaled by QSCALE (qkv GEMM: q pre-scaled into log2 domain).
template<int MODE>
__global__ __launch_bounds__(256) void gemm_bf16(
    const u16* __restrict__ A, const u16* __restrict__ Bt,
    const float* __restrict__ bias, const float* resid, void* Cout,
    int M, int N, int K) {
    __shared__ char smem[32768];   // 2 x (As 8KB + Bs 8KB)
    int tid = threadIdx.x, lane = tid & 63, wave = tid >> 6;
    int wr = wave >> 1, wc = wave & 1;
    int r16 = lane & 15, kg = lane >> 4;
    int row0 = blockIdx.y * 128, col0 = blockIdx.x * 128;
    f32x4 acc[4][4];
#pragma unroll
    for (int mt = 0; mt < 4; mt++)
#pragma unroll
        for (int nt = 0; nt < 4; nt++) acc[mt][nt] = (f32x4){0.f, 0.f, 0.f, 0.f};

    auto stage = [&](char* dstbase, int ks) {
        int k0 = ks << 5;
#pragma unroll
        for (int it = 0; it < 4; it++) {
            int c = it * 256 + tid;
            const u16* src;
            if (c < 512) {
                int ml = c >> 2, s = c & 3;
                int kgs = s ^ ((ml >> 1) & 3);
                int gm = row0 + ml; if (gm >= M) gm = M - 1;
                src = A + (size_t)gm * K + k0 + kgs * 8;
            } else {
                int cc = c - 512;
                int nl = cc >> 2, s = cc & 3;
                int kgs = s ^ ((nl >> 1) & 3);
                src = Bt + (size_t)(col0 + nl) * K + k0 + kgs * 8;
            }
            gload_lds16(src, dstbase + it * 4096 + wave * 1024);
        }
    };

    int nsteps = K >> 5;
    stage(smem, 0);
    __syncthreads();               // drains vmcnt: tile 0 resident
    for (int ks = 0; ks < nsteps; ks++) {
        char* curb = smem + (ks & 1) * 16384;
        if (ks + 1 < nsteps) stage(smem + ((ks + 1) & 1) * 16384, ks + 1);
        short8 af[4], bfr[4];
#pragma unroll
        for (int mt = 0; mt < 4; mt++) {
            int ml = wr * 64 + mt * 16 + r16;
            af[mt] = *(const short8*)(curb + ml * 64 + ((kg ^ ((ml >> 1) & 3)) << 4));
        }
#pragma unroll
        for (int nt = 0; nt < 4; nt++) {
            int nl = wc * 64 + nt * 16 + r16;
            bfr[nt] = *(const short8*)(curb + 8192 + nl * 64 + ((kg ^ ((nl >> 1) & 3)) << 4));
        }
        __builtin_amdgcn_s_setprio(1);
#pragma unroll
        for (int mt = 0; mt < 4; mt++)
#pragma unroll
            for (int nt = 0; nt < 4; nt++)
                acc[mt][nt] = __builtin_amdgcn_mfma_f32_16x16x32_bf16(af[mt], bfr[nt], acc[mt][nt], 0, 0, 0);
        __builtin_amdgcn_s_setprio(0);
        __syncthreads();           // next tile landed; curb reads done before overwrite
    }
#pragma unroll
    for (int mt = 0; mt < 4; mt++) {
#pragma unroll
        for (int r = 0; r < 4; r++) {
            int gm = row0 + wr * 64 + mt * 16 + kg * 4 + r;
            if (gm >= M) continue;
#pragma unroll
            for (int nt = 0; nt < 4; nt++) {
                int gn = col0 + wc * 64 + nt * 16 + r16;
                float v = acc[mt][nt][r];
                if constexpr (MODE == 1) {
                    v += bias[gn];
                    v = 0.5f * v * (1.f + erff(v * 0.70710678118f));
                }
                if constexpr (MODE == 2) {
                    v += bias[gn] + resid[(size_t)gm * N + gn];
                    ((float*)Cout)[(size_t)gm * N + gn] = v;
                } else {
                    if constexpr (MODE == 3) { if (gn < 768) v *= QSCALE; }
                    ((u16*)Cout)[(size_t)gm * N + gn] = f2b(v);
                }
            }
        }
    }
}

// ---------------- cls attention pass 1 (q pre-scaled; log2-domain softmax) ----------------
__global__ void cls_partial_kernel(const u16* __restrict__ qkv, float* __restrict__ part) {
    int c = blockIdx.x, bh = blockIdx.y;
    int b = bh / HEADS, hh = bh % HEADS;
    int tid = threadIdx.x;
    int wave = tid >> 6, lane = tid & 63;
    __shared__ float s_q[HD];
    __shared__ float s_sc[CLS_CH];
    __shared__ float sm[4], ss[4];
    __shared__ float sacc[4][HD];
    if (tid < HD) s_q[tid] = b2f(qkv[(size_t)(b * NN) * 2304 + hh * HD + tid]);
    __syncthreads();

    int j0 = c * CLS_CH;
    int j = j0 + tid;
    float sc = -1e30f;
    if (j < NN) {
        const short8* kp = (const short8*)(qkv + ((size_t)(b * NN) + j) * 2304 + C + hh * HD);
        float acc = 0.f;
#pragma unroll
        for (int u = 0; u < 8; u++) {
            short8 kv = kp[u];
#pragma unroll
            for (int e = 0; e < 8; e++) acc += s_q[u * 8 + e] * b2f((u16)kv[e]);
        }
        sc = acc;     // already in log2 domain (q pre-scaled by QSCALE)
    }
    float m = sc;
    for (int off = 32; off; off >>= 1) m = fmaxf(m, __shfl_xor(m, off));
    if (lane == 0) sm[wave] = m;
    __syncthreads();
    m = fmaxf(fmaxf(sm[0], sm[1]), fmaxf(sm[2], sm[3]));
    float e = (j < NN) ? fast_exp2(sc - m) : 0.f;
    s_sc[tid] = e;
    float su = e;
    for (int off = 32; off; off >>= 1) su += __shfl_xor(su, off);
    if (lane == 0) ss[wave] = su;
    __syncthreads();
    float ssum = ss[0] + ss[1] + ss[2] + ss[3];

    int jj = tid >> 6, d = tid & 63;
    int jmax = NN - j0; if (jmax > CLS_CH) jmax = CLS_CH;
    const u16* vcol = qkv + ((size_t)(b * NN) + j0) * 2304 + 2 * C + hh * HD + d;
    float acc = 0.f;
    for (int t = jj; t < jmax; t += 4)
        acc += s_sc[t] * b2f(vcol[(size_t)t * 2304]);
    sacc[jj][d] = acc;
    __syncthreads();
    if (tid < HD) {
        float pv = sacc[0][tid] + sacc[1][tid] + sacc[2][tid] + sacc[3][tid];
        float* pp = part + ((size_t)bh * CLS_NC + c) * 66;
        pp[2 + tid] = pv;
        if (tid == 0) { pp[0] = m; pp[1] = ssum; }
    }
}

// ---------------- cls attention pass 2: merge chunk partials (log2 domain) ----------------
__global__ void cls_reduce_kernel(const float* __restrict__ part, u16* __restrict__ y) {
    int bh = blockIdx.x;
    int b = bh / HEADS, hh = bh % HEADS;
    int d = threadIdx.x;   // 64
    float gm = -1e30f;
#pragma unroll
    for (int c = 0; c < CLS_NC; c++)
        gm = fmaxf(gm, part[((size_t)bh * CLS_NC + c) * 66]);
    float tot = 0.f, pv = 0.f;
#pragma unroll
    for (int c = 0; c < CLS_NC; c++) {
        const float* pp = part + ((size_t)bh * CLS_NC + c) * 66;
        float w = fast_exp2(pp[0] - gm);
        tot += pp[1] * w;
        pv  += pp[2 + d] * w;
    }
    y[(size_t)(b * NN) * C + hh * HD + d] = f2b(pv / tot);
}

// ---------------- repack K: qkv_b -> Kb[bh][f][208][64], pad rows zeroed ----------------
__global__ void repack_k_kernel(const u16* __restrict__ qkv, u16* __restrict__ Kb) {
    int t = blockIdx.x * 256 + threadIdx.x;
    if (t >= 24 * NF * 208 * 8) return;
    int d8 = t & 7;
    int rest = t >> 3;
    int n = rest % 208;
    rest /= 208;
    int f = rest % NF;
    int bh = rest / NF;
    int b = bh / HEADS, h = bh % HEADS;
    short8 v = {0, 0, 0, 0, 0, 0, 0, 0};
    if (n < SL)
        v = *(const short8*)(qkv + ((size_t)(b * NN) + 1 + f * SL + n) * 2304 + C + h * HD + d8 * 8);
    *(short8*)(Kb + (((size_t)bh * NF + f) * 208 + n) * 64 + d8 * 8) = v;
}

// ---------------- repack V: qkv_b -> Vt[bh][f][d][224] (transposed, pad zeroed) ----------------
__global__ void repack_v_kernel(const u16* __restrict__ qkv, u16* __restrict__ Vt) {
    int t = blockIdx.x * 256 + threadIdx.x;
    if (t >= 24 * NF * 64 * 28) return;
    int n8 = t % 28;
    int rest = t / 28;
    int d = rest % 64;
    rest /= 64;
    int f = rest % NF;
    int bh = rest / NF;
    int b = bh / HEADS, h = bh % HEADS;
    int n0 = n8 * 8;
    const u16* src = qkv + ((size_t)(b * NN) + 1 + f * SL) * 2304 + 2 * C + h * HD + d;
    short8 v;
#pragma unroll
    for (int j = 0; j < 8; j++) {
        int n = n0 + j;
        v[j] = (n < SL) ? (short)src[(size_t)n * 2304] : (short)0;
    }
    *(short8*)(Vt + (((size_t)bh * NF + f) * 64 + d) * 224 + n0) = v;
}

// ---------------- MFMA spatial attention (q pre-scaled; log2-domain softmax) ----------------
__global__ void space_attn_mfma(
    const u16* __restrict__ qkv, const u16* __restrict__ Kb,
    const u16* __restrict__ Vt, u16* __restrict__ x1) {
    __shared__ u16 smem[28160];  // [0,26624)B: swizzled K_f; rest: 4 x 7424B P bufs
    int tid = threadIdx.x;
    int lane = tid & 63, wave = tid >> 6;
    int r16 = lane & 15, kg = lane >> 4;
    int f = blockIdx.y, bh = blockIdx.z;
    int b = bh / HEADS, h = bh % HEADS;

    const char* kb_g = (const char*)(Kb + ((size_t)bh * NF + f) * 208 * 64);
    for (int w = wave; w < 26; w += 4) {
        int p = w * 1024 + lane * 16;
        int row = p >> 7;
        int src = (p & ~127) | ((p & 127) ^ ((row & 7) << 4));
        gload_lds16(kb_g + src, (char*)smem + p);
    }
    __syncthreads();

    int strip = blockIdx.x * 4 + wave;
    if (strip >= 98) return;
    int q0 = strip * 16;

    const u16* qrow = qkv + ((size_t)(b * NN) + 1 + q0 + r16) * 2304 + h * HD + kg * 8;
    short8 aq0 = *(const short8*)(qrow);
    short8 aq1 = *(const short8*)(qrow + 32);

    f32x4 acc[13];
#pragma unroll
    for (int t = 0; t < 13; t++) acc[t] = (f32x4){0.f, 0.f, 0.f, 0.f};
    const char* ksm = (const char*)smem;
    int swz = (r16 & 7) << 4;
    __builtin_amdgcn_s_setprio(1);
#pragma unroll
    for (int t = 0; t < 13; t++) {
        const char* krow = ksm + (t * 16 + r16) * 128;
        short8 bk0 = *(const short8*)(krow + ((kg * 16) ^ swz));
        short8 bk1 = *(const short8*)(krow + ((64 + kg * 16) ^ swz));
        acc[t] = __builtin_amdgcn_mfma_f32_16x16x32_bf16(aq0, bk0, acc[t], 0, 0, 0);
        acc[t] = __builtin_amdgcn_mfma_f32_16x16x32_bf16(aq1, bk1, acc[t], 0, 0, 0);
    }
    __builtin_amdgcn_s_setprio(0);

    // scores already in log2 domain (q pre-scaled by QSCALE in qkv epilogue)
    bool tail_mask = (r16 >= 4);
    float mrow[4] = {-1e30f, -1e30f, -1e30f, -1e30f};
#pragma unroll
    for (int t = 0; t < 13; t++) {
        if (t == 12 && tail_mask) continue;
#pragma unroll
        for (int r = 0; r < 4; r++) mrow[r] = fmaxf(mrow[r], acc[t][r]);
    }
#pragma unroll
    for (int off = 8; off; off >>= 1)
#pragma unroll
        for (int r = 0; r < 4; r++) mrow[r] = fmaxf(mrow[r], __shfl_xor(mrow[r], off));

    float ssum[4] = {0.f, 0.f, 0.f, 0.f};
#pragma unroll
    for (int t = 0; t < 13; t++) {
#pragma unroll
        for (int r = 0; r < 4; r++) {
            float p = (t == 12 && tail_mask) ? 0.f : fast_exp2(acc[t][r] - mrow[r]);
            acc[t][r] = p;
            ssum[r] += p;
        }
    }
#pragma unroll
    for (int off = 8; off; off >>= 1)
#pragma unroll
        for (int r = 0; r < 4; r++) ssum[r] += __shfl_xor(ssum[r], off);
    float inv[4];
#pragma unroll
    for (int r = 0; r < 4; r++) inv[r] = 1.f / ssum[r];

    u16* pb = smem + 13312 + wave * 3712;
#pragma unroll
    for (int t = 0; t < 13; t++)
#pragma unroll
        for (int r = 0; r < 4; r++)
            pb[(kg * 4 + r) * 232 + t * 16 + r16] = f2b(acc[t][r]);
    {
        int zr = lane >> 2, zc = 208 + (lane & 3) * 4;
        *(uint2*)(&pb[zr * 232 + zc]) = (uint2){0u, 0u};
    }

    f32x4 o[4];
#pragma unroll
    for (int dt = 0; dt < 4; dt++) o[dt] = (f32x4){0.f, 0.f, 0.f, 0.f};
    const u16* vbase = Vt + ((size_t)bh * NF + f) * 64 * 224;
    __builtin_amdgcn_s_setprio(1);
#pragma unroll
    for (int kc = 0; kc < 7; kc++) {
        short8 pa = *(const short8*)(&pb[r16 * 232 + kc * 32 + kg * 8]);
#pragma unroll
        for (int dt = 0; dt < 4; dt++) {
            short8 bv = *(const short8*)(vbase + (dt * 16 + r16) * 224 + kc * 32 + kg * 8);
            o[dt] = __builtin_amdgcn_mfma_f32_16x16x32_bf16(pa, bv, o[dt], 0, 0, 0);
        }
    }
    __builtin_amdgcn_s_setprio(0);

#pragma unroll
    for (int dt = 0; dt < 4; dt++)
#pragma unroll
        for (int r = 0; r < 4; r++) {
            int q = q0 + kg * 4 + r;
            x1[(((size_t)(b * SS + q)) * NF + f) * C + h * HD + dt * 16 + r16] = f2b(o[dt][r] * inv[r]);
        }
}

// ---------------- diagonal gather (bf16): xd[b,s,:] = x1[b,s,s/SL,:] ----------------
__global__ void diag_kernel(const u16* __restrict__ x1, u16* __restrict__ xd) {
    int i = blockIdx.x * 256 + threadIdx.x;
    int total = BB * SS * (C / 8);
    if (i >= total) return;
    int c8 = i % (C / 8);
    int row = i / (C / 8);
    int s = row % SS;
    int f = s / SL;
    ((short8*)(xd + (size_t)row * C))[c8] =
        ((const short8*)(x1 + (((size_t)row) * NF + f) * C))[c8];
}

// ---------------- temporal attention (log2-domain softmax) ----------------
__global__ void attn2_kernel(const u16* __restrict__ q2, const u16* __restrict__ k2,
                             const u16* __restrict__ x1, u16* __restrict__ y) {
    int item = blockIdx.x * 4 + (threadIdx.x >> 6);
    if (item >= BB * HEADS * SS) return;
    int lane = threadIdx.x & 63;
    int s = item % SS;
    int bh = item / SS;
    int b = bh / HEADS, hh = bh % HEADS;
    size_t rowbs = (size_t)(b * SS + s);
    float qv = b2f(q2[rowbs * C + hh * HD + lane]) * QSCALE;
    float lg[NF];
#pragma unroll
    for (int f = 0; f < NF; f++) {
        float p = qv * b2f(k2[(rowbs * NF + f) * C + hh * HD + lane]);
        for (int off = 32; off; off >>= 1) p += __shfl_xor(p, off);
        lg[f] = p;
    }
    float m = lg[0];
#pragma unroll
    for (int f = 1; f < NF; f++) m = fmaxf(m, lg[f]);
    float sum = 0.f;
#pragma unroll
    for (int f = 0; f < NF; f++) { lg[f] = fast_exp2(lg[f] - m); sum += lg[f]; }
    float inv = 1.f / sum;
    float acc = 0.f;
#pragma unroll
    for (int f = 0; f < NF; f++) acc += lg[f] * b2f(x1[(rowbs * NF + f) * C + hh * HD + lane]);
    y[((size_t)(b * NN) + 1 + s) * C + hh * HD + lane] = f2b(acc * inv);
}

extern "C" void kernel_launch(void* const* d_in, const int* in_sizes, int n_in,
                              void* d_out, int out_size, void* d_ws, size_t ws_size,
                              hipStream_t stream) {
    const float* x    = (const float*)d_in[0];
    const float* g1   = (const float*)d_in[1];
    const float* b1   = (const float*)d_in[2];
    const float* Wqkv = (const float*)d_in[3];
    const float* Wq   = (const float*)d_in[4];
    const float* Wkv  = (const float*)d_in[5];
    const float* Wp   = (const float*)d_in[6];
    const float* bp   = (const float*)d_in[7];
    const float* g2   = (const float*)d_in[8];
    const float* b2_  = (const float*)d_in[9];
    const float* W1   = (const float*)d_in[10];
    const float* bf1  = (const float*)d_in[11];
    const float* W2   = (const float*)d_in[12];
    const float* bf2  = (const float*)d_in[13];
    float* out = (float*)d_out;

    // workspace layout (u16 elements)
    u16* us     = (u16*)d_ws;
    u16* xn_b   = us;                    // M1*768    (reused as hn after LN2)
    u16* qkv_b  = xn_b   + 2409984;      // M1*2304
    u16* Wt_qkv = qkv_b  + 7229952;      // 2304*768
    u16* Wt_q   = Wt_qkv + 1769472;      // 768*768
    u16* Wt_kv  = Wt_q   + 589824;       // 768*768 (first half of Wkv)
    u16* Wt_p   = Wt_kv  + 589824;       // 768*768
    u16* W1t    = Wt_p   + 589824;       // 3072*768
    u16* W2t    = W1t    + 2359296;      // 768*3072
    u16* Kb     = W2t    + 2359296;      // 24*8*208*64
    u16* Vt     = Kb     + 2555904;      // 24*8*64*224
    u16* x1b    = Vt     + 2752512;      // B*S*F*C
    u16* xdb    = x1b    + 19267584;     // B*S*C
    u16* q2b    = xdb    + 2408448;      // B*S*C
    u16* k2b    = q2b    + 2408448;      // B*S*F*C
    u16* y_b    = k2b    + 19267584;     // B*N*C
    u16* a1b    = y_b    + 2409984;      // B*N*HID
    float* cls_ws = (float*)(a1b + 9639936);  // 24*7*66 floats

    const int M1 = BB * NN;       // 3138
    const int M2 = BB * SS;       // 3136
    const int M3 = BB * SS * NF;  // 25088

    // 0. weight transpose + bf16 convert
    wtrans_kernel<<<dim3(2304 / 64, 768 / 64), 256, 0, stream>>>(Wqkv, Wt_qkv, 768, 2304, 2304);
    wtrans_kernel<<<dim3(768 / 64, 768 / 64), 256, 0, stream>>>(Wq, Wt_q, 768, 768, 768);
    wtrans_kernel<<<dim3(768 / 64, 768 / 64), 256, 0, stream>>>(Wkv, Wt_kv, 768, 768, 1536);
    wtrans_kernel<<<dim3(768 / 64, 768 / 64), 256, 0, stream>>>(Wp, Wt_p, 768, 768, 768);
    wtrans_kernel<<<dim3(3072 / 64, 768 / 64), 256, 0, stream>>>(W1, W1t, 768, 3072, 3072);
    wtrans_kernel<<<dim3(768 / 64, 3072 / 64), 256, 0, stream>>>(W2, W2t, 3072, 768, 768);
    // 1. LN1 -> bf16
    ln_kernel<<<M1, 256, 0, stream>>>(x, g1, b1, xn_b, M1);
    // 2. qkv_b = xn_b @ Wqkv (bf16 out; q cols pre-scaled by QSCALE)
    gemm_bf16<3><<<dim3(2304 / 128, (M1 + 127) / 128), 256, 0, stream>>>(
        xn_b, Wt_qkv, nullptr, nullptr, qkv_b, M1, 2304, 768);
    // 3. repack K, V
    repack_k_kernel<<<(24 * NF * 208 * 8 + 255) / 256, 256, 0, stream>>>(qkv_b, Kb);
    repack_v_kernel<<<(24 * NF * 64 * 28 + 255) / 256, 256, 0, stream>>>(qkv_b, Vt);
    // 4. cls attention (two-pass flash-style) -> y_b row 0
    cls_partial_kernel<<<dim3(CLS_NC, BB * HEADS), 256, 0, stream>>>(qkv_b, cls_ws);
    cls_reduce_kernel<<<BB * HEADS, 64, 0, stream>>>(cls_ws, y_b);
    // 5. spatial attention -> x1b (4-wave blocks, K in LDS)
    space_attn_mfma<<<dim3(25, NF, 24), 256, 0, stream>>>(qkv_b, Kb, Vt, x1b);
    // 6. diag gather
    diag_kernel<<<(BB * SS * (C / 8) + 255) / 256, 256, 0, stream>>>(x1b, xdb);
    // 7. q2 = xd @ Wq
    gemm_bf16<0><<<dim3(768 / 128, (M2 + 127) / 128), 256, 0, stream>>>(
        xdb, Wt_q, nullptr, nullptr, q2b, M2, 768, 768);
    // 8. k2 = x1 @ Wkv[:, :C]
    gemm_bf16<0><<<dim3(768 / 128, M3 / 128), 256, 0, stream>>>(
        x1b, Wt_kv, nullptr, nullptr, k2b, M3, 768, 768);
    // 9. temporal attention -> y_b rows 1..S
    attn2_kernel<<<(BB * HEADS * SS + 3) / 4, 256, 0, stream>>>(q2b, k2b, x1b, y_b);
    // 10. proj: out = y_b @ Wp + bp + x  (f32)
    gemm_bf16<2><<<dim3(768 / 128, (M1 + 127) / 128), 256, 0, stream>>>(
        y_b, Wt_p, bp, x, out, M1, 768, 768);
    // 11. LN2 -> bf16 (reuse xn_b)
    ln_kernel<<<M1, 256, 0, stream>>>(out, g2, b2_, xn_b, M1);
    // 12. fc1 + exact GELU -> bf16
    gemm_bf16<1><<<dim3(3072 / 128, (M1 + 127) / 128), 256, 0, stream>>>(
        xn_b, W1t, bf1, nullptr, a1b, M1, 3072, 768);
    // 13. fc2 + bias + residual (f32, in-place on d_out)
    gemm_bf16<2><<<dim3(768 / 128, (M1 + 127) / 128), 256, 0, stream>>>(
        a1b, W2t, bf2, out, out, M1, 768, 3072);
}

// Round 10
// 346.991 us; speedup vs baseline: 13.8017x; 1.0540x over previous
//
#include <hip/hip_runtime.h>
#include <hip/hip_bf16.h>
#include <math.h>

#define C     768
#define HEADS 12
#define HD    64
#define NF    8
#define SL    196
#define BB    2
#define NN    1569   // 1 + NF*SL
#define SS    1568   // NF*SL
#define HID   3072
#define CLS_CH 256
#define CLS_NC 7     // ceil(NN / CLS_CH)
#define QSCALE 0.18033688011112042f   // 0.125 * log2(e); scores live in log2 domain

typedef __attribute__((ext_vector_type(8))) short short8;
typedef __attribute__((ext_vector_type(4))) float f32x4;
typedef unsigned short u16;

__device__ inline float fast_exp2(float x) { return __builtin_amdgcn_exp2f(x); }

__device__ inline u16 f2b(float f) {
    __hip_bfloat16 h = __float2bfloat16(f);   // HW v_cvt path (RNE)
    return *reinterpret_cast<u16*>(&h);
}
__device__ inline float b2f(u16 u) {
    union { unsigned u; float f; } v; v.u = ((unsigned)u) << 16;
    return v.f;
}

__device__ inline void gload_lds16(const void* g, void* l) {
    __builtin_amdgcn_global_load_lds(
        (const __attribute__((address_space(1))) void*)g,
        (__attribute__((address_space(3))) void*)l, 16, 0, 0);
}

// ---------------- LayerNorm: f32 in -> bf16 out ----------------
__global__ void ln_kernel(const float* __restrict__ x, const float* __restrict__ g,
                          const float* __restrict__ b, u16* __restrict__ out, int rows) {
    int row = blockIdx.x;
    if (row >= rows) return;
    const float* xr = x + (size_t)row * C;
    int tid = threadIdx.x;
    float v[3];
    float sum = 0.f, sumsq = 0.f;
#pragma unroll
    for (int i = 0; i < 3; i++) {
        v[i] = xr[tid + 256 * i];
        sum += v[i]; sumsq += v[i] * v[i];
    }
    __shared__ float s1[4], s2[4];
    for (int off = 32; off; off >>= 1) {
        sum   += __shfl_xor(sum, off);
        sumsq += __shfl_xor(sumsq, off);
    }
    int wave = tid >> 6, lane = tid & 63;
    if (lane == 0) { s1[wave] = sum; s2[wave] = sumsq; }
    __syncthreads();
    sum   = s1[0] + s1[1] + s1[2] + s1[3];
    sumsq = s2[0] + s2[1] + s2[2] + s2[3];
    float mu  = sum / C;
    float var = sumsq / C - mu * mu;
    float rstd = rsqrtf(fmaxf(var, 0.f) + 1e-5f);
    u16* outr = out + (size_t)row * C;
#pragma unroll
    for (int i = 0; i < 3; i++) {
        int c = tid + 256 * i;
        outr[c] = f2b((v[i] - mu) * rstd * g[c] + b[c]);
    }
}

// ---------------- weight transpose+convert: W[K][ldb] (first N cols) -> Wt[N][K] bf16 ----------
__global__ void wtrans_kernel(const float* __restrict__ W, u16* __restrict__ Wt,
                              int K, int N, int ldb) {
    __shared__ float tile[64][65];
    int nb = blockIdx.x * 64, kb = blockIdx.y * 64;
    int tx = threadIdx.x & 63, ty = threadIdx.x >> 6;
#pragma unroll
    for (int i = 0; i < 64; i += 4)
        tile[ty + i][tx] = W[(size_t)(kb + ty + i) * ldb + nb + tx];
    __syncthreads();
#pragma unroll
    for (int i = 0; i < 64; i += 4)
        Wt[(size_t)(nb + ty + i) * K + kb + tx] = f2b(tile[tx][ty + i]);
}

// ---------------- bf16 MFMA GEMM (2-phase double-buffered): C = A(MxK) @ Bt(NxK)^T ----------
// MODE 0: bf16 out. MODE 1: bf16 out, bias + exact GELU. MODE 2: f32 out, bias + resid.
// MODE 3: bf16 out, cols < 768 scaled by QSCALE (qkv GEMM: q pre-scaled into log2 domain).
template<int MODE>
__global__ __launch_bounds__(256) void gemm_bf16(
    const u16* __restrict__ A, const u16* __restrict__ Bt,
    const float* __restrict__ bias, const float* resid, void* Cout,
    int M, int N, int K) {
    __shared__ char smem[32768];   // 2 x (As 8KB + Bs 8KB)
    int tid = threadIdx.x, lane = tid & 63, wave = tid >> 6;
    int wr = wave >> 1, wc = wave & 1;
    int r16 = lane & 15, kg = lane >> 4;
    int row0 = blockIdx.y * 128, col0 = blockIdx.x * 128;
    f32x4 acc[4][4];
#pragma unroll
    for (int mt = 0; mt < 4; mt++)
#pragma unroll
        for (int nt = 0; nt < 4; nt++) acc[mt][nt] = (f32x4){0.f, 0.f, 0.f, 0.f};

    auto stage = [&](char* dstbase, int ks) {
        int k0 = ks << 5;
#pragma unroll
        for (int it = 0; it < 4; it++) {
            int c = it * 256 + tid;
            const u16* src;
            if (c < 512) {
                int ml = c >> 2, s = c & 3;
                int kgs = s ^ ((ml >> 1) & 3);
                int gm = row0 + ml; if (gm >= M) gm = M - 1;
                src = A + (size_t)gm * K + k0 + kgs * 8;
            } else {
                int cc = c - 512;
                int nl = cc >> 2, s = cc & 3;
                int kgs = s ^ ((nl >> 1) & 3);
                src = Bt + (size_t)(col0 + nl) * K + k0 + kgs * 8;
            }
            gload_lds16(src, dstbase + it * 4096 + wave * 1024);
        }
    };

    int nsteps = K >> 5;
    stage(smem, 0);
    __syncthreads();               // drains vmcnt: tile 0 resident
    for (int ks = 0; ks < nsteps; ks++) {
        char* curb = smem + (ks & 1) * 16384;
        if (ks + 1 < nsteps) stage(smem + ((ks + 1) & 1) * 16384, ks + 1);
        short8 af[4], bfr[4];
#pragma unroll
        for (int mt = 0; mt < 4; mt++) {
            int ml = wr * 64 + mt * 16 + r16;
            af[mt] = *(const short8*)(curb + ml * 64 + ((kg ^ ((ml >> 1) & 3)) << 4));
        }
#pragma unroll
        for (int nt = 0; nt < 4; nt++) {
            int nl = wc * 64 + nt * 16 + r16;
            bfr[nt] = *(const short8*)(curb + 8192 + nl * 64 + ((kg ^ ((nl >> 1) & 3)) << 4));
        }
        __builtin_amdgcn_s_setprio(1);
#pragma unroll
        for (int mt = 0; mt < 4; mt++)
#pragma unroll
            for (int nt = 0; nt < 4; nt++)
                acc[mt][nt] = __builtin_amdgcn_mfma_f32_16x16x32_bf16(af[mt], bfr[nt], acc[mt][nt], 0, 0, 0);
        __builtin_amdgcn_s_setprio(0);
        __syncthreads();           // next tile landed; curb reads done before overwrite
    }
#pragma unroll
    for (int mt = 0; mt < 4; mt++) {
#pragma unroll
        for (int r = 0; r < 4; r++) {
            int gm = row0 + wr * 64 + mt * 16 + kg * 4 + r;
            if (gm >= M) continue;
#pragma unroll
            for (int nt = 0; nt < 4; nt++) {
                int gn = col0 + wc * 64 + nt * 16 + r16;
                float v = acc[mt][nt][r];
                if constexpr (MODE == 1) {
                    v += bias[gn];
                    v = 0.5f * v * (1.f + erff(v * 0.70710678118f));
                }
                if constexpr (MODE == 2) {
                    v += bias[gn] + resid[(size_t)gm * N + gn];
                    ((float*)Cout)[(size_t)gm * N + gn] = v;
                } else {
                    if constexpr (MODE == 3) { if (gn < 768) v *= QSCALE; }
                    ((u16*)Cout)[(size_t)gm * N + gn] = f2b(v);
                }
            }
        }
    }
}

// ---------------- cls attention pass 1 (q pre-scaled; log2-domain softmax) ----------------
__global__ void cls_partial_kernel(const u16* __restrict__ qkv, float* __restrict__ part) {
    int c = blockIdx.x, bh = blockIdx.y;
    int b = bh / HEADS, hh = bh % HEADS;
    int tid = threadIdx.x;
    int wave = tid >> 6, lane = tid & 63;
    __shared__ float s_q[HD];
    __shared__ float s_sc[CLS_CH];
    __shared__ float sm[4], ss[4];
    __shared__ float sacc[4][HD];
    if (tid < HD) s_q[tid] = b2f(qkv[(size_t)(b * NN) * 2304 + hh * HD + tid]);
    __syncthreads();

    int j0 = c * CLS_CH;
    int j = j0 + tid;
    float sc = -1e30f;
    if (j < NN) {
        const short8* kp = (const short8*)(qkv + ((size_t)(b * NN) + j) * 2304 + C + hh * HD);
        float acc = 0.f;
#pragma unroll
        for (int u = 0; u < 8; u++) {
            short8 kv = kp[u];
#pragma unroll
            for (int e = 0; e < 8; e++) acc += s_q[u * 8 + e] * b2f((u16)kv[e]);
        }
        sc = acc;     // already in log2 domain (q pre-scaled by QSCALE)
    }
    float m = sc;
    for (int off = 32; off; off >>= 1) m = fmaxf(m, __shfl_xor(m, off));
    if (lane == 0) sm[wave] = m;
    __syncthreads();
    m = fmaxf(fmaxf(sm[0], sm[1]), fmaxf(sm[2], sm[3]));
    float e = (j < NN) ? fast_exp2(sc - m) : 0.f;
    s_sc[tid] = e;
    float su = e;
    for (int off = 32; off; off >>= 1) su += __shfl_xor(su, off);
    if (lane == 0) ss[wave] = su;
    __syncthreads();
    float ssum = ss[0] + ss[1] + ss[2] + ss[3];

    int jj = tid >> 6, d = tid & 63;
    int jmax = NN - j0; if (jmax > CLS_CH) jmax = CLS_CH;
    const u16* vcol = qkv + ((size_t)(b * NN) + j0) * 2304 + 2 * C + hh * HD + d;
    float acc = 0.f;
    for (int t = jj; t < jmax; t += 4)
        acc += s_sc[t] * b2f(vcol[(size_t)t * 2304]);
    sacc[jj][d] = acc;
    __syncthreads();
    if (tid < HD) {
        float pv = sacc[0][tid] + sacc[1][tid] + sacc[2][tid] + sacc[3][tid];
        float* pp = part + ((size_t)bh * CLS_NC + c) * 66;
        pp[2 + tid] = pv;
        if (tid == 0) { pp[0] = m; pp[1] = ssum; }
    }
}

// ---------------- cls attention pass 2: merge chunk partials (log2 domain) ----------------
__global__ void cls_reduce_kernel(const float* __restrict__ part, u16* __restrict__ y) {
    int bh = blockIdx.x;
    int b = bh / HEADS, hh = bh % HEADS;
    int d = threadIdx.x;   // 64
    float gm = -1e30f;
#pragma unroll
    for (int c = 0; c < CLS_NC; c++)
        gm = fmaxf(gm, part[((size_t)bh * CLS_NC + c) * 66]);
    float tot = 0.f, pv = 0.f;
#pragma unroll
    for (int c = 0; c < CLS_NC; c++) {
        const float* pp = part + ((size_t)bh * CLS_NC + c) * 66;
        float w = fast_exp2(pp[0] - gm);
        tot += pp[1] * w;
        pv  += pp[2 + d] * w;
    }
    y[(size_t)(b * NN) * C + hh * HD + d] = f2b(pv / tot);
}

// ---------------- repack K: qkv_b -> Kb[bh][f][208][64], pad rows zeroed ----------------
__global__ void repack_k_kernel(const u16* __restrict__ qkv, u16* __restrict__ Kb) {
    int t = blockIdx.x * 256 + threadIdx.x;
    if (t >= 24 * NF * 208 * 8) return;
    int d8 = t & 7;
    int rest = t >> 3;
    int n = rest % 208;
    rest /= 208;
    int f = rest % NF;
    int bh = rest / NF;
    int b = bh / HEADS, h = bh % HEADS;
    short8 v = {0, 0, 0, 0, 0, 0, 0, 0};
    if (n < SL)
        v = *(const short8*)(qkv + ((size_t)(b * NN) + 1 + f * SL + n) * 2304 + C + h * HD + d8 * 8);
    *(short8*)(Kb + (((size_t)bh * NF + f) * 208 + n) * 64 + d8 * 8) = v;
}

// ---------------- repack V: qkv_b -> Vt[bh][f][d][224] (transposed, pad zeroed) ----------------
__global__ void repack_v_kernel(const u16* __restrict__ qkv, u16* __restrict__ Vt) {
    int t = blockIdx.x * 256 + threadIdx.x;
    if (t >= 24 * NF * 64 * 28) return;
    int n8 = t % 28;
    int rest = t / 28;
    int d = rest % 64;
    rest /= 64;
    int f = rest % NF;
    int bh = rest / NF;
    int b = bh / HEADS, h = bh % HEADS;
    int n0 = n8 * 8;
    const u16* src = qkv + ((size_t)(b * NN) + 1 + f * SL) * 2304 + 2 * C + h * HD + d;
    short8 v;
#pragma unroll
    for (int j = 0; j < 8; j++) {
        int n = n0 + j;
        v[j] = (n < SL) ? (short)src[(size_t)n * 2304] : (short)0;
    }
    *(short8*)(Vt + (((size_t)bh * NF + f) * 64 + d) * 224 + n0) = v;
}

// ---------------- MFMA spatial attention v3 ----------------
// 1-D grid of 4800 blocks, XCD-aware decode: n&7 -> XCD; each XCD owns 3 bh x 8 f
// complete (bh,f) groups so K_f/V_f stay L2-resident. LDS overlay: K buf (26.6KB)
// is dead after QK^T; a second barrier lets the 4 P bufs (29.7KB) reuse it ->
// 29.7KB total -> 5 blocks/CU (was 2 at 56.3KB).
__global__ void space_attn_mfma(
    const u16* __restrict__ qkv, const u16* __restrict__ Kb,
    const u16* __restrict__ Vt, u16* __restrict__ x1) {
    __shared__ u16 smem[14848];  // 29696 B: phase 1 = swizzled K_f; phase 2 = 4 x 7424B P bufs
    int tid = threadIdx.x;
    int lane = tid & 63, wave = tid >> 6;
    int r16 = lane & 15, kg = lane >> 4;

    // XCD-aware decode (bijective): n = xcd + 8*(gw*25 + j)
    int n = blockIdx.x;
    int xcd = n & 7;
    int slot = n >> 3;
    int j = slot % 25;
    int gw = slot / 25;            // 0..23
    int bh = xcd * 3 + gw % 3;     // 3 bh per XCD
    int f = gw / 3;                // 8 f per XCD
    int b = bh / HEADS, h = bh % HEADS;

    // --- phase 1: stage K_f into LDS (linear dest, pre-swizzled source) ---
    const char* kb_g = (const char*)(Kb + ((size_t)bh * NF + f) * 208 * 64);
    for (int w = wave; w < 26; w += 4) {
        int p = w * 1024 + lane * 16;
        int row = p >> 7;
        int src = (p & ~127) | ((p & 127) ^ ((row & 7) << 4));
        gload_lds16(kb_g + src, (char*)smem + p);
    }
    __syncthreads();

    int strip = j * 4 + wave;
    bool act = strip < 98;
    if (!act) strip = 97;          // clamp: duplicate compute, guarded epilogue
    int q0 = strip * 16;

    const u16* qrow = qkv + ((size_t)(b * NN) + 1 + q0 + r16) * 2304 + h * HD + kg * 8;
    short8 aq0 = *(const short8*)(qrow);
    short8 aq1 = *(const short8*)(qrow + 32);

    f32x4 acc[13];
#pragma unroll
    for (int t = 0; t < 13; t++) acc[t] = (f32x4){0.f, 0.f, 0.f, 0.f};
    const char* ksm = (const char*)smem;
    int swz = (r16 & 7) << 4;
    __builtin_amdgcn_s_setprio(1);
#pragma unroll
    for (int t = 0; t < 13; t++) {
        const char* krow = ksm + (t * 16 + r16) * 128;
        short8 bk0 = *(const short8*)(krow + ((kg * 16) ^ swz));
        short8 bk1 = *(const short8*)(krow + ((64 + kg * 16) ^ swz));
        acc[t] = __builtin_amdgcn_mfma_f32_16x16x32_bf16(aq0, bk0, acc[t], 0, 0, 0);
        acc[t] = __builtin_amdgcn_mfma_f32_16x16x32_bf16(aq1, bk1, acc[t], 0, 0, 0);
    }
    __builtin_amdgcn_s_setprio(0);

    // scores already in log2 domain (q pre-scaled by QSCALE in qkv epilogue)
    bool tail_mask = (r16 >= 4);
    float mrow[4] = {-1e30f, -1e30f, -1e30f, -1e30f};
#pragma unroll
    for (int t = 0; t < 13; t++) {
        if (t == 12 && tail_mask) continue;
#pragma unroll
        for (int r = 0; r < 4; r++) mrow[r] = fmaxf(mrow[r], acc[t][r]);
    }
#pragma unroll
    for (int off = 8; off; off >>= 1)
#pragma unroll
        for (int r = 0; r < 4; r++) mrow[r] = fmaxf(mrow[r], __shfl_xor(mrow[r], off));

    float ssum[4] = {0.f, 0.f, 0.f, 0.f};
#pragma unroll
    for (int t = 0; t < 13; t++) {
#pragma unroll
        for (int r = 0; r < 4; r++) {
            float p = (t == 12 && tail_mask) ? 0.f : fast_exp2(acc[t][r] - mrow[r]);
            acc[t][r] = p;
            ssum[r] += p;
        }
    }
#pragma unroll
    for (int off = 8; off; off >>= 1)
#pragma unroll
        for (int r = 0; r < 4; r++) ssum[r] += __shfl_xor(ssum[r], off);
    float inv[4];
#pragma unroll
    for (int r = 0; r < 4; r++) inv[r] = 1.f / ssum[r];

    // --- phase 2: K buf is dead; P bufs overlay it ---
    __syncthreads();
    u16* pb = smem + wave * 3712;   // 7424 B per wave, stride 232 u16
#pragma unroll
    for (int t = 0; t < 13; t++)
#pragma unroll
        for (int r = 0; r < 4; r++)
            pb[(kg * 4 + r) * 232 + t * 16 + r16] = f2b(acc[t][r]);
    {
        int zr = lane >> 2, zc = 208 + (lane & 3) * 4;
        *(uint2*)(&pb[zr * 232 + zc]) = (uint2){0u, 0u};
    }

    f32x4 o[4];
#pragma unroll
    for (int dt = 0; dt < 4; dt++) o[dt] = (f32x4){0.f, 0.f, 0.f, 0.f};
    const u16* vbase = Vt + ((size_t)bh * NF + f) * 64 * 224;
    __builtin_amdgcn_s_setprio(1);
#pragma unroll
    for (int kc = 0; kc < 7; kc++) {
        short8 pa = *(const short8*)(&pb[r16 * 232 + kc * 32 + kg * 8]);
#pragma unroll
        for (int dt = 0; dt < 4; dt++) {
            short8 bv = *(const short8*)(vbase + (dt * 16 + r16) * 224 + kc * 32 + kg * 8);
            o[dt] = __builtin_amdgcn_mfma_f32_16x16x32_bf16(pa, bv, o[dt], 0, 0, 0);
        }
    }
    __builtin_amdgcn_s_setprio(0);

    if (act) {
#pragma unroll
        for (int dt = 0; dt < 4; dt++)
#pragma unroll
            for (int r = 0; r < 4; r++) {
                int q = q0 + kg * 4 + r;
                x1[(((size_t)(b * SS + q)) * NF + f) * C + h * HD + dt * 16 + r16] = f2b(o[dt][r] * inv[r]);
            }
    }
}

// ---------------- diagonal gather (bf16): xd[b,s,:] = x1[b,s,s/SL,:] ----------------
__global__ void diag_kernel(const u16* __restrict__ x1, u16* __restrict__ xd) {
    int i = blockIdx.x * 256 + threadIdx.x;
    int total = BB * SS * (C / 8);
    if (i >= total) return;
    int c8 = i % (C / 8);
    int row = i / (C / 8);
    int s = row % SS;
    int f = s / SL;
    ((short8*)(xd + (size_t)row * C))[c8] =
        ((const short8*)(x1 + (((size_t)row) * NF + f) * C))[c8];
}

// ---------------- temporal attention (log2-domain softmax) ----------------
__global__ void attn2_kernel(const u16* __restrict__ q2, const u16* __restrict__ k2,
                             const u16* __restrict__ x1, u16* __restrict__ y) {
    int item = blockIdx.x * 4 + (threadIdx.x >> 6);
    if (item >= BB * HEADS * SS) return;
    int lane = threadIdx.x & 63;
    int s = item % SS;
    int bh = item / SS;
    int b = bh / HEADS, hh = bh % HEADS;
    size_t rowbs = (size_t)(b * SS + s);
    float qv = b2f(q2[rowbs * C + hh * HD + lane]) * QSCALE;
    float lg[NF];
#pragma unroll
    for (int f = 0; f < NF; f++) {
        float p = qv * b2f(k2[(rowbs * NF + f) * C + hh * HD + lane]);
        for (int off = 32; off; off >>= 1) p += __shfl_xor(p, off);
        lg[f] = p;
    }
    float m = lg[0];
#pragma unroll
    for (int f = 1; f < NF; f++) m = fmaxf(m, lg[f]);
    float sum = 0.f;
#pragma unroll
    for (int f = 0; f < NF; f++) { lg[f] = fast_exp2(lg[f] - m); sum += lg[f]; }
    float inv = 1.f / sum;
    float acc = 0.f;
#pragma unroll
    for (int f = 0; f < NF; f++) acc += lg[f] * b2f(x1[(rowbs * NF + f) * C + hh * HD + lane]);
    y[((size_t)(b * NN) + 1 + s) * C + hh * HD + lane] = f2b(acc * inv);
}

extern "C" void kernel_launch(void* const* d_in, const int* in_sizes, int n_in,
                              void* d_out, int out_size, void* d_ws, size_t ws_size,
                              hipStream_t stream) {
    const float* x    = (const float*)d_in[0];
    const float* g1   = (const float*)d_in[1];
    const float* b1   = (const float*)d_in[2];
    const float* Wqkv = (const float*)d_in[3];
    const float* Wq   = (const float*)d_in[4];
    const float* Wkv  = (const float*)d_in[5];
    const float* Wp   = (const float*)d_in[6];
    const float* bp   = (const float*)d_in[7];
    const float* g2   = (const float*)d_in[8];
    const float* b2_  = (const float*)d_in[9];
    const float* W1   = (const float*)d_in[10];
    const float* bf1  = (const float*)d_in[11];
    const float* W2   = (const float*)d_in[12];
    const float* bf2  = (const float*)d_in[13];
    float* out = (float*)d_out;

    // workspace layout (u16 elements)
    u16* us     = (u16*)d_ws;
    u16* xn_b   = us;                    // M1*768    (reused as hn after LN2)
    u16* qkv_b  = xn_b   + 2409984;      // M1*2304
    u16* Wt_qkv = qkv_b  + 7229952;      // 2304*768
    u16* Wt_q   = Wt_qkv + 1769472;      // 768*768
    u16* Wt_kv  = Wt_q   + 589824;       // 768*768 (first half of Wkv)
    u16* Wt_p   = Wt_kv  + 589824;       // 768*768
    u16* W1t    = Wt_p   + 589824;       // 3072*768
    u16* W2t    = W1t    + 2359296;      // 768*3072
    u16* Kb     = W2t    + 2359296;      // 24*8*208*64
    u16* Vt     = Kb     + 2555904;      // 24*8*64*224
    u16* x1b    = Vt     + 2752512;      // B*S*F*C
    u16* xdb    = x1b    + 19267584;     // B*S*C
    u16* q2b    = xdb    + 2408448;      // B*S*C
    u16* k2b    = q2b    + 2408448;      // B*S*F*C
    u16* y_b    = k2b    + 19267584;     // B*N*C
    u16* a1b    = y_b    + 2409984;      // B*N*HID
    float* cls_ws = (float*)(a1b + 9639936);  // 24*7*66 floats

    const int M1 = BB * NN;       // 3138
    const int M2 = BB * SS;       // 3136
    const int M3 = BB * SS * NF;  // 25088

    // 0. weight transpose + bf16 convert
    wtrans_kernel<<<dim3(2304 / 64, 768 / 64), 256, 0, stream>>>(Wqkv, Wt_qkv, 768, 2304, 2304);
    wtrans_kernel<<<dim3(768 / 64, 768 / 64), 256, 0, stream>>>(Wq, Wt_q, 768, 768, 768);
    wtrans_kernel<<<dim3(768 / 64, 768 / 64), 256, 0, stream>>>(Wkv, Wt_kv, 768, 768, 1536);
    wtrans_kernel<<<dim3(768 / 64, 768 / 64), 256, 0, stream>>>(Wp, Wt_p, 768, 768, 768);
    wtrans_kernel<<<dim3(3072 / 64, 768 / 64), 256, 0, stream>>>(W1, W1t, 768, 3072, 3072);
    wtrans_kernel<<<dim3(768 / 64, 3072 / 64), 256, 0, stream>>>(W2, W2t, 3072, 768, 768);
    // 1. LN1 -> bf16
    ln_kernel<<<M1, 256, 0, stream>>>(x, g1, b1, xn_b, M1);
    // 2. qkv_b = xn_b @ Wqkv (bf16 out; q cols pre-scaled by QSCALE)
    gemm_bf16<3><<<dim3(2304 / 128, (M1 + 127) / 128), 256, 0, stream>>>(
        xn_b, Wt_qkv, nullptr, nullptr, qkv_b, M1, 2304, 768);
    // 3. repack K, V
    repack_k_kernel<<<(24 * NF * 208 * 8 + 255) / 256, 256, 0, stream>>>(qkv_b, Kb);
    repack_v_kernel<<<(24 * NF * 64 * 28 + 255) / 256, 256, 0, stream>>>(qkv_b, Vt);
    // 4. cls attention (two-pass flash-style) -> y_b row 0
    cls_partial_kernel<<<dim3(CLS_NC, BB * HEADS), 256, 0, stream>>>(qkv_b, cls_ws);
    cls_reduce_kernel<<<BB * HEADS, 64, 0, stream>>>(cls_ws, y_b);
    // 5. spatial attention -> x1b (XCD-aware 1-D grid, P-over-K LDS overlay)
    space_attn_mfma<<<4800, 256, 0, stream>>>(qkv_b, Kb, Vt, x1b);
    // 6. diag gather
    diag_kernel<<<(BB * SS * (C / 8) + 255) / 256, 256, 0, stream>>>(x1b, xdb);
    // 7. q2 = xd @ Wq
    gemm_bf16<0><<<dim3(768 / 128, (M2 + 127) / 128), 256, 0, stream>>>(
        xdb, Wt_q, nullptr, nullptr, q2b, M2, 768, 768);
    // 8. k2 = x1 @ Wkv[:, :C]
    gemm_bf16<0><<<dim3(768 / 128, M3 / 128), 256, 0, stream>>>(
        x1b, Wt_kv, nullptr, nullptr, k2b, M3, 768, 768);
    // 9. temporal attention -> y_b rows 1..S
    attn2_kernel<<<(BB * HEADS * SS + 3) / 4, 256, 0, stream>>>(q2b, k2b, x1b, y_b);
    // 10. proj: out = y_b @ Wp + bp + x  (f32)
    gemm_bf16<2><<<dim3(768 / 128, (M1 + 127) / 128), 256, 0, stream>>>(
        y_b, Wt_p, bp, x, out, M1, 768, 768);
    // 11. LN2 -> bf16 (reuse xn_b)
    ln_kernel<<<M1, 256, 0, stream>>>(out, g2, b2_, xn_b, M1);
    // 12. fc1 + exact GELU -> bf16
    gemm_bf16<1><<<dim3(3072 / 128, (M1 + 127) / 128), 256, 0, stream>>>(
        xn_b, W1t, bf1, nullptr, a1b, M1, 3072, 768);
    // 13. fc2 + bias + residual (f32, in-place on d_out)
    gemm_bf16<2><<<dim3(768 / 128, (M1 + 127) / 128), 256, 0, stream>>>(
        a1b, W2t, bf2, out, out, M1, 768, 3072);
}

// Round 11
// 334.495 us; speedup vs baseline: 14.3173x; 1.0374x over previous
//
#include <hip/hip_runtime.h>
#include <hip/hip_bf16.h>
#include <math.h>

#define C     768
#define HEADS 12
#define HD    64
#define NF    8
#define SL    196
#define BB    2
#define NN    1569   // 1 + NF*SL
#define SS    1568   // NF*SL
#define HID   3072
#define CLS_CH 256
#define CLS_NC 7     // ceil(NN / CLS_CH)
#define QSCALE 0.18033688011112042f   // 0.125 * log2(e); scores live in log2 domain

typedef __attribute__((ext_vector_type(8))) short short8;
typedef __attribute__((ext_vector_type(4))) float f32x4;
typedef unsigned short u16;

__device__ inline float fast_exp2(float x) { return __builtin_amdgcn_exp2f(x); }

__device__ inline u16 f2b(float f) {
    __hip_bfloat16 h = __float2bfloat16(f);   // HW v_cvt path (RNE)
    return *reinterpret_cast<u16*>(&h);
}
__device__ inline float b2f(u16 u) {
    union { unsigned u; float f; } v; v.u = ((unsigned)u) << 16;
    return v.f;
}

__device__ inline void gload_lds16(const void* g, void* l) {
    __builtin_amdgcn_global_load_lds(
        (const __attribute__((address_space(1))) void*)g,
        (__attribute__((address_space(3))) void*)l, 16, 0, 0);
}

// ---------------- LayerNorm: f32 in -> bf16 out ----------------
__global__ void ln_kernel(const float* __restrict__ x, const float* __restrict__ g,
                          const float* __restrict__ b, u16* __restrict__ out, int rows) {
    int row = blockIdx.x;
    if (row >= rows) return;
    const float* xr = x + (size_t)row * C;
    int tid = threadIdx.x;
    float v[3];
    float sum = 0.f, sumsq = 0.f;
#pragma unroll
    for (int i = 0; i < 3; i++) {
        v[i] = xr[tid + 256 * i];
        sum += v[i]; sumsq += v[i] * v[i];
    }
    __shared__ float s1[4], s2[4];
    for (int off = 32; off; off >>= 1) {
        sum   += __shfl_xor(sum, off);
        sumsq += __shfl_xor(sumsq, off);
    }
    int wave = tid >> 6, lane = tid & 63;
    if (lane == 0) { s1[wave] = sum; s2[wave] = sumsq; }
    __syncthreads();
    sum   = s1[0] + s1[1] + s1[2] + s1[3];
    sumsq = s2[0] + s2[1] + s2[2] + s2[3];
    float mu  = sum / C;
    float var = sumsq / C - mu * mu;
    float rstd = rsqrtf(fmaxf(var, 0.f) + 1e-5f);
    u16* outr = out + (size_t)row * C;
#pragma unroll
    for (int i = 0; i < 3; i++) {
        int c = tid + 256 * i;
        outr[c] = f2b((v[i] - mu) * rstd * g[c] + b[c]);
    }
}

// ---------------- weight transpose+convert: W[K][ldb] (first N cols) -> Wt[N][K] bf16 ----------
__global__ void wtrans_kernel(const float* __restrict__ W, u16* __restrict__ Wt,
                              int K, int N, int ldb) {
    __shared__ float tile[64][65];
    int nb = blockIdx.x * 64, kb = blockIdx.y * 64;
    int tx = threadIdx.x & 63, ty = threadIdx.x >> 6;
#pragma unroll
    for (int i = 0; i < 64; i += 4)
        tile[ty + i][tx] = W[(size_t)(kb + ty + i) * ldb + nb + tx];
    __syncthreads();
#pragma unroll
    for (int i = 0; i < 64; i += 4)
        Wt[(size_t)(nb + ty + i) * K + kb + tx] = f2b(tile[tx][ty + i]);
}

// ---------------- bf16 MFMA GEMM (2-phase dbuf, XCD-swizzled 1-D grid) ----------------
// C(MxN) = A(MxK stride lda) @ Bt(NxK stride ldb)^T. 128x128 tile, BK=32, 4 waves.
// MODE 0: bf16 out. MODE 1: bf16 out, bias + exact GELU. MODE 2: f32 out, bias + resid.
// MODE 3: bf16 out, cols < 768 scaled by QSCALE. MODE 4: split-K f32 partials
// (grid gy doubled; chunk = by / mtiles selects K-half and partial buffer).
template<int MODE>
__global__ __launch_bounds__(256) void gemm_bf16(
    const u16* __restrict__ A, const u16* __restrict__ Bt,
    const float* __restrict__ bias, const float* resid, void* Cout,
    int M, int N, int K, int lda, int ldb, int gx) {
    __shared__ char smem[32768];   // 2 x (As 8KB + Bs 8KB)
    int tid = threadIdx.x, lane = tid & 63, wave = tid >> 6;
    int wr = wave >> 1, wc = wave & 1;
    int r16 = lane & 15, kg = lane >> 4;

    // XCD-aware bijective swizzle (m204): round-robin position -> chunked position
    int nwg = gridDim.x, orig = blockIdx.x;
    int q = nwg >> 3, r = nwg & 7, xcd = orig & 7, lid = orig >> 3;
    int wg = (xcd < r ? xcd * (q + 1) : r * (q + 1) + (xcd - r) * q) + lid;
    int bx = wg % gx, by = wg / gx;
    if constexpr (MODE == 4) {
        int mt = (M + 127) >> 7;
        int chunk = by / mt; by -= chunk * mt;
        A    += (size_t)chunk * K;
        Bt   += (size_t)chunk * K;
        Cout  = (void*)((float*)Cout + (size_t)chunk * ((size_t)M * N));
    }
    int row0 = by * 128, col0 = bx * 128;

    f32x4 acc[4][4];
#pragma unroll
    for (int mt = 0; mt < 4; mt++)
#pragma unroll
        for (int nt = 0; nt < 4; nt++) acc[mt][nt] = (f32x4){0.f, 0.f, 0.f, 0.f};

    auto stage = [&](char* dstbase, int ks) {
        int k0 = ks << 5;
#pragma unroll
        for (int it = 0; it < 4; it++) {
            int c = it * 256 + tid;
            const u16* src;
            if (c < 512) {
                int ml = c >> 2, s = c & 3;
                int kgs = s ^ ((ml >> 1) & 3);
                int gm = row0 + ml; if (gm >= M) gm = M - 1;
                src = A + (size_t)gm * lda + k0 + kgs * 8;
            } else {
                int cc = c - 512;
                int nl = cc >> 2, s = cc & 3;
                int kgs = s ^ ((nl >> 1) & 3);
                src = Bt + (size_t)(col0 + nl) * ldb + k0 + kgs * 8;
            }
            gload_lds16(src, dstbase + it * 4096 + wave * 1024);
        }
    };

    int nsteps = K >> 5;
    stage(smem, 0);
    __syncthreads();               // drains vmcnt: tile 0 resident
    for (int ks = 0; ks < nsteps; ks++) {
        char* curb = smem + (ks & 1) * 16384;
        if (ks + 1 < nsteps) stage(smem + ((ks + 1) & 1) * 16384, ks + 1);
        short8 af[4], bfr[4];
#pragma unroll
        for (int mt = 0; mt < 4; mt++) {
            int ml = wr * 64 + mt * 16 + r16;
            af[mt] = *(const short8*)(curb + ml * 64 + ((kg ^ ((ml >> 1) & 3)) << 4));
        }
#pragma unroll
        for (int nt = 0; nt < 4; nt++) {
            int nl = wc * 64 + nt * 16 + r16;
            bfr[nt] = *(const short8*)(curb + 8192 + nl * 64 + ((kg ^ ((nl >> 1) & 3)) << 4));
        }
        __builtin_amdgcn_s_setprio(1);
#pragma unroll
        for (int mt = 0; mt < 4; mt++)
#pragma unroll
            for (int nt = 0; nt < 4; nt++)
                acc[mt][nt] = __builtin_amdgcn_mfma_f32_16x16x32_bf16(af[mt], bfr[nt], acc[mt][nt], 0, 0, 0);
        __builtin_amdgcn_s_setprio(0);
        __syncthreads();           // next tile landed; curb reads done before overwrite
    }
#pragma unroll
    for (int mt = 0; mt < 4; mt++) {
#pragma unroll
        for (int r2 = 0; r2 < 4; r2++) {
            int gm = row0 + wr * 64 + mt * 16 + kg * 4 + r2;
            if (gm >= M) continue;
#pragma unroll
            for (int nt = 0; nt < 4; nt++) {
                int gn = col0 + wc * 64 + nt * 16 + r16;
                float v = acc[mt][nt][r2];
                if constexpr (MODE == 1) {
                    v += bias[gn];
                    v = 0.5f * v * (1.f + erff(v * 0.70710678118f));
                }
                if constexpr (MODE == 2) {
                    v += bias[gn] + resid[(size_t)gm * N + gn];
                    ((float*)Cout)[(size_t)gm * N + gn] = v;
                } else if constexpr (MODE == 4) {
                    ((float*)Cout)[(size_t)gm * N + gn] = v;
                } else {
                    if constexpr (MODE == 3) { if (gn < 768) v *= QSCALE; }
                    ((u16*)Cout)[(size_t)gm * N + gn] = f2b(v);
                }
            }
        }
    }
}

// ---------------- fc2 split-K merge: out += p0 + p1 + bias (float4) ----------------
__global__ void fc2_merge_kernel(const float* __restrict__ p0, const float* __restrict__ p1,
                                 const float* __restrict__ bias, float* __restrict__ out) {
    int i = blockIdx.x * 256 + threadIdx.x;
    int total = BB * NN * (C / 4);
    if (i >= total) return;
    int c4 = i % (C / 4);
    float4 bb = ((const float4*)bias)[c4];
    float4 a0 = ((const float4*)p0)[i];
    float4 a1 = ((const float4*)p1)[i];
    float4 o  = ((float4*)out)[i];
    o.x += a0.x + a1.x + bb.x;
    o.y += a0.y + a1.y + bb.y;
    o.z += a0.z + a1.z + bb.z;
    o.w += a0.w + a1.w + bb.w;
    ((float4*)out)[i] = o;
}

// ---------------- cls attention pass 1 (q pre-scaled; log2-domain softmax) ----------------
__global__ void cls_partial_kernel(const u16* __restrict__ qkv, float* __restrict__ part) {
    int c = blockIdx.x, bh = blockIdx.y;
    int b = bh / HEADS, hh = bh % HEADS;
    int tid = threadIdx.x;
    int wave = tid >> 6, lane = tid & 63;
    __shared__ float s_q[HD];
    __shared__ float s_sc[CLS_CH];
    __shared__ float sm[4], ss[4];
    __shared__ float sacc[4][HD];
    if (tid < HD) s_q[tid] = b2f(qkv[(size_t)(b * NN) * 2304 + hh * HD + tid]);
    __syncthreads();

    int j0 = c * CLS_CH;
    int j = j0 + tid;
    float sc = -1e30f;
    if (j < NN) {
        const short8* kp = (const short8*)(qkv + ((size_t)(b * NN) + j) * 2304 + C + hh * HD);
        float acc = 0.f;
#pragma unroll
        for (int u = 0; u < 8; u++) {
            short8 kv = kp[u];
#pragma unroll
            for (int e = 0; e < 8; e++) acc += s_q[u * 8 + e] * b2f((u16)kv[e]);
        }
        sc = acc;     // already in log2 domain (q pre-scaled by QSCALE)
    }
    float m = sc;
    for (int off = 32; off; off >>= 1) m = fmaxf(m, __shfl_xor(m, off));
    if (lane == 0) sm[wave] = m;
    __syncthreads();
    m = fmaxf(fmaxf(sm[0], sm[1]), fmaxf(sm[2], sm[3]));
    float e = (j < NN) ? fast_exp2(sc - m) : 0.f;
    s_sc[tid] = e;
    float su = e;
    for (int off = 32; off; off >>= 1) su += __shfl_xor(su, off);
    if (lane == 0) ss[wave] = su;
    __syncthreads();
    float ssum = ss[0] + ss[1] + ss[2] + ss[3];

    int jj = tid >> 6, d = tid & 63;
    int jmax = NN - j0; if (jmax > CLS_CH) jmax = CLS_CH;
    const u16* vcol = qkv + ((size_t)(b * NN) + j0) * 2304 + 2 * C + hh * HD + d;
    float acc = 0.f;
    for (int t = jj; t < jmax; t += 4)
        acc += s_sc[t] * b2f(vcol[(size_t)t * 2304]);
    sacc[jj][d] = acc;
    __syncthreads();
    if (tid < HD) {
        float pv = sacc[0][tid] + sacc[1][tid] + sacc[2][tid] + sacc[3][tid];
        float* pp = part + ((size_t)bh * CLS_NC + c) * 66;
        pp[2 + tid] = pv;
        if (tid == 0) { pp[0] = m; pp[1] = ssum; }
    }
}

// ---------------- cls attention pass 2: merge chunk partials (log2 domain) ----------------
__global__ void cls_reduce_kernel(const float* __restrict__ part, u16* __restrict__ y) {
    int bh = blockIdx.x;
    int b = bh / HEADS, hh = bh % HEADS;
    int d = threadIdx.x;   // 64
    float gm = -1e30f;
#pragma unroll
    for (int c = 0; c < CLS_NC; c++)
        gm = fmaxf(gm, part[((size_t)bh * CLS_NC + c) * 66]);
    float tot = 0.f, pv = 0.f;
#pragma unroll
    for (int c = 0; c < CLS_NC; c++) {
        const float* pp = part + ((size_t)bh * CLS_NC + c) * 66;
        float w = fast_exp2(pp[0] - gm);
        tot += pp[1] * w;
        pv  += pp[2 + d] * w;
    }
    y[(size_t)(b * NN) * C + hh * HD + d] = f2b(pv / tot);
}

// ---------------- repack K: qkv_b -> Kb[bh][f][208][64], pad rows zeroed ----------------
__global__ void repack_k_kernel(const u16* __restrict__ qkv, u16* __restrict__ Kb) {
    int t = blockIdx.x * 256 + threadIdx.x;
    if (t >= 24 * NF * 208 * 8) return;
    int d8 = t & 7;
    int rest = t >> 3;
    int n = rest % 208;
    rest /= 208;
    int f = rest % NF;
    int bh = rest / NF;
    int b = bh / HEADS, h = bh % HEADS;
    short8 v = {0, 0, 0, 0, 0, 0, 0, 0};
    if (n < SL)
        v = *(const short8*)(qkv + ((size_t)(b * NN) + 1 + f * SL + n) * 2304 + C + h * HD + d8 * 8);
    *(short8*)(Kb + (((size_t)bh * NF + f) * 208 + n) * 64 + d8 * 8) = v;
}

// ---------------- repack V: qkv_b -> Vt[bh][f][d][224] (transposed, pad zeroed) ----------------
__global__ void repack_v_kernel(const u16* __restrict__ qkv, u16* __restrict__ Vt) {
    int t = blockIdx.x * 256 + threadIdx.x;
    if (t >= 24 * NF * 64 * 28) return;
    int n8 = t % 28;
    int rest = t / 28;
    int d = rest % 64;
    rest /= 64;
    int f = rest % NF;
    int bh = rest / NF;
    int b = bh / HEADS, h = bh % HEADS;
    int n0 = n8 * 8;
    const u16* src = qkv + ((size_t)(b * NN) + 1 + f * SL) * 2304 + 2 * C + h * HD + d;
    short8 v;
#pragma unroll
    for (int j = 0; j < 8; j++) {
        int n = n0 + j;
        v[j] = (n < SL) ? (short)src[(size_t)n * 2304] : (short)0;
    }
    *(short8*)(Vt + (((size_t)bh * NF + f) * 64 + d) * 224 + n0) = v;
}

// ---------------- MFMA spatial attention v3 (XCD-aware, P-over-K LDS overlay) ----------------
__global__ void space_attn_mfma(
    const u16* __restrict__ qkv, const u16* __restrict__ Kb,
    const u16* __restrict__ Vt, u16* __restrict__ x1) {
    __shared__ u16 smem[14848];  // 29696 B: phase 1 = swizzled K_f; phase 2 = 4 x 7424B P bufs
    int tid = threadIdx.x;
    int lane = tid & 63, wave = tid >> 6;
    int r16 = lane & 15, kg = lane >> 4;

    // XCD-aware decode (bijective): n = xcd + 8*(gw*25 + j)
    int n = blockIdx.x;
    int xcd = n & 7;
    int slot = n >> 3;
    int j = slot % 25;
    int gw = slot / 25;            // 0..23
    int bh = xcd * 3 + gw % 3;     // 3 bh per XCD
    int f = gw / 3;                // 8 f per XCD
    int b = bh / HEADS, h = bh % HEADS;

    // --- phase 1: stage K_f into LDS (linear dest, pre-swizzled source) ---
    const char* kb_g = (const char*)(Kb + ((size_t)bh * NF + f) * 208 * 64);
    for (int w = wave; w < 26; w += 4) {
        int p = w * 1024 + lane * 16;
        int row = p >> 7;
        int src = (p & ~127) | ((p & 127) ^ ((row & 7) << 4));
        gload_lds16(kb_g + src, (char*)smem + p);
    }
    __syncthreads();

    int strip = j * 4 + wave;
    bool act = strip < 98;
    if (!act) strip = 97;          // clamp: duplicate compute, guarded epilogue
    int q0 = strip * 16;

    const u16* qrow = qkv + ((size_t)(b * NN) + 1 + q0 + r16) * 2304 + h * HD + kg * 8;
    short8 aq0 = *(const short8*)(qrow);
    short8 aq1 = *(const short8*)(qrow + 32);

    f32x4 acc[13];
#pragma unroll
    for (int t = 0; t < 13; t++) acc[t] = (f32x4){0.f, 0.f, 0.f, 0.f};
    const char* ksm = (const char*)smem;
    int swz = (r16 & 7) << 4;
    __builtin_amdgcn_s_setprio(1);
#pragma unroll
    for (int t = 0; t < 13; t++) {
        const char* krow = ksm + (t * 16 + r16) * 128;
        short8 bk0 = *(const short8*)(krow + ((kg * 16) ^ swz));
        short8 bk1 = *(const short8*)(krow + ((64 + kg * 16) ^ swz));
        acc[t] = __builtin_amdgcn_mfma_f32_16x16x32_bf16(aq0, bk0, acc[t], 0, 0, 0);
        acc[t] = __builtin_amdgcn_mfma_f32_16x16x32_bf16(aq1, bk1, acc[t], 0, 0, 0);
    }
    __builtin_amdgcn_s_setprio(0);

    bool tail_mask = (r16 >= 4);
    float mrow[4] = {-1e30f, -1e30f, -1e30f, -1e30f};
#pragma unroll
    for (int t = 0; t < 13; t++) {
        if (t == 12 && tail_mask) continue;
#pragma unroll
        for (int r = 0; r < 4; r++) mrow[r] = fmaxf(mrow[r], acc[t][r]);
    }
#pragma unroll
    for (int off = 8; off; off >>= 1)
#pragma unroll
        for (int r = 0; r < 4; r++) mrow[r] = fmaxf(mrow[r], __shfl_xor(mrow[r], off));

    float ssum[4] = {0.f, 0.f, 0.f, 0.f};
#pragma unroll
    for (int t = 0; t < 13; t++) {
#pragma unroll
        for (int r = 0; r < 4; r++) {
            float p = (t == 12 && tail_mask) ? 0.f : fast_exp2(acc[t][r] - mrow[r]);
            acc[t][r] = p;
            ssum[r] += p;
        }
    }
#pragma unroll
    for (int off = 8; off; off >>= 1)
#pragma unroll
        for (int r = 0; r < 4; r++) ssum[r] += __shfl_xor(ssum[r], off);
    float inv[4];
#pragma unroll
    for (int r = 0; r < 4; r++) inv[r] = 1.f / ssum[r];

    // --- phase 2: K buf is dead; P bufs overlay it ---
    __syncthreads();
    u16* pb = smem + wave * 3712;   // 7424 B per wave, stride 232 u16
#pragma unroll
    for (int t = 0; t < 13; t++)
#pragma unroll
        for (int r = 0; r < 4; r++)
            pb[(kg * 4 + r) * 232 + t * 16 + r16] = f2b(acc[t][r]);
    {
        int zr = lane >> 2, zc = 208 + (lane & 3) * 4;
        *(uint2*)(&pb[zr * 232 + zc]) = (uint2){0u, 0u};
    }

    f32x4 o[4];
#pragma unroll
    for (int dt = 0; dt < 4; dt++) o[dt] = (f32x4){0.f, 0.f, 0.f, 0.f};
    const u16* vbase = Vt + ((size_t)bh * NF + f) * 64 * 224;
    __builtin_amdgcn_s_setprio(1);
#pragma unroll
    for (int kc = 0; kc < 7; kc++) {
        short8 pa = *(const short8*)(&pb[r16 * 232 + kc * 32 + kg * 8]);
#pragma unroll
        for (int dt = 0; dt < 4; dt++) {
            short8 bv = *(const short8*)(vbase + (dt * 16 + r16) * 224 + kc * 32 + kg * 8);
            o[dt] = __builtin_amdgcn_mfma_f32_16x16x32_bf16(pa, bv, o[dt], 0, 0, 0);
        }
    }
    __builtin_amdgcn_s_setprio(0);

    if (act) {
#pragma unroll
        for (int dt = 0; dt < 4; dt++)
#pragma unroll
            for (int r = 0; r < 4; r++) {
                int q = q0 + kg * 4 + r;
                x1[(((size_t)(b * SS + q)) * NF + f) * C + h * HD + dt * 16 + r16] = f2b(o[dt][r] * inv[r]);
            }
    }
}

// ---------------- diagonal gather (bf16): xd[b,s,:] = x1[b,s,s/SL,:] ----------------
__global__ void diag_kernel(const u16* __restrict__ x1, u16* __restrict__ xd) {
    int i = blockIdx.x * 256 + threadIdx.x;
    int total = BB * SS * (C / 8);
    if (i >= total) return;
    int c8 = i % (C / 8);
    int row = i / (C / 8);
    int s = row % SS;
    int f = s / SL;
    ((short8*)(xd + (size_t)row * C))[c8] =
        ((const short8*)(x1 + (((size_t)row) * NF + f) * C))[c8];
}

// ---------------- temporal attention (log2-domain softmax) ----------------
__global__ void attn2_kernel(const u16* __restrict__ q2, const u16* __restrict__ k2,
                             const u16* __restrict__ x1, u16* __restrict__ y) {
    int item = blockIdx.x * 4 + (threadIdx.x >> 6);
    if (item >= BB * HEADS * SS) return;
    int lane = threadIdx.x & 63;
    int s = item % SS;
    int bh = item / SS;
    int b = bh / HEADS, hh = bh % HEADS;
    size_t rowbs = (size_t)(b * SS + s);
    float qv = b2f(q2[rowbs * C + hh * HD + lane]) * QSCALE;
    float lg[NF];
#pragma unroll
    for (int f = 0; f < NF; f++) {
        float p = qv * b2f(k2[(rowbs * NF + f) * C + hh * HD + lane]);
        for (int off = 32; off; off >>= 1) p += __shfl_xor(p, off);
        lg[f] = p;
    }
    float m = lg[0];
#pragma unroll
    for (int f = 1; f < NF; f++) m = fmaxf(m, lg[f]);
    float sum = 0.f;
#pragma unroll
    for (int f = 0; f < NF; f++) { lg[f] = fast_exp2(lg[f] - m); sum += lg[f]; }
    float inv = 1.f / sum;
    float acc = 0.f;
#pragma unroll
    for (int f = 0; f < NF; f++) acc += lg[f] * b2f(x1[(rowbs * NF + f) * C + hh * HD + lane]);
    y[((size_t)(b * NN) + 1 + s) * C + hh * HD + lane] = f2b(acc * inv);
}

extern "C" void kernel_launch(void* const* d_in, const int* in_sizes, int n_in,
                              void* d_out, int out_size, void* d_ws, size_t ws_size,
                              hipStream_t stream) {
    const float* x    = (const float*)d_in[0];
    const float* g1   = (const float*)d_in[1];
    const float* b1   = (const float*)d_in[2];
    const float* Wqkv = (const float*)d_in[3];
    const float* Wq   = (const float*)d_in[4];
    const float* Wkv  = (const float*)d_in[5];
    const float* Wp   = (const float*)d_in[6];
    const float* bp   = (const float*)d_in[7];
    const float* g2   = (const float*)d_in[8];
    const float* b2_  = (const float*)d_in[9];
    const float* W1   = (const float*)d_in[10];
    const float* bf1  = (const float*)d_in[11];
    const float* W2   = (const float*)d_in[12];
    const float* bf2  = (const float*)d_in[13];
    float* out = (float*)d_out;

    // workspace layout (u16 elements)
    u16* us     = (u16*)d_ws;
    u16* xn_b   = us;                    // M1*768    (reused as hn after LN2)
    u16* qkv_b  = xn_b   + 2409984;      // M1*2304
    u16* Wt_qkv = qkv_b  + 7229952;      // 2304*768
    u16* Wt_q   = Wt_qkv + 1769472;      // 768*768
    u16* Wt_kv  = Wt_q   + 589824;       // 768*768 (first half of Wkv)
    u16* Wt_p   = Wt_kv  + 589824;       // 768*768
    u16* W1t    = Wt_p   + 589824;       // 3072*768
    u16* W2t    = W1t    + 2359296;      // 768*3072
    u16* Kb     = W2t    + 2359296;      // 24*8*208*64
    u16* Vt     = Kb     + 2555904;      // 24*8*64*224
    u16* x1b    = Vt     + 2752512;      // B*S*F*C
    u16* xdb    = x1b    + 19267584;     // B*S*C
    u16* q2b    = xdb    + 2408448;      // B*S*C
    u16* k2b    = q2b    + 2408448;      // B*S*F*C
    u16* y_b    = k2b    + 19267584;     // B*N*C
    u16* a1b    = y_b    + 2409984;      // B*N*HID
    float* cls_ws   = (float*)(a1b + 9639936);     // 24*7*66 floats
    float* fc2_part = cls_ws + 24 * 7 * 66;        // 2 * M1*768 floats

    const int M1 = BB * NN;       // 3138
    const int M2 = BB * SS;       // 3136
    const int M3 = BB * SS * NF;  // 25088

    // 0. weight transpose + bf16 convert
    wtrans_kernel<<<dim3(2304 / 64, 768 / 64), 256, 0, stream>>>(Wqkv, Wt_qkv, 768, 2304, 2304);
    wtrans_kernel<<<dim3(768 / 64, 768 / 64), 256, 0, stream>>>(Wq, Wt_q, 768, 768, 768);
    wtrans_kernel<<<dim3(768 / 64, 768 / 64), 256, 0, stream>>>(Wkv, Wt_kv, 768, 768, 1536);
    wtrans_kernel<<<dim3(768 / 64, 768 / 64), 256, 0, stream>>>(Wp, Wt_p, 768, 768, 768);
    wtrans_kernel<<<dim3(3072 / 64, 768 / 64), 256, 0, stream>>>(W1, W1t, 768, 3072, 3072);
    wtrans_kernel<<<dim3(768 / 64, 3072 / 64), 256, 0, stream>>>(W2, W2t, 3072, 768, 768);
    // 1. LN1 -> bf16
    ln_kernel<<<M1, 256, 0, stream>>>(x, g1, b1, xn_b, M1);
    // 2. qkv_b = xn_b @ Wqkv (bf16 out; q cols pre-scaled by QSCALE)
    gemm_bf16<3><<<18 * 25, 256, 0, stream>>>(
        xn_b, Wt_qkv, nullptr, nullptr, qkv_b, M1, 2304, 768, 768, 768, 18);
    // 3. repack K, V
    repack_k_kernel<<<(24 * NF * 208 * 8 + 255) / 256, 256, 0, stream>>>(qkv_b, Kb);
    repack_v_kernel<<<(24 * NF * 64 * 28 + 255) / 256, 256, 0, stream>>>(qkv_b, Vt);
    // 4. cls attention (two-pass flash-style) -> y_b row 0
    cls_partial_kernel<<<dim3(CLS_NC, BB * HEADS), 256, 0, stream>>>(qkv_b, cls_ws);
    cls_reduce_kernel<<<BB * HEADS, 64, 0, stream>>>(cls_ws, y_b);
    // 5. spatial attention -> x1b (XCD-aware 1-D grid, P-over-K LDS overlay)
    space_attn_mfma<<<4800, 256, 0, stream>>>(qkv_b, Kb, Vt, x1b);
    // 6. diag gather
    diag_kernel<<<(BB * SS * (C / 8) + 255) / 256, 256, 0, stream>>>(x1b, xdb);
    // 7. q2 = xd @ Wq
    gemm_bf16<0><<<6 * 25, 256, 0, stream>>>(
        xdb, Wt_q, nullptr, nullptr, q2b, M2, 768, 768, 768, 768, 6);
    // 8. k2 = x1 @ Wkv[:, :C]
    gemm_bf16<0><<<6 * 196, 256, 0, stream>>>(
        x1b, Wt_kv, nullptr, nullptr, k2b, M3, 768, 768, 768, 768, 6);
    // 9. temporal attention -> y_b rows 1..S
    attn2_kernel<<<(BB * HEADS * SS + 3) / 4, 256, 0, stream>>>(q2b, k2b, x1b, y_b);
    // 10. proj: out = y_b @ Wp + bp + x  (f32)
    gemm_bf16<2><<<6 * 25, 256, 0, stream>>>(
        y_b, Wt_p, bp, x, out, M1, 768, 768, 768, 768, 6);
    // 11. LN2 -> bf16 (reuse xn_b)
    ln_kernel<<<M1, 256, 0, stream>>>(out, g2, b2_, xn_b, M1);
    // 12. fc1 + exact GELU -> bf16
    gemm_bf16<1><<<24 * 25, 256, 0, stream>>>(
        xn_b, W1t, bf1, nullptr, a1b, M1, 3072, 768, 768, 768, 24);
    // 13. fc2 split-K=2: partials (f32), then merge (+bias+resid in-place on d_out)
    gemm_bf16<4><<<6 * 25 * 2, 256, 0, stream>>>(
        a1b, W2t, nullptr, nullptr, fc2_part, M1, 768, 1536, 3072, 3072, 6);
    fc2_merge_kernel<<<(BB * NN * (C / 4) + 255) / 256, 256, 0, stream>>>(
        fc2_part, fc2_part + (size_t)M1 * 768, bf2, out);
}

// Round 12
// 313.782 us; speedup vs baseline: 15.2624x; 1.0660x over previous
//
#include <hip/hip_runtime.h>
#include <hip/hip_bf16.h>
#include <math.h>

#define C     768
#define HEADS 12
#define HD    64
#define NF    8
#define SL    196
#define BB    2
#define NN    1569   // 1 + NF*SL
#define SS    1568   // NF*SL
#define HID   3072
#define CLS_CH 256
#define CLS_NC 7     // ceil(NN / CLS_CH)
#define QSCALE 0.18033688011112042f   // 0.125 * log2(e); scores live in log2 domain

typedef __attribute__((ext_vector_type(8))) short short8;
typedef __attribute__((ext_vector_type(4))) float f32x4;
typedef unsigned short u16;

__device__ inline float fast_exp2(float x) { return __builtin_amdgcn_exp2f(x); }

__device__ inline u16 f2b(float f) {
    __hip_bfloat16 h = __float2bfloat16(f);   // HW v_cvt path (RNE)
    return *reinterpret_cast<u16*>(&h);
}
__device__ inline float b2f(u16 u) {
    union { unsigned u; float f; } v; v.u = ((unsigned)u) << 16;
    return v.f;
}

__device__ inline void gload_lds16(const void* g, void* l) {
    __builtin_amdgcn_global_load_lds(
        (const __attribute__((address_space(1))) void*)g,
        (__attribute__((address_space(3))) void*)l, 16, 0, 0);
}

// ---------------- LayerNorm: f32 in -> bf16 out ----------------
__global__ void ln_kernel(const float* __restrict__ x, const float* __restrict__ g,
                          const float* __restrict__ b, u16* __restrict__ out, int rows) {
    int row = blockIdx.x;
    if (row >= rows) return;
    const float* xr = x + (size_t)row * C;
    int tid = threadIdx.x;
    float v[3];
    float sum = 0.f, sumsq = 0.f;
#pragma unroll
    for (int i = 0; i < 3; i++) {
        v[i] = xr[tid + 256 * i];
        sum += v[i]; sumsq += v[i] * v[i];
    }
    __shared__ float s1[4], s2[4];
    for (int off = 32; off; off >>= 1) {
        sum   += __shfl_xor(sum, off);
        sumsq += __shfl_xor(sumsq, off);
    }
    int wave = tid >> 6, lane = tid & 63;
    if (lane == 0) { s1[wave] = sum; s2[wave] = sumsq; }
    __syncthreads();
    sum   = s1[0] + s1[1] + s1[2] + s1[3];
    sumsq = s2[0] + s2[1] + s2[2] + s2[3];
    float mu  = sum / C;
    float var = sumsq / C - mu * mu;
    float rstd = rsqrtf(fmaxf(var, 0.f) + 1e-5f);
    u16* outr = out + (size_t)row * C;
#pragma unroll
    for (int i = 0; i < 3; i++) {
        int c = tid + 256 * i;
        outr[c] = f2b((v[i] - mu) * rstd * g[c] + b[c]);
    }
}

// ---------------- weight transpose+convert: W[K][ldb] (first N cols) -> Wt[N][K] bf16 ----------
__global__ void wtrans_kernel(const float* __restrict__ W, u16* __restrict__ Wt,
                              int K, int N, int ldb) {
    __shared__ float tile[64][65];
    int nb = blockIdx.x * 64, kb = blockIdx.y * 64;
    int tx = threadIdx.x & 63, ty = threadIdx.x >> 6;
#pragma unroll
    for (int i = 0; i < 64; i += 4)
        tile[ty + i][tx] = W[(size_t)(kb + ty + i) * ldb + nb + tx];
    __syncthreads();
#pragma unroll
    for (int i = 0; i < 64; i += 4)
        Wt[(size_t)(nb + ty + i) * K + kb + tx] = f2b(tile[tx][ty + i]);
}

// ---------------- bf16 MFMA GEMM (2-phase dbuf, XCD-swizzled 1-D grid) ----------------
// C(MxN) = A(MxK stride lda) @ Bt(NxK stride ldb)^T. 128x128 tile, BK=32, 4 waves.
// MODE 0: bf16 out. MODE 1: bf16 out, bias + exact GELU. MODE 2: f32 out, bias + resid.
// MODE 3: bf16 out, cols < 768 scaled by QSCALE. MODE 4: split-K f32 partials
// (grid gy multiplied by #chunks; chunk = by / mtiles selects K-slice and partial buffer).
template<int MODE>
__global__ __launch_bounds__(256) void gemm_bf16(
    const u16* __restrict__ A, const u16* __restrict__ Bt,
    const float* __restrict__ bias, const float* resid, void* Cout,
    int M, int N, int K, int lda, int ldb, int gx) {
    __shared__ char smem[32768];   // 2 x (As 8KB + Bs 8KB)
    int tid = threadIdx.x, lane = tid & 63, wave = tid >> 6;
    int wr = wave >> 1, wc = wave & 1;
    int r16 = lane & 15, kg = lane >> 4;

    // XCD-aware bijective swizzle (m204): round-robin position -> chunked position
    int nwg = gridDim.x, orig = blockIdx.x;
    int q = nwg >> 3, r = nwg & 7, xcd = orig & 7, lid = orig >> 3;
    int wg = (xcd < r ? xcd * (q + 1) : r * (q + 1) + (xcd - r) * q) + lid;
    int bx = wg % gx, by = wg / gx;
    if constexpr (MODE == 4) {
        int mt = (M + 127) >> 7;
        int chunk = by / mt; by -= chunk * mt;
        A    += (size_t)chunk * K;
        Bt   += (size_t)chunk * K;
        Cout  = (void*)((float*)Cout + (size_t)chunk * ((size_t)M * N));
    }
    int row0 = by * 128, col0 = bx * 128;

    f32x4 acc[4][4];
#pragma unroll
    for (int mt = 0; mt < 4; mt++)
#pragma unroll
        for (int nt = 0; nt < 4; nt++) acc[mt][nt] = (f32x4){0.f, 0.f, 0.f, 0.f};

    auto stage = [&](char* dstbase, int ks) {
        int k0 = ks << 5;
#pragma unroll
        for (int it = 0; it < 4; it++) {
            int c = it * 256 + tid;
            const u16* src;
            if (c < 512) {
                int ml = c >> 2, s = c & 3;
                int kgs = s ^ ((ml >> 1) & 3);
                int gm = row0 + ml; if (gm >= M) gm = M - 1;
                src = A + (size_t)gm * lda + k0 + kgs * 8;
            } else {
                int cc = c - 512;
                int nl = cc >> 2, s = cc & 3;
                int kgs = s ^ ((nl >> 1) & 3);
                src = Bt + (size_t)(col0 + nl) * ldb + k0 + kgs * 8;
            }
            gload_lds16(src, dstbase + it * 4096 + wave * 1024);
        }
    };

    int nsteps = K >> 5;
    stage(smem, 0);
    __syncthreads();               // drains vmcnt: tile 0 resident
    for (int ks = 0; ks < nsteps; ks++) {
        char* curb = smem + (ks & 1) * 16384;
        if (ks + 1 < nsteps) stage(smem + ((ks + 1) & 1) * 16384, ks + 1);
        short8 af[4], bfr[4];
#pragma unroll
        for (int mt = 0; mt < 4; mt++) {
            int ml = wr * 64 + mt * 16 + r16;
            af[mt] = *(const short8*)(curb + ml * 64 + ((kg ^ ((ml >> 1) & 3)) << 4));
        }
#pragma unroll
        for (int nt = 0; nt < 4; nt++) {
            int nl = wc * 64 + nt * 16 + r16;
            bfr[nt] = *(const short8*)(curb + 8192 + nl * 64 + ((kg ^ ((nl >> 1) & 3)) << 4));
        }
        __builtin_amdgcn_s_setprio(1);
#pragma unroll
        for (int mt = 0; mt < 4; mt++)
#pragma unroll
            for (int nt = 0; nt < 4; nt++)
                acc[mt][nt] = __builtin_amdgcn_mfma_f32_16x16x32_bf16(af[mt], bfr[nt], acc[mt][nt], 0, 0, 0);
        __builtin_amdgcn_s_setprio(0);
        __syncthreads();           // next tile landed; curb reads done before overwrite
    }
#pragma unroll
    for (int mt = 0; mt < 4; mt++) {
#pragma unroll
        for (int r2 = 0; r2 < 4; r2++) {
            int gm = row0 + wr * 64 + mt * 16 + kg * 4 + r2;
            if (gm >= M) continue;
#pragma unroll
            for (int nt = 0; nt < 4; nt++) {
                int gn = col0 + wc * 64 + nt * 16 + r16;
                float v = acc[mt][nt][r2];
                if constexpr (MODE == 1) {
                    v += bias[gn];
                    v = 0.5f * v * (1.f + erff(v * 0.70710678118f));
                }
                if constexpr (MODE == 2) {
                    v += bias[gn] + resid[(size_t)gm * N + gn];
                    ((float*)Cout)[(size_t)gm * N + gn] = v;
                } else if constexpr (MODE == 4) {
                    ((float*)Cout)[(size_t)gm * N + gn] = v;
                } else {
                    if constexpr (MODE == 3) { if (gn < 768) v *= QSCALE; }
                    ((u16*)Cout)[(size_t)gm * N + gn] = f2b(v);
                }
            }
        }
    }
}

// ---------------- fc2 split-K=4 merge: out += p0+p1+p2+p3 + bias (float4) ----------------
__global__ void fc2_merge_kernel(const float* __restrict__ p,
                                 const float* __restrict__ bias, float* __restrict__ out) {
    int i = blockIdx.x * 256 + threadIdx.x;
    int total = BB * NN * (C / 4);
    if (i >= total) return;
    int c4 = i % (C / 4);
    size_t stride = (size_t)BB * NN * (C / 4);
    float4 bb = ((const float4*)bias)[c4];
    float4 a0 = ((const float4*)p)[i];
    float4 a1 = ((const float4*)p)[i + stride];
    float4 a2 = ((const float4*)p)[i + 2 * stride];
    float4 a3 = ((const float4*)p)[i + 3 * stride];
    float4 o  = ((float4*)out)[i];
    o.x += a0.x + a1.x + a2.x + a3.x + bb.x;
    o.y += a0.y + a1.y + a2.y + a3.y + bb.y;
    o.z += a0.z + a1.z + a2.z + a3.z + bb.z;
    o.w += a0.w + a1.w + a2.w + a3.w + bb.w;
    ((float4*)out)[i] = o;
}

// ---------------- cls attention pass 1 (q pre-scaled; log2-domain softmax) ----------------
__global__ void cls_partial_kernel(const u16* __restrict__ qkv, float* __restrict__ part) {
    int c = blockIdx.x, bh = blockIdx.y;
    int b = bh / HEADS, hh = bh % HEADS;
    int tid = threadIdx.x;
    int wave = tid >> 6, lane = tid & 63;
    __shared__ float s_q[HD];
    __shared__ float s_sc[CLS_CH];
    __shared__ float sm[4], ss[4];
    __shared__ float sacc[4][HD];
    if (tid < HD) s_q[tid] = b2f(qkv[(size_t)(b * NN) * 2304 + hh * HD + tid]);
    __syncthreads();

    int j0 = c * CLS_CH;
    int j = j0 + tid;
    float sc = -1e30f;
    if (j < NN) {
        const short8* kp = (const short8*)(qkv + ((size_t)(b * NN) + j) * 2304 + C + hh * HD);
        float acc = 0.f;
#pragma unroll
        for (int u = 0; u < 8; u++) {
            short8 kv = kp[u];
#pragma unroll
            for (int e = 0; e < 8; e++) acc += s_q[u * 8 + e] * b2f((u16)kv[e]);
        }
        sc = acc;     // already in log2 domain (q pre-scaled by QSCALE)
    }
    float m = sc;
    for (int off = 32; off; off >>= 1) m = fmaxf(m, __shfl_xor(m, off));
    if (lane == 0) sm[wave] = m;
    __syncthreads();
    m = fmaxf(fmaxf(sm[0], sm[1]), fmaxf(sm[2], sm[3]));
    float e = (j < NN) ? fast_exp2(sc - m) : 0.f;
    s_sc[tid] = e;
    float su = e;
    for (int off = 32; off; off >>= 1) su += __shfl_xor(su, off);
    if (lane == 0) ss[wave] = su;
    __syncthreads();
    float ssum = ss[0] + ss[1] + ss[2] + ss[3];

    int jj = tid >> 6, d = tid & 63;
    int jmax = NN - j0; if (jmax > CLS_CH) jmax = CLS_CH;
    const u16* vcol = qkv + ((size_t)(b * NN) + j0) * 2304 + 2 * C + hh * HD + d;
    float acc = 0.f;
    for (int t = jj; t < jmax; t += 4)
        acc += s_sc[t] * b2f(vcol[(size_t)t * 2304]);
    sacc[jj][d] = acc;
    __syncthreads();
    if (tid < HD) {
        float pv = sacc[0][tid] + sacc[1][tid] + sacc[2][tid] + sacc[3][tid];
        float* pp = part + ((size_t)bh * CLS_NC + c) * 66;
        pp[2 + tid] = pv;
        if (tid == 0) { pp[0] = m; pp[1] = ssum; }
    }
}

// ---------------- cls attention pass 2: merge chunk partials (log2 domain) ----------------
__global__ void cls_reduce_kernel(const float* __restrict__ part, u16* __restrict__ y) {
    int bh = blockIdx.x;
    int b = bh / HEADS, hh = bh % HEADS;
    int d = threadIdx.x;   // 64
    float gm = -1e30f;
#pragma unroll
    for (int c = 0; c < CLS_NC; c++)
        gm = fmaxf(gm, part[((size_t)bh * CLS_NC + c) * 66]);
    float tot = 0.f, pv = 0.f;
#pragma unroll
    for (int c = 0; c < CLS_NC; c++) {
        const float* pp = part + ((size_t)bh * CLS_NC + c) * 66;
        float w = fast_exp2(pp[0] - gm);
        tot += pp[1] * w;
        pv  += pp[2 + d] * w;
    }
    y[(size_t)(b * NN) * C + hh * HD + d] = f2b(pv / tot);
}

// ---------------- repack K: qkv_b -> Kb[bh][f][208][64], pad rows zeroed ----------------
__global__ void repack_k_kernel(const u16* __restrict__ qkv, u16* __restrict__ Kb) {
    int t = blockIdx.x * 256 + threadIdx.x;
    if (t >= 24 * NF * 208 * 8) return;
    int d8 = t & 7;
    int rest = t >> 3;
    int n = rest % 208;
    rest /= 208;
    int f = rest % NF;
    int bh = rest / NF;
    int b = bh / HEADS, h = bh % HEADS;
    short8 v = {0, 0, 0, 0, 0, 0, 0, 0};
    if (n < SL)
        v = *(const short8*)(qkv + ((size_t)(b * NN) + 1 + f * SL + n) * 2304 + C + h * HD + d8 * 8);
    *(short8*)(Kb + (((size_t)bh * NF + f) * 208 + n) * 64 + d8 * 8) = v;
}

// ---------------- repack V: qkv_b -> Vt[bh][f][d][224] (transposed, pad zeroed) ----------------
__global__ void repack_v_kernel(const u16* __restrict__ qkv, u16* __restrict__ Vt) {
    int t = blockIdx.x * 256 + threadIdx.x;
    if (t >= 24 * NF * 64 * 28) return;
    int n8 = t % 28;
    int rest = t / 28;
    int d = rest % 64;
    rest /= 64;
    int f = rest % NF;
    int bh = rest / NF;
    int b = bh / HEADS, h = bh % HEADS;
    int n0 = n8 * 8;
    const u16* src = qkv + ((size_t)(b * NN) + 1 + f * SL) * 2304 + 2 * C + h * HD + d;
    short8 v;
#pragma unroll
    for (int j = 0; j < 8; j++) {
        int n = n0 + j;
        v[j] = (n < SL) ? (short)src[(size_t)n * 2304] : (short)0;
    }
    *(short8*)(Vt + (((size_t)bh * NF + f) * 64 + d) * 224 + n0) = v;
}

// ---------------- MFMA spatial attention v4 (XCD-aware, P-over-K overlay, V reg dbuf) -------
__global__ void space_attn_mfma(
    const u16* __restrict__ qkv, const u16* __restrict__ Kb,
    const u16* __restrict__ Vt, u16* __restrict__ x1) {
    __shared__ u16 smem[14848];  // 29696 B: phase 1 = swizzled K_f; phase 2 = 4 x 7424B P bufs
    int tid = threadIdx.x;
    int lane = tid & 63, wave = tid >> 6;
    int r16 = lane & 15, kg = lane >> 4;

    // XCD-aware decode (bijective): n = xcd + 8*(gw*25 + j)
    int n = blockIdx.x;
    int xcd = n & 7;
    int slot = n >> 3;
    int j = slot % 25;
    int gw = slot / 25;            // 0..23
    int bh = xcd * 3 + gw % 3;     // 3 bh per XCD
    int f = gw / 3;                // 8 f per XCD
    int b = bh / HEADS, h = bh % HEADS;

    // --- phase 1: stage K_f into LDS (linear dest, pre-swizzled source) ---
    const char* kb_g = (const char*)(Kb + ((size_t)bh * NF + f) * 208 * 64);
    for (int w = wave; w < 26; w += 4) {
        int p = w * 1024 + lane * 16;
        int row = p >> 7;
        int src = (p & ~127) | ((p & 127) ^ ((row & 7) << 4));
        gload_lds16(kb_g + src, (char*)smem + p);
    }
    __syncthreads();

    int strip = j * 4 + wave;
    bool act = strip < 98;
    if (!act) strip = 97;          // clamp: duplicate compute, guarded epilogue
    int q0 = strip * 16;

    const u16* qrow = qkv + ((size_t)(b * NN) + 1 + q0 + r16) * 2304 + h * HD + kg * 8;
    short8 aq0 = *(const short8*)(qrow);
    short8 aq1 = *(const short8*)(qrow + 32);

    f32x4 acc[13];
#pragma unroll
    for (int t = 0; t < 13; t++) acc[t] = (f32x4){0.f, 0.f, 0.f, 0.f};
    const char* ksm = (const char*)smem;
    int swz = (r16 & 7) << 4;
    __builtin_amdgcn_s_setprio(1);
#pragma unroll
    for (int t = 0; t < 13; t++) {
        const char* krow = ksm + (t * 16 + r16) * 128;
        short8 bk0 = *(const short8*)(krow + ((kg * 16) ^ swz));
        short8 bk1 = *(const short8*)(krow + ((64 + kg * 16) ^ swz));
        acc[t] = __builtin_amdgcn_mfma_f32_16x16x32_bf16(aq0, bk0, acc[t], 0, 0, 0);
        acc[t] = __builtin_amdgcn_mfma_f32_16x16x32_bf16(aq1, bk1, acc[t], 0, 0, 0);
    }
    __builtin_amdgcn_s_setprio(0);

    // issue first V fragments NOW so their latency hides under softmax VALU
    const u16* vbase = Vt + ((size_t)bh * NF + f) * 64 * 224;
    short8 vf[2][4];
#pragma unroll
    for (int dt = 0; dt < 4; dt++)
        vf[0][dt] = *(const short8*)(vbase + (dt * 16 + r16) * 224 + kg * 8);

    // softmax (scores already in log2 domain; q pre-scaled by QSCALE in qkv epilogue)
    bool tail_mask = (r16 >= 4);
    float mrow[4] = {-1e30f, -1e30f, -1e30f, -1e30f};
#pragma unroll
    for (int t = 0; t < 13; t++) {
        if (t == 12 && tail_mask) continue;
#pragma unroll
        for (int r = 0; r < 4; r++) mrow[r] = fmaxf(mrow[r], acc[t][r]);
    }
#pragma unroll
    for (int off = 8; off; off >>= 1)
#pragma unroll
        for (int r = 0; r < 4; r++) mrow[r] = fmaxf(mrow[r], __shfl_xor(mrow[r], off));

    float ssum[4] = {0.f, 0.f, 0.f, 0.f};
#pragma unroll
    for (int t = 0; t < 13; t++) {
#pragma unroll
        for (int r = 0; r < 4; r++) {
            float p = (t == 12 && tail_mask) ? 0.f : fast_exp2(acc[t][r] - mrow[r]);
            acc[t][r] = p;
            ssum[r] += p;
        }
    }
#pragma unroll
    for (int off = 8; off; off >>= 1)
#pragma unroll
        for (int r = 0; r < 4; r++) ssum[r] += __shfl_xor(ssum[r], off);
    float inv[4];
#pragma unroll
    for (int r = 0; r < 4; r++) inv[r] = 1.f / ssum[r];

    // --- phase 2: K buf is dead; P bufs overlay it ---
    __syncthreads();
    u16* pb = smem + wave * 3712;   // 7424 B per wave, stride 232 u16
#pragma unroll
    for (int t = 0; t < 13; t++)
#pragma unroll
        for (int r = 0; r < 4; r++)
            pb[(kg * 4 + r) * 232 + t * 16 + r16] = f2b(acc[t][r]);
    {
        int zr = lane >> 2, zc = 208 + (lane & 3) * 4;
        *(uint2*)(&pb[zr * 232 + zc]) = (uint2){0u, 0u};
    }

    // --- PV with V register double-buffer: kc+1 loads overlap kc MFMAs ---
    f32x4 o[4];
#pragma unroll
    for (int dt = 0; dt < 4; dt++) o[dt] = (f32x4){0.f, 0.f, 0.f, 0.f};
    __builtin_amdgcn_s_setprio(1);
#pragma unroll
    for (int kc = 0; kc < 7; kc++) {
        if (kc < 6) {
#pragma unroll
            for (int dt = 0; dt < 4; dt++)
                vf[(kc + 1) & 1][dt] = *(const short8*)(vbase + (dt * 16 + r16) * 224 + (kc + 1) * 32 + kg * 8);
        }
        short8 pa = *(const short8*)(&pb[r16 * 232 + kc * 32 + kg * 8]);
#pragma unroll
        for (int dt = 0; dt < 4; dt++)
            o[dt] = __builtin_amdgcn_mfma_f32_16x16x32_bf16(pa, vf[kc & 1][dt], o[dt], 0, 0, 0);
    }
    __builtin_amdgcn_s_setprio(0);

    if (act) {
#pragma unroll
        for (int dt = 0; dt < 4; dt++)
#pragma unroll
            for (int r = 0; r < 4; r++) {
                int q = q0 + kg * 4 + r;
                x1[(((size_t)(b * SS + q)) * NF + f) * C + h * HD + dt * 16 + r16] = f2b(o[dt][r] * inv[r]);
            }
    }
}

// ---------------- diagonal gather (bf16): xd[b,s,:] = x1[b,s,s/SL,:] ----------------
__global__ void diag_kernel(const u16* __restrict__ x1, u16* __restrict__ xd) {
    int i = blockIdx.x * 256 + threadIdx.x;
    int total = BB * SS * (C / 8);
    if (i >= total) return;
    int c8 = i % (C / 8);
    int row = i / (C / 8);
    int s = row % SS;
    int f = s / SL;
    ((short8*)(xd + (size_t)row * C))[c8] =
        ((const short8*)(x1 + (((size_t)row) * NF + f) * C))[c8];
}

// ---------------- temporal attention (log2-domain softmax) ----------------
__global__ void attn2_kernel(const u16* __restrict__ q2, const u16* __restrict__ k2,
                             const u16* __restrict__ x1, u16* __restrict__ y) {
    int item = blockIdx.x * 4 + (threadIdx.x >> 6);
    if (item >= BB * HEADS * SS) return;
    int lane = threadIdx.x & 63;
    int s = item % SS;
    int bh = item / SS;
    int b = bh / HEADS, hh = bh % HEADS;
    size_t rowbs = (size_t)(b * SS + s);
    float qv = b2f(q2[rowbs * C + hh * HD + lane]) * QSCALE;
    float lg[NF];
#pragma unroll
    for (int f = 0; f < NF; f++) {
        float p = qv * b2f(k2[(rowbs * NF + f) * C + hh * HD + lane]);
        for (int off = 32; off; off >>= 1) p += __shfl_xor(p, off);
        lg[f] = p;
    }
    float m = lg[0];
#pragma unroll
    for (int f = 1; f < NF; f++) m = fmaxf(m, lg[f]);
    float sum = 0.f;
#pragma unroll
    for (int f = 0; f < NF; f++) { lg[f] = fast_exp2(lg[f] - m); sum += lg[f]; }
    float inv = 1.f / sum;
    float acc = 0.f;
#pragma unroll
    for (int f = 0; f < NF; f++) acc += lg[f] * b2f(x1[(rowbs * NF + f) * C + hh * HD + lane]);
    y[((size_t)(b * NN) + 1 + s) * C + hh * HD + lane] = f2b(acc * inv);
}

extern "C" void kernel_launch(void* const* d_in, const int* in_sizes, int n_in,
                              void* d_out, int out_size, void* d_ws, size_t ws_size,
                              hipStream_t stream) {
    const float* x    = (const float*)d_in[0];
    const float* g1   = (const float*)d_in[1];
    const float* b1   = (const float*)d_in[2];
    const float* Wqkv = (const float*)d_in[3];
    const float* Wq   = (const float*)d_in[4];
    const float* Wkv  = (const float*)d_in[5];
    const float* Wp   = (const float*)d_in[6];
    const float* bp   = (const float*)d_in[7];
    const float* g2   = (const float*)d_in[8];
    const float* b2_  = (const float*)d_in[9];
    const float* W1   = (const float*)d_in[10];
    const float* bf1  = (const float*)d_in[11];
    const float* W2   = (const float*)d_in[12];
    const float* bf2  = (const float*)d_in[13];
    float* out = (float*)d_out;

    // workspace layout (u16 elements)
    u16* us     = (u16*)d_ws;
    u16* xn_b   = us;                    // M1*768    (reused as hn after LN2)
    u16* qkv_b  = xn_b   + 2409984;      // M1*2304
    u16* Wt_qkv = qkv_b  + 7229952;      // 2304*768
    u16* Wt_q   = Wt_qkv + 1769472;      // 768*768
    u16* Wt_kv  = Wt_q   + 589824;       // 768*768 (first half of Wkv)
    u16* Wt_p   = Wt_kv  + 589824;       // 768*768
    u16* W1t    = Wt_p   + 589824;       // 3072*768
    u16* W2t    = W1t    + 2359296;      // 768*3072
    u16* Kb     = W2t    + 2359296;      // 24*8*208*64
    u16* Vt     = Kb     + 2555904;      // 24*8*64*224
    u16* x1b    = Vt     + 2752512;      // B*S*F*C
    u16* xdb    = x1b    + 19267584;     // B*S*C
    u16* q2b    = xdb    + 2408448;      // B*S*C
    u16* k2b    = q2b    + 2408448;      // B*S*F*C
    u16* y_b    = k2b    + 19267584;     // B*N*C
    u16* a1b    = y_b    + 2409984;      // B*N*HID
    float* cls_ws   = (float*)(a1b + 9639936);     // 24*7*66 floats
    float* fc2_part = cls_ws + 24 * 7 * 66;        // 4 * M1*768 floats

    const int M1 = BB * NN;       // 3138
    const int M2 = BB * SS;       // 3136
    const int M3 = BB * SS * NF;  // 25088

    // 0. weight transpose + bf16 convert
    wtrans_kernel<<<dim3(2304 / 64, 768 / 64), 256, 0, stream>>>(Wqkv, Wt_qkv, 768, 2304, 2304);
    wtrans_kernel<<<dim3(768 / 64, 768 / 64), 256, 0, stream>>>(Wq, Wt_q, 768, 768, 768);
    wtrans_kernel<<<dim3(768 / 64, 768 / 64), 256, 0, stream>>>(Wkv, Wt_kv, 768, 768, 1536);
    wtrans_kernel<<<dim3(768 / 64, 768 / 64), 256, 0, stream>>>(Wp, Wt_p, 768, 768, 768);
    wtrans_kernel<<<dim3(3072 / 64, 768 / 64), 256, 0, stream>>>(W1, W1t, 768, 3072, 3072);
    wtrans_kernel<<<dim3(768 / 64, 3072 / 64), 256, 0, stream>>>(W2, W2t, 3072, 768, 768);
    // 1. LN1 -> bf16
    ln_kernel<<<M1, 256, 0, stream>>>(x, g1, b1, xn_b, M1);
    // 2. qkv_b = xn_b @ Wqkv (bf16 out; q cols pre-scaled by QSCALE)
    gemm_bf16<3><<<18 * 25, 256, 0, stream>>>(
        xn_b, Wt_qkv, nullptr, nullptr, qkv_b, M1, 2304, 768, 768, 768, 18);
    // 3. repack K, V
    repack_k_kernel<<<(24 * NF * 208 * 8 + 255) / 256, 256, 0, stream>>>(qkv_b, Kb);
    repack_v_kernel<<<(24 * NF * 64 * 28 + 255) / 256, 256, 0, stream>>>(qkv_b, Vt);
    // 4. cls attention (two-pass flash-style) -> y_b row 0
    cls_partial_kernel<<<dim3(CLS_NC, BB * HEADS), 256, 0, stream>>>(qkv_b, cls_ws);
    cls_reduce_kernel<<<BB * HEADS, 64, 0, stream>>>(cls_ws, y_b);
    // 5. spatial attention -> x1b (XCD-aware 1-D grid, P-over-K overlay, V reg dbuf)
    space_attn_mfma<<<4800, 256, 0, stream>>>(qkv_b, Kb, Vt, x1b);
    // 6. diag gather
    diag_kernel<<<(BB * SS * (C / 8) + 255) / 256, 256, 0, stream>>>(x1b, xdb);
    // 7. q2 = xd @ Wq
    gemm_bf16<0><<<6 * 25, 256, 0, stream>>>(
        xdb, Wt_q, nullptr, nullptr, q2b, M2, 768, 768, 768, 768, 6);
    // 8. k2 = x1 @ Wkv[:, :C]
    gemm_bf16<0><<<6 * 196, 256, 0, stream>>>(
        x1b, Wt_kv, nullptr, nullptr, k2b, M3, 768, 768, 768, 768, 6);
    // 9. temporal attention -> y_b rows 1..S
    attn2_kernel<<<(BB * HEADS * SS + 3) / 4, 256, 0, stream>>>(q2b, k2b, x1b, y_b);
    // 10. proj: out = y_b @ Wp + bp + x  (f32)
    gemm_bf16<2><<<6 * 25, 256, 0, stream>>>(
        y_b, Wt_p, bp, x, out, M1, 768, 768, 768, 768, 6);
    // 11. LN2 -> bf16 (reuse xn_b)
    ln_kernel<<<M1, 256, 0, stream>>>(out, g2, b2_, xn_b, M1);
    // 12. fc1 + exact GELU -> bf16
    gemm_bf16<1><<<24 * 25, 256, 0, stream>>>(
        xn_b, W1t, bf1, nullptr, a1b, M1, 3072, 768, 768, 768, 24);
    // 13. fc2 split-K=4: partials (f32), then merge (+bias+resid in-place on d_out)
    gemm_bf16<4><<<6 * 25 * 4, 256, 0, stream>>>(
        a1b, W2t, nullptr, nullptr, fc2_part, M1, 768, 768, 3072, 3072, 6);
    fc2_merge_kernel<<<(BB * NN * (C / 4) + 255) / 256, 256, 0, stream>>>(
        fc2_part, bf2, out);
}